// Round 3
// baseline (4711.968 us; speedup 1.0000x reference)
//
#include <hip/hip_runtime.h>

#define NN 50000
#define TT 5
#define EE 500000
#define NC 8192
#define ET (EE + NN)

__device__ __forceinline__ float lrelu(float x) { return x >= 0.f ? x : 0.2f * x; }
__device__ __forceinline__ float sigm(float x) { return 1.f / (1.f + expf(-x)); }
__device__ __forceinline__ float fsel(float4 v, int i) {
    float r = v.x; if (i == 1) r = v.y; if (i == 2) r = v.z; if (i == 3) r = v.w; return r;
}
__device__ __forceinline__ float fget(float4 v, int k) {
    return k == 0 ? v.x : k == 1 ? v.y : k == 2 ? v.z : v.w;
}

// ---------------- CSR build ----------------
__global__ void k_fill1(int* p, int n) {
    int i = blockIdx.x * 256 + threadIdx.x;
    if (i < n) p[i] = 1;
}

__global__ void k_count(const int* __restrict__ edges, int* __restrict__ cnt) {
    int i = blockIdx.x * 256 + threadIdx.x;
    if (i >= TT * EE) return;
    int t = i / EE, e = i % EE;
    int dst = edges[(size_t)t * 2 * EE + EE + e];
    atomicAdd(&cnt[t * NN + dst], 1);
}

__global__ void k_scan(int* __restrict__ cnt, int* __restrict__ off) {
    int t = blockIdx.x;
    __shared__ int s[256];
    int carry = 0;
    for (int base = 0; base < NN; base += 256) {
        int i = base + threadIdx.x;
        int v = (i < NN) ? cnt[t * NN + i] : 0;
        s[threadIdx.x] = v;
        __syncthreads();
        for (int o = 1; o < 256; o <<= 1) {
            int tv = (threadIdx.x >= o) ? s[threadIdx.x - o] : 0;
            __syncthreads();
            s[threadIdx.x] += tv;
            __syncthreads();
        }
        int incl = s[threadIdx.x];
        int excl = carry + incl - v;
        if (i < NN) {
            off[t * (NN + 1) + i] = excl;
            cnt[t * NN + i] = excl;   // becomes fill pointer
        }
        carry += s[255];
        __syncthreads();
    }
    if (threadIdx.x == 0) off[t * (NN + 1) + NN] = carry;
}

__global__ void k_csrfill(const int* __restrict__ edges, int* __restrict__ fil,
                          int* __restrict__ csr) {
    int i = blockIdx.x * 256 + threadIdx.x;
    if (i >= TT * ET) return;
    int t = i / ET, r = i % ET;
    int src, dst;
    if (r < EE) {
        src = edges[(size_t)t * 2 * EE + r];
        dst = edges[(size_t)t * 2 * EE + EE + r];
    } else {
        src = dst = r - EE;
    }
    int pos = atomicAdd(&fil[t * NN + dst], 1);
    csr[(size_t)t * ET + pos] = src;
}

// ---------------- misc ----------------
__global__ void k_transpose(const float* __restrict__ src, float* __restrict__ dst,
                            int R, int C) {
    int i = blockIdx.x * 256 + threadIdx.x;
    if (i >= R * C) return;
    int r = i / C, c = i % C;
    dst[c * R + r] = src[i];
}

__global__ void k_gather(const float* __restrict__ x, const int* __restrict__ clf,
                         float* __restrict__ dst) {
    int i = blockIdx.x * 256 + threadIdx.x;
    if (i >= NC * 16) return;
    int row = i >> 4, c4 = i & 15;
    int node = clf[row];
    ((float4*)dst)[row * 16 + c4] = ((const float4*)x)[(size_t)node * 16 + c4];
}

// ---------------- GEMMs ----------------
// h[N,256] = x[N,64] @ W[64,256]
__global__ __launch_bounds__(256) void k_gemm_h(const float* __restrict__ x,
                                                const float* __restrict__ W,
                                                float* __restrict__ h) {
    __shared__ float Wl[64 * 256];
    for (int i = threadIdx.x; i < 4096; i += 256)
        *(float4*)&Wl[i * 4] = ((const float4*)W)[i];
    __syncthreads();
    int lane = threadIdx.x & 63;
    int wg = threadIdx.x >> 6;
    int col = lane * 4;
    int base = blockIdx.x * 32 + wg * 8;
    float4 acc[8];
#pragma unroll
    for (int r = 0; r < 8; ++r) acc[r] = make_float4(0.f, 0.f, 0.f, 0.f);
    for (int k = 0; k < 64; k += 4) {
        float4 xq[8];
#pragma unroll
        for (int r = 0; r < 8; ++r) {
            int row = base + r; if (row > NN - 1) row = NN - 1;
            xq[r] = *(const float4*)&x[(size_t)row * 64 + k];
        }
#pragma unroll
        for (int kk = 0; kk < 4; ++kk) {
            float4 w4 = *(const float4*)&Wl[(k + kk) * 256 + col];
#pragma unroll
            for (int r = 0; r < 8; ++r) {
                float xv = fget(xq[r], kk);
                acc[r].x += xv * w4.x; acc[r].y += xv * w4.y;
                acc[r].z += xv * w4.z; acc[r].w += xv * w4.w;
            }
        }
    }
#pragma unroll
    for (int r = 0; r < 8; ++r) {
        int row = base + r;
        if (row < NN) *(float4*)&h[(size_t)row * 256 + col] = acc[r];
    }
}

// out[N,64] = relu(x[N,256] @ W[256,64] + b)
__global__ __launch_bounds__(256) void k_gemm_lin(const float* __restrict__ x,
                                                  const float* __restrict__ W,
                                                  const float* __restrict__ b,
                                                  float* __restrict__ out) {
    __shared__ float Wl[256 * 64];
    for (int i = threadIdx.x; i < 4096; i += 256)
        *(float4*)&Wl[i * 4] = ((const float4*)W)[i];
    __syncthreads();
    int cg = threadIdx.x & 15;
    int wg = threadIdx.x >> 4;
    int col = cg * 4;
    int base = blockIdx.x * 128 + wg * 8;
    float4 acc[8];
#pragma unroll
    for (int r = 0; r < 8; ++r) acc[r] = make_float4(0.f, 0.f, 0.f, 0.f);
    for (int k = 0; k < 256; k += 4) {
        float4 xq[8];
#pragma unroll
        for (int r = 0; r < 8; ++r) {
            int row = base + r; if (row > NN - 1) row = NN - 1;
            xq[r] = *(const float4*)&x[(size_t)row * 256 + k];
        }
#pragma unroll
        for (int kk = 0; kk < 4; ++kk) {
            float4 w4 = *(const float4*)&Wl[(k + kk) * 64 + col];
#pragma unroll
            for (int r = 0; r < 8; ++r) {
                float xv = fget(xq[r], kk);
                acc[r].x += xv * w4.x; acc[r].y += xv * w4.y;
                acc[r].z += xv * w4.z; acc[r].w += xv * w4.w;
            }
        }
    }
    float4 b4 = ((const float4*)b)[cg];
#pragma unroll
    for (int r = 0; r < 8; ++r) {
        int row = base + r;
        if (row < NN) {
            float4 o;
            o.x = fmaxf(acc[r].x + b4.x, 0.f);
            o.y = fmaxf(acc[r].y + b4.y, 0.f);
            o.z = fmaxf(acc[r].z + b4.z, 0.f);
            o.w = fmaxf(acc[r].w + b4.w, 0.f);
            *(float4*)&out[(size_t)row * 64 + col] = o;
        }
    }
}

// ---------------- attention ----------------
__global__ __launch_bounds__(256) void k_alar(const float* __restrict__ h,
                                              const float* __restrict__ as_,
                                              const float* __restrict__ ad_,
                                              float* __restrict__ al,
                                              float* __restrict__ ar) {
    int lane = threadIdx.x & 63;
    int n = blockIdx.x * 4 + (threadIdx.x >> 6);
    float4 hv = *(const float4*)&h[(size_t)n * 256 + lane * 4];
    float4 ua = ((const float4*)as_)[lane];
    float4 ud = ((const float4*)ad_)[lane];
    float ps = hv.x * ua.x + hv.y * ua.y + hv.z * ua.z + hv.w * ua.w;
    float pd = hv.x * ud.x + hv.y * ud.y + hv.z * ud.z + hv.w * ud.w;
#pragma unroll
    for (int o = 1; o < 16; o <<= 1) {
        ps += __shfl_xor(ps, o, 64);
        pd += __shfl_xor(pd, o, 64);
    }
    if ((lane & 15) == 0) {
        al[n * 4 + (lane >> 4)] = ps;
        ar[n * 4 + (lane >> 4)] = pd;
    }
}

__global__ __launch_bounds__(256) void k_agg(const int* __restrict__ off,
                                             const int* __restrict__ csr,
                                             const float* __restrict__ al,
                                             const float* __restrict__ ar,
                                             const float* __restrict__ h,
                                             const float* __restrict__ bias,
                                             float* __restrict__ out) {
    int lane = threadIdx.x & 63;
    int n = blockIdx.x * 4 + (threadIdx.x >> 6);
    int hd = lane >> 4;
    float4 ar4 = *(const float4*)&ar[n * 4];
    int beg = off[n], end = off[n + 1];
    float4 m4 = make_float4(-1e30f, -1e30f, -1e30f, -1e30f);
    for (int j = beg + lane; j < end; j += 64) {
        int s = csr[j];
        float4 a4 = *(const float4*)&al[s * 4];
        m4.x = fmaxf(m4.x, lrelu(a4.x + ar4.x));
        m4.y = fmaxf(m4.y, lrelu(a4.y + ar4.y));
        m4.z = fmaxf(m4.z, lrelu(a4.z + ar4.z));
        m4.w = fmaxf(m4.w, lrelu(a4.w + ar4.w));
    }
#pragma unroll
    for (int d = 32; d >= 1; d >>= 1) {
        m4.x = fmaxf(m4.x, __shfl_xor(m4.x, d, 64));
        m4.y = fmaxf(m4.y, __shfl_xor(m4.y, d, 64));
        m4.z = fmaxf(m4.z, __shfl_xor(m4.z, d, 64));
        m4.w = fmaxf(m4.w, __shfl_xor(m4.w, d, 64));
    }
    float mh = fsel(m4, hd);
    float arh = fsel(ar4, hd);
    float den = 0.f;
    float4 acc = make_float4(0.f, 0.f, 0.f, 0.f);
    for (int j = beg; j < end; ++j) {
        int s = csr[j];
        float e = lrelu(al[s * 4 + hd] + arh);
        float p = expf(e - mh);
        den += p;
        float4 hv = *(const float4*)&h[(size_t)s * 256 + lane * 4];
        acc.x += p * hv.x; acc.y += p * hv.y;
        acc.z += p * hv.z; acc.w += p * hv.w;
    }
    float inv = 1.f / (den + 1e-16f);
    float4 ub = ((const float4*)bias)[lane];
    float4 o;
    o.x = acc.x * inv + ub.x;
    o.y = acc.y * inv + ub.y;
    o.z = acc.z * inv + ub.z;
    o.w = acc.w * inv + ub.w;
    *(float4*)&out[(size_t)n * 256 + lane * 4] = o;
}

// ---------------- LSTM ----------------
__global__ __launch_bounds__(256) void k_lstm(const float* __restrict__ xa,
                                              const float* __restrict__ xb,
                                              const float* __restrict__ WiT,
                                              const float* __restrict__ WhT,
                                              const float* __restrict__ bb,
                                              const float* __restrict__ h_in,
                                              const float* __restrict__ c_in,
                                              float* __restrict__ h_out,
                                              float* __restrict__ c_out,
                                              float* __restrict__ hs_out) {
    __shared__ float xs[4][192];
    int w = threadIdx.x >> 6, lane = threadIdx.x & 63;
    int row = blockIdx.x * 4 + w;
    xs[w][lane] = xa[(size_t)row * 64 + lane];
    if (xb) xs[w][64 + lane] = xb[(size_t)row * 64 + lane];
    xs[w][128 + lane] = h_in[(size_t)row * 64 + lane];
    __syncthreads();
    float ai = bb[lane];
    float af = bb[64 + lane];
    float ag = bb[128 + lane];
    float ao = bb[192 + lane];
    int D = xb ? 128 : 64;
    for (int k = 0; k < D; ++k) {
        float xv = xs[w][k];
        const float* wr = &WiT[k * 256];
        ai += xv * wr[lane];       af += xv * wr[64 + lane];
        ag += xv * wr[128 + lane]; ao += xv * wr[192 + lane];
    }
    for (int k = 0; k < 64; ++k) {
        float hv = xs[w][128 + k];
        const float* wr = &WhT[k * 256];
        ai += hv * wr[lane];       af += hv * wr[64 + lane];
        ag += hv * wr[128 + lane]; ao += hv * wr[192 + lane];
    }
    float iv = sigm(ai), fv = sigm(af), gv = tanhf(ag), ov = sigm(ao);
    float c = fv * c_in[(size_t)row * 64 + lane] + iv * gv;
    float hh = ov * tanhf(c);
    c_out[(size_t)row * 64 + lane] = c;
    h_out[(size_t)row * 64 + lane] = hh;
    if (hs_out) hs_out[(size_t)row * 64 + lane] = hh;
}

// ---------------- final FC ----------------
__global__ __launch_bounds__(256) void k_final(const float* __restrict__ h1,
                                               const float* __restrict__ h2,
                                               const float* __restrict__ w1,
                                               const float* __restrict__ b1,
                                               const float* __restrict__ w2,
                                               const float* __restrict__ b2,
                                               float* __restrict__ out) {
    __shared__ float zs[4][128];
    int w = threadIdx.x >> 6, lane = threadIdx.x & 63;
    int row = blockIdx.x * 4 + w;
    zs[w][lane] = h1[(size_t)row * 64 + lane];
    zs[w][64 + lane] = h2[(size_t)row * 64 + lane];
    __syncthreads();
    float acc = b1[lane];
    for (int k = 0; k < 128; ++k) acc += zs[w][k] * w1[k * 64 + lane];
    float r = fmaxf(acc, 0.f);
    float t0 = r * w2[lane * 2];
    float t1 = r * w2[lane * 2 + 1];
#pragma unroll
    for (int o = 32; o >= 1; o >>= 1) {
        t0 += __shfl_xor(t0, o, 64);
        t1 += __shfl_xor(t1, o, 64);
    }
    if (lane == 0) {
        out[row * 2]     = fmaxf(t0 + b2[0], 0.f);
        out[row * 2 + 1] = fmaxf(t1 + b2[1], 0.f);
    }
}

extern "C" void kernel_launch(void* const* d_in, const int* in_sizes, int n_in,
                              void* d_out, int out_size, void* d_ws, size_t ws_size,
                              hipStream_t stream) {
    const float* emb  = (const float*)d_in[0];
    const float* g1W  = (const float*)d_in[1];
    const float* g1as = (const float*)d_in[2];
    const float* g1ad = (const float*)d_in[3];
    const float* g1b  = (const float*)d_in[4];
    const float* l1W  = (const float*)d_in[5];
    const float* l1b  = (const float*)d_in[6];
    const float* g2W  = (const float*)d_in[7];
    const float* g2as = (const float*)d_in[8];
    const float* g2ad = (const float*)d_in[9];
    const float* g2b  = (const float*)d_in[10];
    const float* l2W  = (const float*)d_in[11];
    const float* l2b  = (const float*)d_in[12];
    const float* Wi1  = (const float*)d_in[13];
    const float* Wh1  = (const float*)d_in[14];
    const float* b1   = (const float*)d_in[15];
    const float* Wi2  = (const float*)d_in[16];
    const float* Wh2  = (const float*)d_in[17];
    const float* b2   = (const float*)d_in[18];
    const float* fc1W = (const float*)d_in[19];
    const float* fc1b = (const float*)d_in[20];
    const float* fc2W = (const float*)d_in[21];
    const float* fc2b = (const float*)d_in[22];
    const int* edges = (const int*)d_in[23];
    const int* clf   = (const int*)d_in[27];

    char* ws = (char*)d_ws;
    size_t woff = 0;
    auto alloc = [&](size_t bytes) -> void* {
        void* p = ws + woff;
        woff += (bytes + 255) & ~(size_t)255;
        return p;
    };
    int* csr_off  = (int*)alloc((size_t)TT * (NN + 1) * 4);
    int* csr_fil  = (int*)alloc((size_t)TT * NN * 4);
    int* csr_src  = (int*)alloc((size_t)TT * ET * 4);
    float* xbuf   = (float*)alloc((size_t)NN * 64 * 4);
    float* hbuf   = (float*)alloc((size_t)NN * 256 * 4);
    float* gat    = (float*)alloc((size_t)NN * 256 * 4);
    float* albuf  = (float*)alloc((size_t)NN * 4 * 4);
    float* arbuf  = (float*)alloc((size_t)NN * 4 * 4);
    float* seq    = (float*)alloc((size_t)2 * TT * NC * 64 * 4);
    float* hsb    = (float*)alloc((size_t)TT * NC * 64 * 4);
    float* h1s    = (float*)alloc((size_t)NC * 64 * 4);
    float* c1s    = (float*)alloc((size_t)NC * 64 * 4);
    float* h2s    = (float*)alloc((size_t)NC * 64 * 4);
    float* c2s    = (float*)alloc((size_t)NC * 64 * 4);
    float* WiT1   = (float*)alloc(128 * 256 * 4);
    float* WhT1   = (float*)alloc(64 * 256 * 4);
    float* WiT2   = (float*)alloc(64 * 256 * 4);
    float* WhT2   = (float*)alloc(64 * 256 * 4);

    // CSR build (per snapshot, includes self-loops)
    k_fill1<<<(TT * NN + 255) / 256, 256, 0, stream>>>(csr_fil, TT * NN);
    k_count<<<(TT * EE + 255) / 256, 256, 0, stream>>>(edges, csr_fil);
    k_scan<<<TT, 256, 0, stream>>>(csr_fil, csr_off);
    k_csrfill<<<(TT * ET + 255) / 256, 256, 0, stream>>>(edges, csr_fil, csr_src);

    // LSTM weight transposes (f32 [K][256] for coalesced gate loads)
    k_transpose<<<(256 * 128 + 255) / 256, 256, 0, stream>>>(Wi1, WiT1, 256, 128);
    k_transpose<<<(256 * 64 + 255) / 256, 256, 0, stream>>>(Wh1, WhT1, 256, 64);
    k_transpose<<<(256 * 64 + 255) / 256, 256, 0, stream>>>(Wi2, WiT2, 256, 64);
    k_transpose<<<(256 * 64 + 255) / 256, 256, 0, stream>>>(Wh2, WhT2, 256, 64);

    for (int s = 0; s < 2; ++s) {
        const float* gW  = s ? g2W : g1W;
        const float* gas = s ? g2as : g1as;
        const float* gad = s ? g2ad : g1ad;
        const float* gb  = s ? g2b : g1b;
        const float* lW  = s ? l2W : l1W;
        const float* lb  = s ? l2b : l1b;
        for (int t = 0; t < TT; ++t) {
            for (int l = 0; l < 2; ++l) {
                const float* xin = (l == 0) ? (emb + (size_t)t * NN * 64) : xbuf;
                k_gemm_h<<<(NN + 31) / 32, 256, 0, stream>>>(
                    xin, gW + (size_t)l * 64 * 256, hbuf);
                k_alar<<<NN / 4, 256, 0, stream>>>(
                    hbuf, gas + l * 256, gad + l * 256, albuf, arbuf);
                k_agg<<<NN / 4, 256, 0, stream>>>(
                    csr_off + (size_t)t * (NN + 1), csr_src + (size_t)t * ET,
                    albuf, arbuf, hbuf, gb + l * 256, gat);
                k_gemm_lin<<<(NN + 127) / 128, 256, 0, stream>>>(
                    gat, lW + (size_t)l * 256 * 64, lb + l * 64, xbuf);
            }
            k_gather<<<(NC * 16 + 255) / 256, 256, 0, stream>>>(
                xbuf, clf, seq + ((size_t)s * TT + t) * NC * 64);
        }
    }

    hipMemsetAsync(h1s, 0, (size_t)NC * 64 * 4, stream);
    hipMemsetAsync(c1s, 0, (size_t)NC * 64 * 4, stream);
    hipMemsetAsync(h2s, 0, (size_t)NC * 64 * 4, stream);
    hipMemsetAsync(c2s, 0, (size_t)NC * 64 * 4, stream);

    // LSTM1: time reversed (outs[::-1]) -> step st reads snapshot TT-1-st
    for (int st = 0; st < TT; ++st) {
        int tsn = TT - 1 - st;
        k_lstm<<<NC / 4, 256, 0, stream>>>(
            seq + (size_t)tsn * NC * 64,
            seq + (size_t)(TT + tsn) * NC * 64,
            WiT1, WhT1, b1, h1s, c1s, h1s, c1s,
            hsb + (size_t)st * NC * 64);
    }
    // LSTM2 over hs
    for (int st = 0; st < TT; ++st) {
        k_lstm<<<NC / 4, 256, 0, stream>>>(
            hsb + (size_t)st * NC * 64, nullptr,
            WiT2, WhT2, b2, h2s, c2s, h2s, c2s, nullptr);
    }
    k_final<<<NC / 4, 256, 0, stream>>>(h1s, h2s, fc1W, fc1b, fc2W, fc2b, (float*)d_out);
}

// Round 6
// 4272.583 us; speedup vs baseline: 1.1028x; 1.1028x over previous
//
#include <hip/hip_runtime.h>

#define NN 50000
#define TT 5
#define EE 500000
#define NC 8192
#define ET (EE + NN)
#define NCH 196   // ceil(NN/256)

__device__ __forceinline__ float lrelu(float x) { return x >= 0.f ? x : 0.2f * x; }
__device__ __forceinline__ float sigm(float x) { return 1.f / (1.f + expf(-x)); }
__device__ __forceinline__ float fsel(float4 v, int i) {
    float r = v.x; if (i == 1) r = v.y; if (i == 2) r = v.z; if (i == 3) r = v.w; return r;
}
__device__ __forceinline__ float fget(float4 v, int k) {
    return k == 0 ? v.x : k == 1 ? v.y : k == 2 ? v.z : v.w;
}

// ---------------- CSR build ----------------
__global__ void k_fill1(int* p, int n) {
    int i = blockIdx.x * 256 + threadIdx.x;
    if (i < n) p[i] = 1;
}

__global__ void k_count(const int* __restrict__ edges, int* __restrict__ cnt) {
    int i = blockIdx.x * 256 + threadIdx.x;
    if (i >= TT * EE) return;
    int t = i / EE, e = i % EE;
    int dst = edges[(size_t)t * 2 * EE + EE + e];
    atomicAdd(&cnt[t * NN + dst], 1);
}

// phase 1: per-chunk sums.  grid = TT*NCH
__global__ __launch_bounds__(256) void k_scan1(const int* __restrict__ cnt,
                                               int* __restrict__ sums) {
    int t = blockIdx.x / NCH, ch = blockIdx.x % NCH;
    int i = ch * 256 + threadIdx.x;
    int v = (i < NN) ? cnt[t * NN + i] : 0;
    __shared__ int s[256];
    s[threadIdx.x] = v;
    __syncthreads();
    for (int o = 128; o > 0; o >>= 1) {
        if (threadIdx.x < o) s[threadIdx.x] += s[threadIdx.x + o];
        __syncthreads();
    }
    if (threadIdx.x == 0) sums[t * NCH + ch] = s[0];
}

// phase 2: exclusive scan of NCH chunk sums per snapshot.  grid = TT
__global__ __launch_bounds__(256) void k_scan2(const int* __restrict__ sums,
                                               int* __restrict__ bases,
                                               int* __restrict__ off) {
    int t = blockIdx.x;
    __shared__ int s[256];
    int v = (threadIdx.x < NCH) ? sums[t * NCH + threadIdx.x] : 0;
    s[threadIdx.x] = v;
    __syncthreads();
    for (int o = 1; o < 256; o <<= 1) {
        int tv = (threadIdx.x >= o) ? s[threadIdx.x - o] : 0;
        __syncthreads();
        s[threadIdx.x] += tv;
        __syncthreads();
    }
    if (threadIdx.x < NCH) bases[t * NCH + threadIdx.x] = s[threadIdx.x] - v;
    if (threadIdx.x == 255) off[t * (NN + 1) + NN] = s[255];
}

// phase 3: local scan + base -> off & fill ptr.  grid = TT*NCH
__global__ __launch_bounds__(256) void k_scan3(int* __restrict__ cnt,
                                               const int* __restrict__ bases,
                                               int* __restrict__ off) {
    int t = blockIdx.x / NCH, ch = blockIdx.x % NCH;
    int i = ch * 256 + threadIdx.x;
    int v = (i < NN) ? cnt[t * NN + i] : 0;
    __shared__ int s[256];
    s[threadIdx.x] = v;
    __syncthreads();
    for (int o = 1; o < 256; o <<= 1) {
        int tv = (threadIdx.x >= o) ? s[threadIdx.x - o] : 0;
        __syncthreads();
        s[threadIdx.x] += tv;
        __syncthreads();
    }
    if (i < NN) {
        int excl = bases[t * NCH + ch] + s[threadIdx.x] - v;
        off[t * (NN + 1) + i] = excl;
        cnt[t * NN + i] = excl;  // becomes fill pointer
    }
}

__global__ void k_csrfill(const int* __restrict__ edges, int* __restrict__ fil,
                          int* __restrict__ csr) {
    int i = blockIdx.x * 256 + threadIdx.x;
    if (i >= TT * ET) return;
    int t = i / ET, r = i % ET;
    int src, dst;
    if (r < EE) {
        src = edges[(size_t)t * 2 * EE + r];
        dst = edges[(size_t)t * 2 * EE + EE + r];
    } else {
        src = dst = r - EE;
    }
    int pos = atomicAdd(&fil[t * NN + dst], 1);
    csr[(size_t)t * ET + pos] = src;
}

// ---------------- misc ----------------
__global__ void k_transpose(const float* __restrict__ src, float* __restrict__ dst,
                            int R, int C) {
    int i = blockIdx.x * 256 + threadIdx.x;
    if (i >= R * C) return;
    int r = i / C, c = i % C;
    dst[c * R + r] = src[i];
}

__global__ void k_gather(const float* __restrict__ x, const int* __restrict__ clf,
                         float* __restrict__ dst) {
    int i = blockIdx.x * 256 + threadIdx.x;
    if (i >= NC * 16) return;
    int row = i >> 4, c4 = i & 15;
    int node = clf[row];
    ((float4*)dst)[row * 16 + c4] = ((const float4*)x)[(size_t)node * 16 + c4];
}

// ---------------- GEMM + fused attention coefficients ----------------
// h[N,256] = x[N,64] @ W[64,256];  al/ar[N,4] = (h * a_s/a_d).sum per head
__global__ __launch_bounds__(256) void k_gemm_h(const float* __restrict__ x,
                                                const float* __restrict__ W,
                                                const float* __restrict__ as_,
                                                const float* __restrict__ ad_,
                                                float* __restrict__ h,
                                                float* __restrict__ al,
                                                float* __restrict__ ar) {
    __shared__ float Wl[64 * 256];
    for (int i = threadIdx.x; i < 4096; i += 256)
        *(float4*)&Wl[i * 4] = ((const float4*)W)[i];
    __syncthreads();
    int lane = threadIdx.x & 63;
    int wg = threadIdx.x >> 6;
    int col = lane * 4;
    int base = blockIdx.x * 32 + wg * 8;
    float4 ua = ((const float4*)as_)[lane];
    float4 ud = ((const float4*)ad_)[lane];
    float4 acc[8];
#pragma unroll
    for (int r = 0; r < 8; ++r) acc[r] = make_float4(0.f, 0.f, 0.f, 0.f);
    for (int k = 0; k < 64; k += 4) {
        float4 xq[8];
#pragma unroll
        for (int r = 0; r < 8; ++r) {
            int row = base + r; if (row > NN - 1) row = NN - 1;
            xq[r] = *(const float4*)&x[(size_t)row * 64 + k];
        }
#pragma unroll
        for (int kk = 0; kk < 4; ++kk) {
            float4 w4 = *(const float4*)&Wl[(k + kk) * 256 + col];
#pragma unroll
            for (int r = 0; r < 8; ++r) {
                float xv = fget(xq[r], kk);
                acc[r].x += xv * w4.x; acc[r].y += xv * w4.y;
                acc[r].z += xv * w4.z; acc[r].w += xv * w4.w;
            }
        }
    }
#pragma unroll
    for (int r = 0; r < 8; ++r) {
        int row = base + r;
        if (row < NN) *(float4*)&h[(size_t)row * 256 + col] = acc[r];
        // fused al/ar: dot with a_s/a_d, reduce across the 16 lanes of this head
        float ps = acc[r].x * ua.x + acc[r].y * ua.y + acc[r].z * ua.z + acc[r].w * ua.w;
        float pd = acc[r].x * ud.x + acc[r].y * ud.y + acc[r].z * ud.z + acc[r].w * ud.w;
#pragma unroll
        for (int o = 1; o < 16; o <<= 1) {
            ps += __shfl_xor(ps, o, 64);
            pd += __shfl_xor(pd, o, 64);
        }
        if (row < NN && (lane & 15) == 0) {
            al[row * 4 + (lane >> 4)] = ps;
            ar[row * 4 + (lane >> 4)] = pd;
        }
    }
}

// out[N,64] = relu(x[N,256] @ W[256,64] + b)
__global__ __launch_bounds__(256) void k_gemm_lin(const float* __restrict__ x,
                                                  const float* __restrict__ W,
                                                  const float* __restrict__ b,
                                                  float* __restrict__ out) {
    __shared__ float Wl[256 * 64];
    for (int i = threadIdx.x; i < 4096; i += 256)
        *(float4*)&Wl[i * 4] = ((const float4*)W)[i];
    __syncthreads();
    int cg = threadIdx.x & 15;
    int wg = threadIdx.x >> 4;
    int col = cg * 4;
    int base = blockIdx.x * 128 + wg * 8;
    float4 acc[8];
#pragma unroll
    for (int r = 0; r < 8; ++r) acc[r] = make_float4(0.f, 0.f, 0.f, 0.f);
    for (int k = 0; k < 256; k += 4) {
        float4 xq[8];
#pragma unroll
        for (int r = 0; r < 8; ++r) {
            int row = base + r; if (row > NN - 1) row = NN - 1;
            xq[r] = *(const float4*)&x[(size_t)row * 256 + k];
        }
#pragma unroll
        for (int kk = 0; kk < 4; ++kk) {
            float4 w4 = *(const float4*)&Wl[(k + kk) * 64 + col];
#pragma unroll
            for (int r = 0; r < 8; ++r) {
                float xv = fget(xq[r], kk);
                acc[r].x += xv * w4.x; acc[r].y += xv * w4.y;
                acc[r].z += xv * w4.z; acc[r].w += xv * w4.w;
            }
        }
    }
    float4 b4 = ((const float4*)b)[cg];
#pragma unroll
    for (int r = 0; r < 8; ++r) {
        int row = base + r;
        if (row < NN) {
            float4 o;
            o.x = fmaxf(acc[r].x + b4.x, 0.f);
            o.y = fmaxf(acc[r].y + b4.y, 0.f);
            o.z = fmaxf(acc[r].z + b4.z, 0.f);
            o.w = fmaxf(acc[r].w + b4.w, 0.f);
            *(float4*)&out[(size_t)row * 64 + col] = o;
        }
    }
}

// ---------------- attention aggregation ----------------
__global__ __launch_bounds__(256) void k_agg(const int* __restrict__ off,
                                             const int* __restrict__ csr,
                                             const float* __restrict__ al,
                                             const float* __restrict__ ar,
                                             const float* __restrict__ h,
                                             const float* __restrict__ bias,
                                             float* __restrict__ out) {
    int lane = threadIdx.x & 63;
    int n = blockIdx.x * 4 + (threadIdx.x >> 6);
    int hd = lane >> 4;
    float4 ar4 = *(const float4*)&ar[n * 4];
    int beg = off[n], end = off[n + 1];
    float4 m4 = make_float4(-1e30f, -1e30f, -1e30f, -1e30f);
    for (int j = beg + lane; j < end; j += 64) {
        int s = csr[j];
        float4 a4 = *(const float4*)&al[s * 4];
        m4.x = fmaxf(m4.x, lrelu(a4.x + ar4.x));
        m4.y = fmaxf(m4.y, lrelu(a4.y + ar4.y));
        m4.z = fmaxf(m4.z, lrelu(a4.z + ar4.z));
        m4.w = fmaxf(m4.w, lrelu(a4.w + ar4.w));
    }
#pragma unroll
    for (int d = 32; d >= 1; d >>= 1) {
        m4.x = fmaxf(m4.x, __shfl_xor(m4.x, d, 64));
        m4.y = fmaxf(m4.y, __shfl_xor(m4.y, d, 64));
        m4.z = fmaxf(m4.z, __shfl_xor(m4.z, d, 64));
        m4.w = fmaxf(m4.w, __shfl_xor(m4.w, d, 64));
    }
    float mh = fsel(m4, hd);
    float arh = fsel(ar4, hd);
    float den = 0.f;
    float4 acc = make_float4(0.f, 0.f, 0.f, 0.f);
    int j = beg;
    for (; j + 2 <= end; j += 2) {
        int s0 = csr[j], s1 = csr[j + 1];
        float e0 = lrelu(al[s0 * 4 + hd] + arh);
        float e1 = lrelu(al[s1 * 4 + hd] + arh);
        float4 h0 = *(const float4*)&h[(size_t)s0 * 256 + lane * 4];
        float4 h1 = *(const float4*)&h[(size_t)s1 * 256 + lane * 4];
        float p0 = expf(e0 - mh), p1 = expf(e1 - mh);
        den += p0 + p1;
        acc.x += p0 * h0.x + p1 * h1.x;
        acc.y += p0 * h0.y + p1 * h1.y;
        acc.z += p0 * h0.z + p1 * h1.z;
        acc.w += p0 * h0.w + p1 * h1.w;
    }
    if (j < end) {
        int s0 = csr[j];
        float e0 = lrelu(al[s0 * 4 + hd] + arh);
        float p0 = expf(e0 - mh);
        float4 h0 = *(const float4*)&h[(size_t)s0 * 256 + lane * 4];
        den += p0;
        acc.x += p0 * h0.x; acc.y += p0 * h0.y;
        acc.z += p0 * h0.z; acc.w += p0 * h0.w;
    }
    float inv = 1.f / (den + 1e-16f);
    float4 ub = ((const float4*)bias)[lane];
    float4 o;
    o.x = acc.x * inv + ub.x;
    o.y = acc.y * inv + ub.y;
    o.z = acc.z * inv + ub.z;
    o.w = acc.w * inv + ub.w;
    *(float4*)&out[(size_t)n * 256 + lane * 4] = o;
}

// ---------------- LSTM ----------------
__global__ __launch_bounds__(256) void k_lstm(const float* __restrict__ xa,
                                              const float* __restrict__ xb,
                                              const float* __restrict__ WiT,
                                              const float* __restrict__ WhT,
                                              const float* __restrict__ bb,
                                              const float* __restrict__ h_in,
                                              const float* __restrict__ c_in,
                                              float* __restrict__ h_out,
                                              float* __restrict__ c_out,
                                              float* __restrict__ hs_out) {
    __shared__ float xs[4][192];
    int w = threadIdx.x >> 6, lane = threadIdx.x & 63;
    int row = blockIdx.x * 4 + w;
    xs[w][lane] = xa[(size_t)row * 64 + lane];
    if (xb) xs[w][64 + lane] = xb[(size_t)row * 64 + lane];
    xs[w][128 + lane] = h_in[(size_t)row * 64 + lane];
    __syncthreads();
    float ai = bb[lane];
    float af = bb[64 + lane];
    float ag = bb[128 + lane];
    float ao = bb[192 + lane];
    int D = xb ? 128 : 64;
    for (int k = 0; k < D; ++k) {
        float xv = xs[w][k];
        const float* wr = &WiT[k * 256];
        ai += xv * wr[lane];       af += xv * wr[64 + lane];
        ag += xv * wr[128 + lane]; ao += xv * wr[192 + lane];
    }
    for (int k = 0; k < 64; ++k) {
        float hv = xs[w][128 + k];
        const float* wr = &WhT[k * 256];
        ai += hv * wr[lane];       af += hv * wr[64 + lane];
        ag += hv * wr[128 + lane]; ao += hv * wr[192 + lane];
    }
    float iv = sigm(ai), fv = sigm(af), gv = tanhf(ag), ov = sigm(ao);
    float c = fv * c_in[(size_t)row * 64 + lane] + iv * gv;
    float hh = ov * tanhf(c);
    c_out[(size_t)row * 64 + lane] = c;
    h_out[(size_t)row * 64 + lane] = hh;
    if (hs_out) hs_out[(size_t)row * 64 + lane] = hh;
}

// ---------------- final FC ----------------
__global__ __launch_bounds__(256) void k_final(const float* __restrict__ h1,
                                               const float* __restrict__ h2,
                                               const float* __restrict__ w1,
                                               const float* __restrict__ b1,
                                               const float* __restrict__ w2,
                                               const float* __restrict__ b2,
                                               float* __restrict__ out) {
    __shared__ float zs[4][128];
    int w = threadIdx.x >> 6, lane = threadIdx.x & 63;
    int row = blockIdx.x * 4 + w;
    zs[w][lane] = h1[(size_t)row * 64 + lane];
    zs[w][64 + lane] = h2[(size_t)row * 64 + lane];
    __syncthreads();
    float acc = b1[lane];
    for (int k = 0; k < 128; ++k) acc += zs[w][k] * w1[k * 64 + lane];
    float r = fmaxf(acc, 0.f);
    float t0 = r * w2[lane * 2];
    float t1 = r * w2[lane * 2 + 1];
#pragma unroll
    for (int o = 32; o >= 1; o >>= 1) {
        t0 += __shfl_xor(t0, o, 64);
        t1 += __shfl_xor(t1, o, 64);
    }
    if (lane == 0) {
        out[row * 2]     = fmaxf(t0 + b2[0], 0.f);
        out[row * 2 + 1] = fmaxf(t1 + b2[1], 0.f);
    }
}

extern "C" void kernel_launch(void* const* d_in, const int* in_sizes, int n_in,
                              void* d_out, int out_size, void* d_ws, size_t ws_size,
                              hipStream_t stream) {
    const float* emb  = (const float*)d_in[0];
    const float* g1W  = (const float*)d_in[1];
    const float* g1as = (const float*)d_in[2];
    const float* g1ad = (const float*)d_in[3];
    const float* g1b  = (const float*)d_in[4];
    const float* l1W  = (const float*)d_in[5];
    const float* l1b  = (const float*)d_in[6];
    const float* g2W  = (const float*)d_in[7];
    const float* g2as = (const float*)d_in[8];
    const float* g2ad = (const float*)d_in[9];
    const float* g2b  = (const float*)d_in[10];
    const float* l2W  = (const float*)d_in[11];
    const float* l2b  = (const float*)d_in[12];
    const float* Wi1  = (const float*)d_in[13];
    const float* Wh1  = (const float*)d_in[14];
    const float* b1   = (const float*)d_in[15];
    const float* Wi2  = (const float*)d_in[16];
    const float* Wh2  = (const float*)d_in[17];
    const float* b2   = (const float*)d_in[18];
    const float* fc1W = (const float*)d_in[19];
    const float* fc1b = (const float*)d_in[20];
    const float* fc2W = (const float*)d_in[21];
    const float* fc2b = (const float*)d_in[22];
    const int* edges = (const int*)d_in[23];
    const int* clf   = (const int*)d_in[27];

    char* ws = (char*)d_ws;
    size_t woff = 0;
    auto alloc = [&](size_t bytes) -> void* {
        void* p = ws + woff;
        woff += (bytes + 255) & ~(size_t)255;
        return p;
    };
    int* csr_off  = (int*)alloc((size_t)TT * (NN + 1) * 4);
    int* csr_fil  = (int*)alloc((size_t)TT * NN * 4);
    int* csr_src  = (int*)alloc((size_t)TT * ET * 4);
    int* scan_sum = (int*)alloc((size_t)TT * NCH * 4);
    int* scan_bas = (int*)alloc((size_t)TT * NCH * 4);
    float* xbuf   = (float*)alloc((size_t)NN * 64 * 4);
    float* hbuf   = (float*)alloc((size_t)NN * 256 * 4);
    float* gat    = (float*)alloc((size_t)NN * 256 * 4);
    float* albuf  = (float*)alloc((size_t)NN * 4 * 4);
    float* arbuf  = (float*)alloc((size_t)NN * 4 * 4);
    float* seq    = (float*)alloc((size_t)2 * TT * NC * 64 * 4);
    float* hsb    = (float*)alloc((size_t)TT * NC * 64 * 4);
    float* h1s    = (float*)alloc((size_t)NC * 64 * 4);
    float* c1s    = (float*)alloc((size_t)NC * 64 * 4);
    float* h2s    = (float*)alloc((size_t)NC * 64 * 4);
    float* c2s    = (float*)alloc((size_t)NC * 64 * 4);
    float* WiT1   = (float*)alloc(128 * 256 * 4);
    float* WhT1   = (float*)alloc(64 * 256 * 4);
    float* WiT2   = (float*)alloc(64 * 256 * 4);
    float* WhT2   = (float*)alloc(64 * 256 * 4);

    // CSR build (per snapshot, includes self-loops)
    k_fill1<<<(TT * NN + 255) / 256, 256, 0, stream>>>(csr_fil, TT * NN);
    k_count<<<(TT * EE + 255) / 256, 256, 0, stream>>>(edges, csr_fil);
    k_scan1<<<TT * NCH, 256, 0, stream>>>(csr_fil, scan_sum);
    k_scan2<<<TT, 256, 0, stream>>>(scan_sum, scan_bas, csr_off);
    k_scan3<<<TT * NCH, 256, 0, stream>>>(csr_fil, scan_bas, csr_off);
    k_csrfill<<<(TT * ET + 255) / 256, 256, 0, stream>>>(edges, csr_fil, csr_src);

    // LSTM weight transposes (f32 [K][256] for coalesced gate loads)
    k_transpose<<<(256 * 128 + 255) / 256, 256, 0, stream>>>(Wi1, WiT1, 256, 128);
    k_transpose<<<(256 * 64 + 255) / 256, 256, 0, stream>>>(Wh1, WhT1, 256, 64);
    k_transpose<<<(256 * 64 + 255) / 256, 256, 0, stream>>>(Wi2, WiT2, 256, 64);
    k_transpose<<<(256 * 64 + 255) / 256, 256, 0, stream>>>(Wh2, WhT2, 256, 64);

    for (int s = 0; s < 2; ++s) {
        const float* gW  = s ? g2W : g1W;
        const float* gas = s ? g2as : g1as;
        const float* gad = s ? g2ad : g1ad;
        const float* gb  = s ? g2b : g1b;
        const float* lW  = s ? l2W : l1W;
        const float* lb  = s ? l2b : l1b;
        for (int t = 0; t < TT; ++t) {
            for (int l = 0; l < 2; ++l) {
                const float* xin = (l == 0) ? (emb + (size_t)t * NN * 64) : xbuf;
                k_gemm_h<<<(NN + 31) / 32, 256, 0, stream>>>(
                    xin, gW + (size_t)l * 64 * 256, gas + l * 256, gad + l * 256,
                    hbuf, albuf, arbuf);
                k_agg<<<NN / 4, 256, 0, stream>>>(
                    csr_off + (size_t)t * (NN + 1), csr_src + (size_t)t * ET,
                    albuf, arbuf, hbuf, gb + l * 256, gat);
                k_gemm_lin<<<(NN + 127) / 128, 256, 0, stream>>>(
                    gat, lW + (size_t)l * 256 * 64, lb + l * 64, xbuf);
            }
            k_gather<<<(NC * 16 + 255) / 256, 256, 0, stream>>>(
                xbuf, clf, seq + ((size_t)s * TT + t) * NC * 64);
        }
    }

    hipMemsetAsync(h1s, 0, (size_t)NC * 64 * 4, stream);
    hipMemsetAsync(c1s, 0, (size_t)NC * 64 * 4, stream);
    hipMemsetAsync(h2s, 0, (size_t)NC * 64 * 4, stream);
    hipMemsetAsync(c2s, 0, (size_t)NC * 64 * 4, stream);

    // LSTM1: time reversed (outs[::-1]) -> step st reads snapshot TT-1-st
    for (int st = 0; st < TT; ++st) {
        int tsn = TT - 1 - st;
        k_lstm<<<NC / 4, 256, 0, stream>>>(
            seq + (size_t)tsn * NC * 64,
            seq + (size_t)(TT + tsn) * NC * 64,
            WiT1, WhT1, b1, h1s, c1s, h1s, c1s,
            hsb + (size_t)st * NC * 64);
    }
    // LSTM2 over hs
    for (int st = 0; st < TT; ++st) {
        k_lstm<<<NC / 4, 256, 0, stream>>>(
            hsb + (size_t)st * NC * 64, nullptr,
            WiT2, WhT2, b2, h2s, c2s, h2s, c2s, nullptr);
    }
    k_final<<<NC / 4, 256, 0, stream>>>(h1s, h2s, fc1W, fc1b, fc2W, fc2b, (float*)d_out);
}

// Round 7
// 3694.906 us; speedup vs baseline: 1.2753x; 1.1563x over previous
//
#include <hip/hip_runtime.h>

#define NN 50000
#define TT 5
#define EE 500000
#define NC 8192
#define ET (EE + NN)
#define NCH 196   // ceil(NN/256)

typedef unsigned short u16;

__device__ __forceinline__ float lrelu(float x) { return x >= 0.f ? x : 0.2f * x; }
__device__ __forceinline__ float sigm(float x) { return 1.f / (1.f + expf(-x)); }
__device__ __forceinline__ float fsel(float4 v, int i) {
    float r = v.x; if (i == 1) r = v.y; if (i == 2) r = v.z; if (i == 3) r = v.w; return r;
}
__device__ __forceinline__ float fget(float4 v, int k) {
    return k == 0 ? v.x : k == 1 ? v.y : k == 2 ? v.z : v.w;
}
__device__ __forceinline__ float bf2f(u16 u) {
    union { unsigned int i; float f; } v; v.i = ((unsigned int)u) << 16; return v.f;
}
__device__ __forceinline__ u16 f2bf(float f) {
    unsigned int x = __float_as_uint(f);
    return (u16)((x + 0x7fffu + ((x >> 16) & 1u)) >> 16);
}
__device__ __forceinline__ ushort4 f4tobf(float4 v) {
    ushort4 u; u.x = f2bf(v.x); u.y = f2bf(v.y); u.z = f2bf(v.z); u.w = f2bf(v.w);
    return u;
}
__device__ __forceinline__ float4 bf4tof(ushort4 u) {
    return make_float4(bf2f(u.x), bf2f(u.y), bf2f(u.z), bf2f(u.w));
}

// ---------------- CSR build ----------------
__global__ void k_fill1(int* p, int n) {
    int i = blockIdx.x * 256 + threadIdx.x;
    if (i < n) p[i] = 1;
}

__global__ void k_count(const int* __restrict__ edges, int* __restrict__ cnt) {
    int i = blockIdx.x * 256 + threadIdx.x;
    if (i >= TT * EE) return;
    int t = i / EE, e = i % EE;
    int dst = edges[(size_t)t * 2 * EE + EE + e];
    atomicAdd(&cnt[t * NN + dst], 1);
}

// phase 1: per-chunk sums.  grid = TT*NCH
__global__ __launch_bounds__(256) void k_scan1(const int* __restrict__ cnt,
                                               int* __restrict__ sums) {
    int t = blockIdx.x / NCH, ch = blockIdx.x % NCH;
    int i = ch * 256 + threadIdx.x;
    int v = (i < NN) ? cnt[t * NN + i] : 0;
    __shared__ int s[256];
    s[threadIdx.x] = v;
    __syncthreads();
    for (int o = 128; o > 0; o >>= 1) {
        if (threadIdx.x < o) s[threadIdx.x] += s[threadIdx.x + o];
        __syncthreads();
    }
    if (threadIdx.x == 0) sums[t * NCH + ch] = s[0];
}

// phase 2: exclusive scan of NCH chunk sums per snapshot.  grid = TT
__global__ __launch_bounds__(256) void k_scan2(const int* __restrict__ sums,
                                               int* __restrict__ bases,
                                               int* __restrict__ off) {
    int t = blockIdx.x;
    __shared__ int s[256];
    int v = (threadIdx.x < NCH) ? sums[t * NCH + threadIdx.x] : 0;
    s[threadIdx.x] = v;
    __syncthreads();
    for (int o = 1; o < 256; o <<= 1) {
        int tv = (threadIdx.x >= o) ? s[threadIdx.x - o] : 0;
        __syncthreads();
        s[threadIdx.x] += tv;
        __syncthreads();
    }
    if (threadIdx.x < NCH) bases[t * NCH + threadIdx.x] = s[threadIdx.x] - v;
    if (threadIdx.x == 255) off[t * (NN + 1) + NN] = s[255];
}

// phase 3: local scan + base -> off & fill ptr.  grid = TT*NCH
__global__ __launch_bounds__(256) void k_scan3(int* __restrict__ cnt,
                                               const int* __restrict__ bases,
                                               int* __restrict__ off) {
    int t = blockIdx.x / NCH, ch = blockIdx.x % NCH;
    int i = ch * 256 + threadIdx.x;
    int v = (i < NN) ? cnt[t * NN + i] : 0;
    __shared__ int s[256];
    s[threadIdx.x] = v;
    __syncthreads();
    for (int o = 1; o < 256; o <<= 1) {
        int tv = (threadIdx.x >= o) ? s[threadIdx.x - o] : 0;
        __syncthreads();
        s[threadIdx.x] += tv;
        __syncthreads();
    }
    if (i < NN) {
        int excl = bases[t * NCH + ch] + s[threadIdx.x] - v;
        off[t * (NN + 1) + i] = excl;
        cnt[t * NN + i] = excl;  // becomes fill pointer
    }
}

__global__ void k_csrfill(const int* __restrict__ edges, int* __restrict__ fil,
                          int* __restrict__ csr) {
    int i = blockIdx.x * 256 + threadIdx.x;
    if (i >= TT * ET) return;
    int t = i / ET, r = i % ET;
    int src, dst;
    if (r < EE) {
        src = edges[(size_t)t * 2 * EE + r];
        dst = edges[(size_t)t * 2 * EE + EE + r];
    } else {
        src = dst = r - EE;
    }
    int pos = atomicAdd(&fil[t * NN + dst], 1);
    csr[(size_t)t * ET + pos] = src;
}

// ---------------- misc ----------------
__global__ void k_transpose(const float* __restrict__ src, float* __restrict__ dst,
                            int R, int C) {
    int i = blockIdx.x * 256 + threadIdx.x;
    if (i >= R * C) return;
    int r = i / C, c = i % C;
    dst[c * R + r] = src[i];
}

__global__ void k_gather(const float* __restrict__ x, const int* __restrict__ clf,
                         float* __restrict__ dst) {
    int i = blockIdx.x * 256 + threadIdx.x;
    if (i >= NC * 16) return;
    int row = i >> 4, c4 = i & 15;
    int node = clf[row];
    ((float4*)dst)[row * 16 + c4] = ((const float4*)x)[(size_t)node * 16 + c4];
}

// ---------------- GEMM + fused attention coefficients ----------------
// h[N,256](bf16) = x[N,64] @ W[64,256];  al/ar[N,4] = (h * a_s/a_d).sum per head (f32-exact)
__global__ __launch_bounds__(256) void k_gemm_h(const float* __restrict__ x,
                                                const float* __restrict__ W,
                                                const float* __restrict__ as_,
                                                const float* __restrict__ ad_,
                                                u16* __restrict__ h,
                                                float* __restrict__ al,
                                                float* __restrict__ ar) {
    __shared__ float Wl[64 * 256];
    for (int i = threadIdx.x; i < 4096; i += 256)
        *(float4*)&Wl[i * 4] = ((const float4*)W)[i];
    __syncthreads();
    int lane = threadIdx.x & 63;
    int wg = threadIdx.x >> 6;
    int col = lane * 4;
    int base = blockIdx.x * 32 + wg * 8;
    float4 ua = ((const float4*)as_)[lane];
    float4 ud = ((const float4*)ad_)[lane];
    float4 acc[8];
#pragma unroll
    for (int r = 0; r < 8; ++r) acc[r] = make_float4(0.f, 0.f, 0.f, 0.f);
    for (int k = 0; k < 64; k += 4) {
        float4 xq[8];
#pragma unroll
        for (int r = 0; r < 8; ++r) {
            int row = base + r; if (row > NN - 1) row = NN - 1;
            xq[r] = *(const float4*)&x[(size_t)row * 64 + k];
        }
#pragma unroll
        for (int kk = 0; kk < 4; ++kk) {
            float4 w4 = *(const float4*)&Wl[(k + kk) * 256 + col];
#pragma unroll
            for (int r = 0; r < 8; ++r) {
                float xv = fget(xq[r], kk);
                acc[r].x += xv * w4.x; acc[r].y += xv * w4.y;
                acc[r].z += xv * w4.z; acc[r].w += xv * w4.w;
            }
        }
    }
#pragma unroll
    for (int r = 0; r < 8; ++r) {
        int row = base + r;
        if (row < NN) *(ushort4*)&h[(size_t)row * 256 + col] = f4tobf(acc[r]);
        // fused al/ar from pre-rounding f32 acc
        float ps = acc[r].x * ua.x + acc[r].y * ua.y + acc[r].z * ua.z + acc[r].w * ua.w;
        float pd = acc[r].x * ud.x + acc[r].y * ud.y + acc[r].z * ud.z + acc[r].w * ud.w;
#pragma unroll
        for (int o = 1; o < 16; o <<= 1) {
            ps += __shfl_xor(ps, o, 64);
            pd += __shfl_xor(pd, o, 64);
        }
        if (row < NN && (lane & 15) == 0) {
            al[row * 4 + (lane >> 4)] = ps;
            ar[row * 4 + (lane >> 4)] = pd;
        }
    }
}

// out[N,64] = relu(x[N,256] @ W[256,64] + b)
__global__ __launch_bounds__(256) void k_gemm_lin(const float* __restrict__ x,
                                                  const float* __restrict__ W,
                                                  const float* __restrict__ b,
                                                  float* __restrict__ out) {
    __shared__ float Wl[256 * 64];
    for (int i = threadIdx.x; i < 4096; i += 256)
        *(float4*)&Wl[i * 4] = ((const float4*)W)[i];
    __syncthreads();
    int cg = threadIdx.x & 15;
    int wg = threadIdx.x >> 4;
    int col = cg * 4;
    int base = blockIdx.x * 128 + wg * 8;
    float4 acc[8];
#pragma unroll
    for (int r = 0; r < 8; ++r) acc[r] = make_float4(0.f, 0.f, 0.f, 0.f);
    for (int k = 0; k < 256; k += 4) {
        float4 xq[8];
#pragma unroll
        for (int r = 0; r < 8; ++r) {
            int row = base + r; if (row > NN - 1) row = NN - 1;
            xq[r] = *(const float4*)&x[(size_t)row * 256 + k];
        }
#pragma unroll
        for (int kk = 0; kk < 4; ++kk) {
            float4 w4 = *(const float4*)&Wl[(k + kk) * 64 + col];
#pragma unroll
            for (int r = 0; r < 8; ++r) {
                float xv = fget(xq[r], kk);
                acc[r].x += xv * w4.x; acc[r].y += xv * w4.y;
                acc[r].z += xv * w4.z; acc[r].w += xv * w4.w;
            }
        }
    }
    float4 b4 = ((const float4*)b)[cg];
#pragma unroll
    for (int r = 0; r < 8; ++r) {
        int row = base + r;
        if (row < NN) {
            float4 o;
            o.x = fmaxf(acc[r].x + b4.x, 0.f);
            o.y = fmaxf(acc[r].y + b4.y, 0.f);
            o.z = fmaxf(acc[r].z + b4.z, 0.f);
            o.w = fmaxf(acc[r].w + b4.w, 0.f);
            *(float4*)&out[(size_t)row * 64 + col] = o;
        }
    }
}

// ---------------- attention aggregation (h in bf16) ----------------
__global__ __launch_bounds__(256) void k_agg(const int* __restrict__ off,
                                             const int* __restrict__ csr,
                                             const float* __restrict__ al,
                                             const float* __restrict__ ar,
                                             const u16* __restrict__ h,
                                             const float* __restrict__ bias,
                                             float* __restrict__ out) {
    int lane = threadIdx.x & 63;
    int n = blockIdx.x * 4 + (threadIdx.x >> 6);
    int hd = lane >> 4;
    float4 ar4 = *(const float4*)&ar[n * 4];
    int beg = off[n], end = off[n + 1];
    float4 m4 = make_float4(-1e30f, -1e30f, -1e30f, -1e30f);
    for (int j = beg + lane; j < end; j += 64) {
        int s = csr[j];
        float4 a4 = *(const float4*)&al[s * 4];
        m4.x = fmaxf(m4.x, lrelu(a4.x + ar4.x));
        m4.y = fmaxf(m4.y, lrelu(a4.y + ar4.y));
        m4.z = fmaxf(m4.z, lrelu(a4.z + ar4.z));
        m4.w = fmaxf(m4.w, lrelu(a4.w + ar4.w));
    }
#pragma unroll
    for (int d = 32; d >= 1; d >>= 1) {
        m4.x = fmaxf(m4.x, __shfl_xor(m4.x, d, 64));
        m4.y = fmaxf(m4.y, __shfl_xor(m4.y, d, 64));
        m4.z = fmaxf(m4.z, __shfl_xor(m4.z, d, 64));
        m4.w = fmaxf(m4.w, __shfl_xor(m4.w, d, 64));
    }
    float mh = fsel(m4, hd);
    float arh = fsel(ar4, hd);
    float den = 0.f;
    float4 acc = make_float4(0.f, 0.f, 0.f, 0.f);
    int j = beg;
    for (; j + 2 <= end; j += 2) {
        int s0 = csr[j], s1 = csr[j + 1];
        float e0 = lrelu(al[s0 * 4 + hd] + arh);
        float e1 = lrelu(al[s1 * 4 + hd] + arh);
        ushort4 u0 = *(const ushort4*)&h[(size_t)s0 * 256 + lane * 4];
        ushort4 u1 = *(const ushort4*)&h[(size_t)s1 * 256 + lane * 4];
        float p0 = expf(e0 - mh), p1 = expf(e1 - mh);
        float4 h0 = bf4tof(u0), h1 = bf4tof(u1);
        den += p0 + p1;
        acc.x += p0 * h0.x + p1 * h1.x;
        acc.y += p0 * h0.y + p1 * h1.y;
        acc.z += p0 * h0.z + p1 * h1.z;
        acc.w += p0 * h0.w + p1 * h1.w;
    }
    if (j < end) {
        int s0 = csr[j];
        float e0 = lrelu(al[s0 * 4 + hd] + arh);
        float p0 = expf(e0 - mh);
        float4 h0 = bf4tof(*(const ushort4*)&h[(size_t)s0 * 256 + lane * 4]);
        den += p0;
        acc.x += p0 * h0.x; acc.y += p0 * h0.y;
        acc.z += p0 * h0.z; acc.w += p0 * h0.w;
    }
    float inv = 1.f / (den + 1e-16f);
    float4 ub = ((const float4*)bias)[lane];
    float4 o;
    o.x = acc.x * inv + ub.x;
    o.y = acc.y * inv + ub.y;
    o.z = acc.z * inv + ub.z;
    o.w = acc.w * inv + ub.w;
    *(float4*)&out[(size_t)n * 256 + lane * 4] = o;
}

// ---------------- LSTM ----------------
__global__ __launch_bounds__(256) void k_lstm(const float* __restrict__ xa,
                                              const float* __restrict__ xb,
                                              const float* __restrict__ WiT,
                                              const float* __restrict__ WhT,
                                              const float* __restrict__ bb,
                                              const float* __restrict__ h_in,
                                              const float* __restrict__ c_in,
                                              float* __restrict__ h_out,
                                              float* __restrict__ c_out,
                                              float* __restrict__ hs_out) {
    __shared__ float xs[4][192];
    int w = threadIdx.x >> 6, lane = threadIdx.x & 63;
    int row = blockIdx.x * 4 + w;
    xs[w][lane] = xa[(size_t)row * 64 + lane];
    if (xb) xs[w][64 + lane] = xb[(size_t)row * 64 + lane];
    xs[w][128 + lane] = h_in[(size_t)row * 64 + lane];
    __syncthreads();
    float ai = bb[lane];
    float af = bb[64 + lane];
    float ag = bb[128 + lane];
    float ao = bb[192 + lane];
    int D = xb ? 128 : 64;
    for (int k = 0; k < D; ++k) {
        float xv = xs[w][k];
        const float* wr = &WiT[k * 256];
        ai += xv * wr[lane];       af += xv * wr[64 + lane];
        ag += xv * wr[128 + lane]; ao += xv * wr[192 + lane];
    }
    for (int k = 0; k < 64; ++k) {
        float hv = xs[w][128 + k];
        const float* wr = &WhT[k * 256];
        ai += hv * wr[lane];       af += hv * wr[64 + lane];
        ag += hv * wr[128 + lane]; ao += hv * wr[192 + lane];
    }
    float iv = sigm(ai), fv = sigm(af), gv = tanhf(ag), ov = sigm(ao);
    float c = fv * c_in[(size_t)row * 64 + lane] + iv * gv;
    float hh = ov * tanhf(c);
    c_out[(size_t)row * 64 + lane] = c;
    h_out[(size_t)row * 64 + lane] = hh;
    if (hs_out) hs_out[(size_t)row * 64 + lane] = hh;
}

// ---------------- final FC ----------------
__global__ __launch_bounds__(256) void k_final(const float* __restrict__ h1,
                                               const float* __restrict__ h2,
                                               const float* __restrict__ w1,
                                               const float* __restrict__ b1,
                                               const float* __restrict__ w2,
                                               const float* __restrict__ b2,
                                               float* __restrict__ out) {
    __shared__ float zs[4][128];
    int w = threadIdx.x >> 6, lane = threadIdx.x & 63;
    int row = blockIdx.x * 4 + w;
    zs[w][lane] = h1[(size_t)row * 64 + lane];
    zs[w][64 + lane] = h2[(size_t)row * 64 + lane];
    __syncthreads();
    float acc = b1[lane];
    for (int k = 0; k < 128; ++k) acc += zs[w][k] * w1[k * 64 + lane];
    float r = fmaxf(acc, 0.f);
    float t0 = r * w2[lane * 2];
    float t1 = r * w2[lane * 2 + 1];
#pragma unroll
    for (int o = 32; o >= 1; o >>= 1) {
        t0 += __shfl_xor(t0, o, 64);
        t1 += __shfl_xor(t1, o, 64);
    }
    if (lane == 0) {
        out[row * 2]     = fmaxf(t0 + b2[0], 0.f);
        out[row * 2 + 1] = fmaxf(t1 + b2[1], 0.f);
    }
}

extern "C" void kernel_launch(void* const* d_in, const int* in_sizes, int n_in,
                              void* d_out, int out_size, void* d_ws, size_t ws_size,
                              hipStream_t stream) {
    const float* emb  = (const float*)d_in[0];
    const float* g1W  = (const float*)d_in[1];
    const float* g1as = (const float*)d_in[2];
    const float* g1ad = (const float*)d_in[3];
    const float* g1b  = (const float*)d_in[4];
    const float* l1W  = (const float*)d_in[5];
    const float* l1b  = (const float*)d_in[6];
    const float* g2W  = (const float*)d_in[7];
    const float* g2as = (const float*)d_in[8];
    const float* g2ad = (const float*)d_in[9];
    const float* g2b  = (const float*)d_in[10];
    const float* l2W  = (const float*)d_in[11];
    const float* l2b  = (const float*)d_in[12];
    const float* Wi1  = (const float*)d_in[13];
    const float* Wh1  = (const float*)d_in[14];
    const float* b1   = (const float*)d_in[15];
    const float* Wi2  = (const float*)d_in[16];
    const float* Wh2  = (const float*)d_in[17];
    const float* b2   = (const float*)d_in[18];
    const float* fc1W = (const float*)d_in[19];
    const float* fc1b = (const float*)d_in[20];
    const float* fc2W = (const float*)d_in[21];
    const float* fc2b = (const float*)d_in[22];
    const int* edges = (const int*)d_in[23];
    const int* clf   = (const int*)d_in[27];

    char* ws = (char*)d_ws;
    size_t woff = 0;
    auto alloc = [&](size_t bytes) -> void* {
        void* p = ws + woff;
        woff += (bytes + 255) & ~(size_t)255;
        return p;
    };
    int* csr_off  = (int*)alloc((size_t)TT * (NN + 1) * 4);
    int* csr_fil  = (int*)alloc((size_t)TT * NN * 4);
    int* csr_src  = (int*)alloc((size_t)TT * ET * 4);
    int* scan_sum = (int*)alloc((size_t)TT * NCH * 4);
    int* scan_bas = (int*)alloc((size_t)TT * NCH * 4);
    float* xbuf   = (float*)alloc((size_t)NN * 64 * 4);
    u16* hbuf     = (u16*)alloc((size_t)NN * 256 * 2);
    float* gat    = (float*)alloc((size_t)NN * 256 * 4);
    float* albuf  = (float*)alloc((size_t)NN * 4 * 4);
    float* arbuf  = (float*)alloc((size_t)NN * 4 * 4);
    float* seq    = (float*)alloc((size_t)2 * TT * NC * 64 * 4);
    float* hsb    = (float*)alloc((size_t)TT * NC * 64 * 4);
    float* h1s    = (float*)alloc((size_t)NC * 64 * 4);
    float* c1s    = (float*)alloc((size_t)NC * 64 * 4);
    float* h2s    = (float*)alloc((size_t)NC * 64 * 4);
    float* c2s    = (float*)alloc((size_t)NC * 64 * 4);
    float* WiT1   = (float*)alloc(128 * 256 * 4);
    float* WhT1   = (float*)alloc(64 * 256 * 4);
    float* WiT2   = (float*)alloc(64 * 256 * 4);
    float* WhT2   = (float*)alloc(64 * 256 * 4);

    // CSR build (per snapshot, includes self-loops)
    k_fill1<<<(TT * NN + 255) / 256, 256, 0, stream>>>(csr_fil, TT * NN);
    k_count<<<(TT * EE + 255) / 256, 256, 0, stream>>>(edges, csr_fil);
    k_scan1<<<TT * NCH, 256, 0, stream>>>(csr_fil, scan_sum);
    k_scan2<<<TT, 256, 0, stream>>>(scan_sum, scan_bas, csr_off);
    k_scan3<<<TT * NCH, 256, 0, stream>>>(csr_fil, scan_bas, csr_off);
    k_csrfill<<<(TT * ET + 255) / 256, 256, 0, stream>>>(edges, csr_fil, csr_src);

    // LSTM weight transposes (f32 [K][256] for coalesced gate loads)
    k_transpose<<<(256 * 128 + 255) / 256, 256, 0, stream>>>(Wi1, WiT1, 256, 128);
    k_transpose<<<(256 * 64 + 255) / 256, 256, 0, stream>>>(Wh1, WhT1, 256, 64);
    k_transpose<<<(256 * 64 + 255) / 256, 256, 0, stream>>>(Wi2, WiT2, 256, 64);
    k_transpose<<<(256 * 64 + 255) / 256, 256, 0, stream>>>(Wh2, WhT2, 256, 64);

    for (int s = 0; s < 2; ++s) {
        const float* gW  = s ? g2W : g1W;
        const float* gas = s ? g2as : g1as;
        const float* gad = s ? g2ad : g1ad;
        const float* gb  = s ? g2b : g1b;
        const float* lW  = s ? l2W : l1W;
        const float* lb  = s ? l2b : l1b;
        for (int t = 0; t < TT; ++t) {
            for (int l = 0; l < 2; ++l) {
                const float* xin = (l == 0) ? (emb + (size_t)t * NN * 64) : xbuf;
                k_gemm_h<<<(NN + 31) / 32, 256, 0, stream>>>(
                    xin, gW + (size_t)l * 64 * 256, gas + l * 256, gad + l * 256,
                    hbuf, albuf, arbuf);
                k_agg<<<NN / 4, 256, 0, stream>>>(
                    csr_off + (size_t)t * (NN + 1), csr_src + (size_t)t * ET,
                    albuf, arbuf, hbuf, gb + l * 256, gat);
                k_gemm_lin<<<(NN + 127) / 128, 256, 0, stream>>>(
                    gat, lW + (size_t)l * 256 * 64, lb + l * 64, xbuf);
            }
            k_gather<<<(NC * 16 + 255) / 256, 256, 0, stream>>>(
                xbuf, clf, seq + ((size_t)s * TT + t) * NC * 64);
        }
    }

    hipMemsetAsync(h1s, 0, (size_t)NC * 64 * 4, stream);
    hipMemsetAsync(c1s, 0, (size_t)NC * 64 * 4, stream);
    hipMemsetAsync(h2s, 0, (size_t)NC * 64 * 4, stream);
    hipMemsetAsync(c2s, 0, (size_t)NC * 64 * 4, stream);

    // LSTM1: time reversed (outs[::-1]) -> step st reads snapshot TT-1-st
    for (int st = 0; st < TT; ++st) {
        int tsn = TT - 1 - st;
        k_lstm<<<NC / 4, 256, 0, stream>>>(
            seq + (size_t)tsn * NC * 64,
            seq + (size_t)(TT + tsn) * NC * 64,
            WiT1, WhT1, b1, h1s, c1s, h1s, c1s,
            hsb + (size_t)st * NC * 64);
    }
    // LSTM2 over hs
    for (int st = 0; st < TT; ++st) {
        k_lstm<<<NC / 4, 256, 0, stream>>>(
            hsb + (size_t)st * NC * 64, nullptr,
            WiT2, WhT2, b2, h2s, c2s, h2s, c2s, nullptr);
    }
    k_final<<<NC / 4, 256, 0, stream>>>(h1s, h2s, fc1W, fc1b, fc2W, fc2b, (float*)d_out);
}

// Round 9
// 3466.925 us; speedup vs baseline: 1.3591x; 1.0658x over previous
//
#include <hip/hip_runtime.h>

#define NN 50000
#define TT 5
#define EE 500000
#define NC 8192
#define ET (EE + NN)
#define NCH 196   // ceil(NN/256)

typedef unsigned short u16;

__device__ __forceinline__ float lrelu(float x) { return x >= 0.f ? x : 0.2f * x; }
__device__ __forceinline__ float sigm(float x) { return 1.f / (1.f + expf(-x)); }
__device__ __forceinline__ float fget(float4 v, int k) {
    return k == 0 ? v.x : k == 1 ? v.y : k == 2 ? v.z : v.w;
}
__device__ __forceinline__ float bf2f(u16 u) {
    union { unsigned int i; float f; } v; v.i = ((unsigned int)u) << 16; return v.f;
}
__device__ __forceinline__ u16 f2bf(float f) {
    unsigned int x = __float_as_uint(f);
    return (u16)((x + 0x7fffu + ((x >> 16) & 1u)) >> 16);
}
__device__ __forceinline__ ushort4 f4tobf(float4 v) {
    ushort4 u; u.x = f2bf(v.x); u.y = f2bf(v.y); u.z = f2bf(v.z); u.w = f2bf(v.w);
    return u;
}
__device__ __forceinline__ float4 bf4tof(ushort4 u) {
    return make_float4(bf2f(u.x), bf2f(u.y), bf2f(u.z), bf2f(u.w));
}

// ---------------- CSR build ----------------
__global__ void k_fill1(int* p, int n) {
    int i = blockIdx.x * 256 + threadIdx.x;
    if (i < n) p[i] = 1;
}

__global__ void k_count(const int* __restrict__ edges, int* __restrict__ cnt) {
    int i = blockIdx.x * 256 + threadIdx.x;
    if (i >= TT * EE) return;
    int t = i / EE, e = i % EE;
    int dst = edges[(size_t)t * 2 * EE + EE + e];
    atomicAdd(&cnt[t * NN + dst], 1);
}

// phase 1: per-chunk sums.  grid = TT*NCH
__global__ __launch_bounds__(256) void k_scan1(const int* __restrict__ cnt,
                                               int* __restrict__ sums) {
    int t = blockIdx.x / NCH, ch = blockIdx.x % NCH;
    int i = ch * 256 + threadIdx.x;
    int v = (i < NN) ? cnt[t * NN + i] : 0;
    __shared__ int s[256];
    s[threadIdx.x] = v;
    __syncthreads();
    for (int o = 128; o > 0; o >>= 1) {
        if (threadIdx.x < o) s[threadIdx.x] += s[threadIdx.x + o];
        __syncthreads();
    }
    if (threadIdx.x == 0) sums[t * NCH + ch] = s[0];
}

// phase 2: exclusive scan of NCH chunk sums per snapshot.  grid = TT
__global__ __launch_bounds__(256) void k_scan2(const int* __restrict__ sums,
                                               int* __restrict__ bases,
                                               int* __restrict__ off) {
    int t = blockIdx.x;
    __shared__ int s[256];
    int v = (threadIdx.x < NCH) ? sums[t * NCH + threadIdx.x] : 0;
    s[threadIdx.x] = v;
    __syncthreads();
    for (int o = 1; o < 256; o <<= 1) {
        int tv = (threadIdx.x >= o) ? s[threadIdx.x - o] : 0;
        __syncthreads();
        s[threadIdx.x] += tv;
        __syncthreads();
    }
    if (threadIdx.x < NCH) bases[t * NCH + threadIdx.x] = s[threadIdx.x] - v;
    if (threadIdx.x == 255) off[t * (NN + 1) + NN] = s[255];
}

// phase 3: local scan + base -> off & fill ptr.  grid = TT*NCH
__global__ __launch_bounds__(256) void k_scan3(int* __restrict__ cnt,
                                               const int* __restrict__ bases,
                                               int* __restrict__ off) {
    int t = blockIdx.x / NCH, ch = blockIdx.x % NCH;
    int i = ch * 256 + threadIdx.x;
    int v = (i < NN) ? cnt[t * NN + i] : 0;
    __shared__ int s[256];
    s[threadIdx.x] = v;
    __syncthreads();
    for (int o = 1; o < 256; o <<= 1) {
        int tv = (threadIdx.x >= o) ? s[threadIdx.x - o] : 0;
        __syncthreads();
        s[threadIdx.x] += tv;
        __syncthreads();
    }
    if (i < NN) {
        int excl = bases[t * NCH + ch] + s[threadIdx.x] - v;
        off[t * (NN + 1) + i] = excl;
        cnt[t * NN + i] = excl;  // becomes fill pointer
    }
}

__global__ void k_csrfill(const int* __restrict__ edges, int* __restrict__ fil,
                          int* __restrict__ csr) {
    int i = blockIdx.x * 256 + threadIdx.x;
    if (i >= TT * ET) return;
    int t = i / ET, r = i % ET;
    int src, dst;
    if (r < EE) {
        src = edges[(size_t)t * 2 * EE + r];
        dst = edges[(size_t)t * 2 * EE + EE + r];
    } else {
        src = dst = r - EE;
    }
    int pos = atomicAdd(&fil[t * NN + dst], 1);
    csr[(size_t)t * ET + pos] = src;
}

// ---------------- misc ----------------
__global__ void k_transpose(const float* __restrict__ src, float* __restrict__ dst,
                            int R, int C) {
    int i = blockIdx.x * 256 + threadIdx.x;
    if (i >= R * C) return;
    int r = i / C, c = i % C;
    dst[c * R + r] = src[i];
}

__global__ void k_gather(const float* __restrict__ x, const int* __restrict__ clf,
                         float* __restrict__ dst) {
    int i = blockIdx.x * 256 + threadIdx.x;
    if (i >= NC * 16) return;
    int row = i >> 4, c4 = i & 15;
    int node = clf[row];
    ((float4*)dst)[row * 16 + c4] = ((const float4*)x)[(size_t)node * 16 + c4];
}

// ---------------- GEMM + fused attention coefficients ----------------
// h[N,256](bf16) = x[N,64] @ W[64,256];  al/ar[N,4] = (h * a_s/a_d).sum per head (f32-exact)
__global__ __launch_bounds__(256) void k_gemm_h(const float* __restrict__ x,
                                                const float* __restrict__ W,
                                                const float* __restrict__ as_,
                                                const float* __restrict__ ad_,
                                                u16* __restrict__ h,
                                                float* __restrict__ al,
                                                float* __restrict__ ar) {
    __shared__ float Wl[64 * 256];
    for (int i = threadIdx.x; i < 4096; i += 256)
        *(float4*)&Wl[i * 4] = ((const float4*)W)[i];
    __syncthreads();
    int lane = threadIdx.x & 63;
    int wg = threadIdx.x >> 6;
    int col = lane * 4;
    int base = blockIdx.x * 32 + wg * 8;
    float4 ua = ((const float4*)as_)[lane];
    float4 ud = ((const float4*)ad_)[lane];
    float4 acc[8];
#pragma unroll
    for (int r = 0; r < 8; ++r) acc[r] = make_float4(0.f, 0.f, 0.f, 0.f);
    for (int k = 0; k < 64; k += 4) {
        float4 xq[8];
#pragma unroll
        for (int r = 0; r < 8; ++r) {
            int row = base + r; if (row > NN - 1) row = NN - 1;
            xq[r] = *(const float4*)&x[(size_t)row * 64 + k];
        }
#pragma unroll
        for (int kk = 0; kk < 4; ++kk) {
            float4 w4 = *(const float4*)&Wl[(k + kk) * 256 + col];
#pragma unroll
            for (int r = 0; r < 8; ++r) {
                float xv = fget(xq[r], kk);
                acc[r].x += xv * w4.x; acc[r].y += xv * w4.y;
                acc[r].z += xv * w4.z; acc[r].w += xv * w4.w;
            }
        }
    }
#pragma unroll
    for (int r = 0; r < 8; ++r) {
        int row = base + r;
        if (row < NN) *(ushort4*)&h[(size_t)row * 256 + col] = f4tobf(acc[r]);
        // fused al/ar from pre-rounding f32 acc
        float ps = acc[r].x * ua.x + acc[r].y * ua.y + acc[r].z * ua.z + acc[r].w * ua.w;
        float pd = acc[r].x * ud.x + acc[r].y * ud.y + acc[r].z * ud.z + acc[r].w * ud.w;
#pragma unroll
        for (int o = 1; o < 16; o <<= 1) {
            ps += __shfl_xor(ps, o, 64);
            pd += __shfl_xor(pd, o, 64);
        }
        if (row < NN && (lane & 15) == 0) {
            al[row * 4 + (lane >> 4)] = ps;
            ar[row * 4 + (lane >> 4)] = pd;
        }
    }
}

// out[N,64] = relu(x[N,256] @ W[256,64] + b)
__global__ __launch_bounds__(256) void k_gemm_lin(const float* __restrict__ x,
                                                  const float* __restrict__ W,
                                                  const float* __restrict__ b,
                                                  float* __restrict__ out) {
    __shared__ float Wl[256 * 64];
    for (int i = threadIdx.x; i < 4096; i += 256)
        *(float4*)&Wl[i * 4] = ((const float4*)W)[i];
    __syncthreads();
    int cg = threadIdx.x & 15;
    int wg = threadIdx.x >> 4;
    int col = cg * 4;
    int base = blockIdx.x * 128 + wg * 8;
    float4 acc[8];
#pragma unroll
    for (int r = 0; r < 8; ++r) acc[r] = make_float4(0.f, 0.f, 0.f, 0.f);
    for (int k = 0; k < 256; k += 4) {
        float4 xq[8];
#pragma unroll
        for (int r = 0; r < 8; ++r) {
            int row = base + r; if (row > NN - 1) row = NN - 1;
            xq[r] = *(const float4*)&x[(size_t)row * 256 + k];
        }
#pragma unroll
        for (int kk = 0; kk < 4; ++kk) {
            float4 w4 = *(const float4*)&Wl[(k + kk) * 64 + col];
#pragma unroll
            for (int r = 0; r < 8; ++r) {
                float xv = fget(xq[r], kk);
                acc[r].x += xv * w4.x; acc[r].y += xv * w4.y;
                acc[r].z += xv * w4.z; acc[r].w += xv * w4.w;
            }
        }
    }
    float4 b4 = ((const float4*)b)[cg];
#pragma unroll
    for (int r = 0; r < 8; ++r) {
        int row = base + r;
        if (row < NN) {
            float4 o;
            o.x = fmaxf(acc[r].x + b4.x, 0.f);
            o.y = fmaxf(acc[r].y + b4.y, 0.f);
            o.z = fmaxf(acc[r].z + b4.z, 0.f);
            o.w = fmaxf(acc[r].w + b4.w, 0.f);
            *(float4*)&out[(size_t)row * 64 + col] = o;
        }
    }
}

// ---------------- attention aggregation (h in bf16, no-max softmax, 4-way MLP) ----
__global__ __launch_bounds__(256) void k_agg(const int* __restrict__ off,
                                             const int* __restrict__ csr,
                                             const float* __restrict__ al,
                                             const float* __restrict__ ar,
                                             const u16* __restrict__ h,
                                             const float* __restrict__ bias,
                                             float* __restrict__ out) {
    int lane = threadIdx.x & 63;
    int n = blockIdx.x * 4 + (threadIdx.x >> 6);
    int hd = lane >> 4;
    // exp(e-m)/sum == exp(e)/sum exactly; e bounded ~[-5,5] so exp is safe in f32
    float arh = ar[n * 4 + hd];
    int beg = off[n], end = off[n + 1];
    float den = 0.f;
    float4 acc = make_float4(0.f, 0.f, 0.f, 0.f);
    int j = beg;
    for (; j + 4 <= end; j += 4) {
        int s0 = csr[j], s1 = csr[j + 1], s2 = csr[j + 2], s3 = csr[j + 3];
        float a0 = al[s0 * 4 + hd];
        float a1 = al[s1 * 4 + hd];
        float a2 = al[s2 * 4 + hd];
        float a3 = al[s3 * 4 + hd];
        ushort4 u0 = *(const ushort4*)&h[(size_t)s0 * 256 + lane * 4];
        ushort4 u1 = *(const ushort4*)&h[(size_t)s1 * 256 + lane * 4];
        ushort4 u2 = *(const ushort4*)&h[(size_t)s2 * 256 + lane * 4];
        ushort4 u3 = *(const ushort4*)&h[(size_t)s3 * 256 + lane * 4];
        float p0 = expf(lrelu(a0 + arh));
        float p1 = expf(lrelu(a1 + arh));
        float p2 = expf(lrelu(a2 + arh));
        float p3 = expf(lrelu(a3 + arh));
        float4 h0 = bf4tof(u0), h1 = bf4tof(u1), h2 = bf4tof(u2), h3 = bf4tof(u3);
        den += (p0 + p1) + (p2 + p3);
        acc.x += p0 * h0.x + p1 * h1.x + p2 * h2.x + p3 * h3.x;
        acc.y += p0 * h0.y + p1 * h1.y + p2 * h2.y + p3 * h3.y;
        acc.z += p0 * h0.z + p1 * h1.z + p2 * h2.z + p3 * h3.z;
        acc.w += p0 * h0.w + p1 * h1.w + p2 * h2.w + p3 * h3.w;
    }
    for (; j < end; ++j) {
        int s0 = csr[j];
        float p0 = expf(lrelu(al[s0 * 4 + hd] + arh));
        float4 h0 = bf4tof(*(const ushort4*)&h[(size_t)s0 * 256 + lane * 4]);
        den += p0;
        acc.x += p0 * h0.x; acc.y += p0 * h0.y;
        acc.z += p0 * h0.z; acc.w += p0 * h0.w;
    }
    float inv = 1.f / (den + 1e-16f);
    float4 ub = ((const float4*)bias)[lane];
    float4 o;
    o.x = acc.x * inv + ub.x;
    o.y = acc.y * inv + ub.y;
    o.z = acc.z * inv + ub.z;
    o.w = acc.w * inv + ub.w;
    *(float4*)&out[(size_t)n * 256 + lane * 4] = o;
}

// ---------------- LSTM ----------------
__global__ __launch_bounds__(256) void k_lstm(const float* __restrict__ xa,
                                              const float* __restrict__ xb,
                                              const float* __restrict__ WiT,
                                              const float* __restrict__ WhT,
                                              const float* __restrict__ bb,
                                              const float* __restrict__ h_in,
                                              const float* __restrict__ c_in,
                                              float* __restrict__ h_out,
                                              float* __restrict__ c_out,
                                              float* __restrict__ hs_out) {
    __shared__ float xs[4][192];
    int w = threadIdx.x >> 6, lane = threadIdx.x & 63;
    int row = blockIdx.x * 4 + w;
    xs[w][lane] = xa[(size_t)row * 64 + lane];
    if (xb) xs[w][64 + lane] = xb[(size_t)row * 64 + lane];
    xs[w][128 + lane] = h_in[(size_t)row * 64 + lane];
    __syncthreads();
    float ai = bb[lane];
    float af = bb[64 + lane];
    float ag = bb[128 + lane];
    float ao = bb[192 + lane];
    int D = xb ? 128 : 64;
    for (int k = 0; k < D; ++k) {
        float xv = xs[w][k];
        const float* wr = &WiT[k * 256];
        ai += xv * wr[lane];       af += xv * wr[64 + lane];
        ag += xv * wr[128 + lane]; ao += xv * wr[192 + lane];
    }
    for (int k = 0; k < 64; ++k) {
        float hv = xs[w][128 + k];
        const float* wr = &WhT[k * 256];
        ai += hv * wr[lane];       af += hv * wr[64 + lane];
        ag += hv * wr[128 + lane]; ao += hv * wr[192 + lane];
    }
    float iv = sigm(ai), fv = sigm(af), gv = tanhf(ag), ov = sigm(ao);
    float c = fv * c_in[(size_t)row * 64 + lane] + iv * gv;
    float hh = ov * tanhf(c);
    c_out[(size_t)row * 64 + lane] = c;
    h_out[(size_t)row * 64 + lane] = hh;
    if (hs_out) hs_out[(size_t)row * 64 + lane] = hh;
}

// ---------------- final FC ----------------
__global__ __launch_bounds__(256) void k_final(const float* __restrict__ h1,
                                               const float* __restrict__ h2,
                                               const float* __restrict__ w1,
                                               const float* __restrict__ b1,
                                               const float* __restrict__ w2,
                                               const float* __restrict__ b2,
                                               float* __restrict__ out) {
    __shared__ float zs[4][128];
    int w = threadIdx.x >> 6, lane = threadIdx.x & 63;
    int row = blockIdx.x * 4 + w;
    zs[w][lane] = h1[(size_t)row * 64 + lane];
    zs[w][64 + lane] = h2[(size_t)row * 64 + lane];
    __syncthreads();
    float acc = b1[lane];
    for (int k = 0; k < 128; ++k) acc += zs[w][k] * w1[k * 64 + lane];
    float r = fmaxf(acc, 0.f);
    float t0 = r * w2[lane * 2];
    float t1 = r * w2[lane * 2 + 1];
#pragma unroll
    for (int o = 32; o >= 1; o >>= 1) {
        t0 += __shfl_xor(t0, o, 64);
        t1 += __shfl_xor(t1, o, 64);
    }
    if (lane == 0) {
        out[row * 2]     = fmaxf(t0 + b2[0], 0.f);
        out[row * 2 + 1] = fmaxf(t1 + b2[1], 0.f);
    }
}

extern "C" void kernel_launch(void* const* d_in, const int* in_sizes, int n_in,
                              void* d_out, int out_size, void* d_ws, size_t ws_size,
                              hipStream_t stream) {
    const float* emb  = (const float*)d_in[0];
    const float* g1W  = (const float*)d_in[1];
    const float* g1as = (const float*)d_in[2];
    const float* g1ad = (const float*)d_in[3];
    const float* g1b  = (const float*)d_in[4];
    const float* l1W  = (const float*)d_in[5];
    const float* l1b  = (const float*)d_in[6];
    const float* g2W  = (const float*)d_in[7];
    const float* g2as = (const float*)d_in[8];
    const float* g2ad = (const float*)d_in[9];
    const float* g2b  = (const float*)d_in[10];
    const float* l2W  = (const float*)d_in[11];
    const float* l2b  = (const float*)d_in[12];
    const float* Wi1  = (const float*)d_in[13];
    const float* Wh1  = (const float*)d_in[14];
    const float* b1   = (const float*)d_in[15];
    const float* Wi2  = (const float*)d_in[16];
    const float* Wh2  = (const float*)d_in[17];
    const float* b2   = (const float*)d_in[18];
    const float* fc1W = (const float*)d_in[19];
    const float* fc1b = (const float*)d_in[20];
    const float* fc2W = (const float*)d_in[21];
    const float* fc2b = (const float*)d_in[22];
    const int* edges = (const int*)d_in[23];
    const int* clf   = (const int*)d_in[27];

    char* ws = (char*)d_ws;
    size_t woff = 0;
    auto alloc = [&](size_t bytes) -> void* {
        void* p = ws + woff;
        woff += (bytes + 255) & ~(size_t)255;
        return p;
    };
    int* csr_off  = (int*)alloc((size_t)TT * (NN + 1) * 4);
    int* csr_fil  = (int*)alloc((size_t)TT * NN * 4);
    int* csr_src  = (int*)alloc((size_t)TT * ET * 4);
    int* scan_sum = (int*)alloc((size_t)TT * NCH * 4);
    int* scan_bas = (int*)alloc((size_t)TT * NCH * 4);
    float* xbuf   = (float*)alloc((size_t)NN * 64 * 4);
    u16* hbuf     = (u16*)alloc((size_t)NN * 256 * 2);
    float* gat    = (float*)alloc((size_t)NN * 256 * 4);
    float* albuf  = (float*)alloc((size_t)NN * 4 * 4);
    float* arbuf  = (float*)alloc((size_t)NN * 4 * 4);
    float* seq    = (float*)alloc((size_t)2 * TT * NC * 64 * 4);
    float* hsb    = (float*)alloc((size_t)TT * NC * 64 * 4);
    float* h1s    = (float*)alloc((size_t)NC * 64 * 4);
    float* c1s    = (float*)alloc((size_t)NC * 64 * 4);
    float* h2s    = (float*)alloc((size_t)NC * 64 * 4);
    float* c2s    = (float*)alloc((size_t)NC * 64 * 4);
    float* WiT1   = (float*)alloc(128 * 256 * 4);
    float* WhT1   = (float*)alloc(64 * 256 * 4);
    float* WiT2   = (float*)alloc(64 * 256 * 4);
    float* WhT2   = (float*)alloc(64 * 256 * 4);

    // CSR build (per snapshot, includes self-loops)
    k_fill1<<<(TT * NN + 255) / 256, 256, 0, stream>>>(csr_fil, TT * NN);
    k_count<<<(TT * EE + 255) / 256, 256, 0, stream>>>(edges, csr_fil);
    k_scan1<<<TT * NCH, 256, 0, stream>>>(csr_fil, scan_sum);
    k_scan2<<<TT, 256, 0, stream>>>(scan_sum, scan_bas, csr_off);
    k_scan3<<<TT * NCH, 256, 0, stream>>>(csr_fil, scan_bas, csr_off);
    k_csrfill<<<(TT * ET + 255) / 256, 256, 0, stream>>>(edges, csr_fil, csr_src);

    // LSTM weight transposes (f32 [K][256] for coalesced gate loads)
    k_transpose<<<(256 * 128 + 255) / 256, 256, 0, stream>>>(Wi1, WiT1, 256, 128);
    k_transpose<<<(256 * 64 + 255) / 256, 256, 0, stream>>>(Wh1, WhT1, 256, 64);
    k_transpose<<<(256 * 64 + 255) / 256, 256, 0, stream>>>(Wi2, WiT2, 256, 64);
    k_transpose<<<(256 * 64 + 255) / 256, 256, 0, stream>>>(Wh2, WhT2, 256, 64);

    for (int s = 0; s < 2; ++s) {
        const float* gW  = s ? g2W : g1W;
        const float* gas = s ? g2as : g1as;
        const float* gad = s ? g2ad : g1ad;
        const float* gb  = s ? g2b : g1b;
        const float* lW  = s ? l2W : l1W;
        const float* lb  = s ? l2b : l1b;
        for (int t = 0; t < TT; ++t) {
            for (int l = 0; l < 2; ++l) {
                const float* xin = (l == 0) ? (emb + (size_t)t * NN * 64) : xbuf;
                k_gemm_h<<<(NN + 31) / 32, 256, 0, stream>>>(
                    xin, gW + (size_t)l * 64 * 256, gas + l * 256, gad + l * 256,
                    hbuf, albuf, arbuf);
                k_agg<<<NN / 4, 256, 0, stream>>>(
                    csr_off + (size_t)t * (NN + 1), csr_src + (size_t)t * ET,
                    albuf, arbuf, hbuf, gb + l * 256, gat);
                k_gemm_lin<<<(NN + 127) / 128, 256, 0, stream>>>(
                    gat, lW + (size_t)l * 256 * 64, lb + l * 64, xbuf);
            }
            k_gather<<<(NC * 16 + 255) / 256, 256, 0, stream>>>(
                xbuf, clf, seq + ((size_t)s * TT + t) * NC * 64);
        }
    }

    hipMemsetAsync(h1s, 0, (size_t)NC * 64 * 4, stream);
    hipMemsetAsync(c1s, 0, (size_t)NC * 64 * 4, stream);
    hipMemsetAsync(h2s, 0, (size_t)NC * 64 * 4, stream);
    hipMemsetAsync(c2s, 0, (size_t)NC * 64 * 4, stream);

    // LSTM1: time reversed (outs[::-1]) -> step st reads snapshot TT-1-st
    for (int st = 0; st < TT; ++st) {
        int tsn = TT - 1 - st;
        k_lstm<<<NC / 4, 256, 0, stream>>>(
            seq + (size_t)tsn * NC * 64,
            seq + (size_t)(TT + tsn) * NC * 64,
            WiT1, WhT1, b1, h1s, c1s, h1s, c1s,
            hsb + (size_t)st * NC * 64);
    }
    // LSTM2 over hs
    for (int st = 0; st < TT; ++st) {
        k_lstm<<<NC / 4, 256, 0, stream>>>(
            hsb + (size_t)st * NC * 64, nullptr,
            WiT2, WhT2, b2, h2s, c2s, h2s, c2s, nullptr);
    }
    k_final<<<NC / 4, 256, 0, stream>>>(h1s, h2s, fc1W, fc1b, fc2W, fc2b, (float*)d_out);
}

// Round 10
// 3127.866 us; speedup vs baseline: 1.5064x; 1.1084x over previous
//
#include <hip/hip_runtime.h>

#define NN 50000
#define TT 5
#define EE 500000
#define NC 8192
#define ET (EE + NN)
#define NCH 196   // ceil(NN/256)

typedef unsigned short u16;
typedef __attribute__((ext_vector_type(8))) short bf16x8;
typedef __attribute__((ext_vector_type(4))) float f32x4;

__device__ __forceinline__ float lrelu(float x) { return x >= 0.f ? x : 0.2f * x; }
__device__ __forceinline__ float sigm(float x) { return 1.f / (1.f + expf(-x)); }
__device__ __forceinline__ float fget(float4 v, int k) {
    return k == 0 ? v.x : k == 1 ? v.y : k == 2 ? v.z : v.w;
}
__device__ __forceinline__ float bf2f(u16 u) {
    union { unsigned int i; float f; } v; v.i = ((unsigned int)u) << 16; return v.f;
}
__device__ __forceinline__ u16 f2bf(float f) {
    unsigned int x = __float_as_uint(f);
    return (u16)((x + 0x7fffu + ((x >> 16) & 1u)) >> 16);
}
__device__ __forceinline__ ushort4 f4tobf(float4 v) {
    ushort4 u; u.x = f2bf(v.x); u.y = f2bf(v.y); u.z = f2bf(v.z); u.w = f2bf(v.w);
    return u;
}
__device__ __forceinline__ float4 bf4tof(ushort4 u) {
    return make_float4(bf2f(u.x), bf2f(u.y), bf2f(u.z), bf2f(u.w));
}

// ---------------- CSR build ----------------
__global__ void k_fill1(int* p, int n) {
    int i = blockIdx.x * 256 + threadIdx.x;
    if (i < n) p[i] = 1;
}

__global__ void k_count(const int* __restrict__ edges, int* __restrict__ cnt) {
    int i = blockIdx.x * 256 + threadIdx.x;
    if (i >= TT * EE) return;
    int t = i / EE, e = i % EE;
    int dst = edges[(size_t)t * 2 * EE + EE + e];
    atomicAdd(&cnt[t * NN + dst], 1);
}

// phase 1: per-chunk sums.  grid = TT*NCH
__global__ __launch_bounds__(256) void k_scan1(const int* __restrict__ cnt,
                                               int* __restrict__ sums) {
    int t = blockIdx.x / NCH, ch = blockIdx.x % NCH;
    int i = ch * 256 + threadIdx.x;
    int v = (i < NN) ? cnt[t * NN + i] : 0;
    __shared__ int s[256];
    s[threadIdx.x] = v;
    __syncthreads();
    for (int o = 128; o > 0; o >>= 1) {
        if (threadIdx.x < o) s[threadIdx.x] += s[threadIdx.x + o];
        __syncthreads();
    }
    if (threadIdx.x == 0) sums[t * NCH + ch] = s[0];
}

// phase 2: exclusive scan of NCH chunk sums per snapshot.  grid = TT
__global__ __launch_bounds__(256) void k_scan2(const int* __restrict__ sums,
                                               int* __restrict__ bases,
                                               int* __restrict__ off) {
    int t = blockIdx.x;
    __shared__ int s[256];
    int v = (threadIdx.x < NCH) ? sums[t * NCH + threadIdx.x] : 0;
    s[threadIdx.x] = v;
    __syncthreads();
    for (int o = 1; o < 256; o <<= 1) {
        int tv = (threadIdx.x >= o) ? s[threadIdx.x - o] : 0;
        __syncthreads();
        s[threadIdx.x] += tv;
        __syncthreads();
    }
    if (threadIdx.x < NCH) bases[t * NCH + threadIdx.x] = s[threadIdx.x] - v;
    if (threadIdx.x == 255) off[t * (NN + 1) + NN] = s[255];
}

// phase 3: local scan + base -> off & fill ptr.  grid = TT*NCH
__global__ __launch_bounds__(256) void k_scan3(int* __restrict__ cnt,
                                               const int* __restrict__ bases,
                                               int* __restrict__ off) {
    int t = blockIdx.x / NCH, ch = blockIdx.x % NCH;
    int i = ch * 256 + threadIdx.x;
    int v = (i < NN) ? cnt[t * NN + i] : 0;
    __shared__ int s[256];
    s[threadIdx.x] = v;
    __syncthreads();
    for (int o = 1; o < 256; o <<= 1) {
        int tv = (threadIdx.x >= o) ? s[threadIdx.x - o] : 0;
        __syncthreads();
        s[threadIdx.x] += tv;
        __syncthreads();
    }
    if (i < NN) {
        int excl = bases[t * NCH + ch] + s[threadIdx.x] - v;
        off[t * (NN + 1) + i] = excl;
        cnt[t * NN + i] = excl;  // becomes fill pointer
    }
}

__global__ void k_csrfill(const int* __restrict__ edges, int* __restrict__ fil,
                          int* __restrict__ csr) {
    int i = blockIdx.x * 256 + threadIdx.x;
    if (i >= TT * ET) return;
    int t = i / ET, r = i % ET;
    int src, dst;
    if (r < EE) {
        src = edges[(size_t)t * 2 * EE + r];
        dst = edges[(size_t)t * 2 * EE + EE + r];
    } else {
        src = dst = r - EE;
    }
    int pos = atomicAdd(&fil[t * NN + dst], 1);
    csr[(size_t)t * ET + pos] = src;
}

// ---------------- misc ----------------
__global__ void k_transpose(const float* __restrict__ src, float* __restrict__ dst,
                            int R, int C) {
    int i = blockIdx.x * 256 + threadIdx.x;
    if (i >= R * C) return;
    int r = i / C, c = i % C;
    dst[c * R + r] = src[i];
}

// lin W [2][256][64] f32 -> WT [2][64][256] bf16 (n-major, k-contiguous)
__global__ void k_prep_linW(const float* __restrict__ W, u16* __restrict__ WT) {
    int i = blockIdx.x * 256 + threadIdx.x;
    if (i >= 2 * 256 * 64) return;
    int l = i / 16384, rem = i % 16384;
    int k = rem / 64, n = rem % 64;
    WT[(size_t)l * 16384 + n * 256 + k] = f2bf(W[i]);
}

__global__ void k_gather(const float* __restrict__ x, const int* __restrict__ clf,
                         float* __restrict__ dst) {
    int i = blockIdx.x * 256 + threadIdx.x;
    if (i >= NC * 16) return;
    int row = i >> 4, c4 = i & 15;
    int node = clf[row];
    ((float4*)dst)[row * 16 + c4] = ((const float4*)x)[(size_t)node * 16 + c4];
}

// ---------------- GEMM + fused attention coefficients ----------------
// h[N,256](bf16) = x[N,64] @ W[64,256];  al/ar[N,4] = (h * a_s/a_d).sum per head (f32-exact)
__global__ __launch_bounds__(256) void k_gemm_h(const float* __restrict__ x,
                                                const float* __restrict__ W,
                                                const float* __restrict__ as_,
                                                const float* __restrict__ ad_,
                                                u16* __restrict__ h,
                                                float* __restrict__ al,
                                                float* __restrict__ ar) {
    __shared__ float Wl[64 * 256];
    for (int i = threadIdx.x; i < 4096; i += 256)
        *(float4*)&Wl[i * 4] = ((const float4*)W)[i];
    __syncthreads();
    int lane = threadIdx.x & 63;
    int wg = threadIdx.x >> 6;
    int col = lane * 4;
    int base = blockIdx.x * 32 + wg * 8;
    float4 ua = ((const float4*)as_)[lane];
    float4 ud = ((const float4*)ad_)[lane];
    float4 acc[8];
#pragma unroll
    for (int r = 0; r < 8; ++r) acc[r] = make_float4(0.f, 0.f, 0.f, 0.f);
    for (int k = 0; k < 64; k += 4) {
        float4 xq[8];
#pragma unroll
        for (int r = 0; r < 8; ++r) {
            int row = base + r; if (row > NN - 1) row = NN - 1;
            xq[r] = *(const float4*)&x[(size_t)row * 64 + k];
        }
#pragma unroll
        for (int kk = 0; kk < 4; ++kk) {
            float4 w4 = *(const float4*)&Wl[(k + kk) * 256 + col];
#pragma unroll
            for (int r = 0; r < 8; ++r) {
                float xv = fget(xq[r], kk);
                acc[r].x += xv * w4.x; acc[r].y += xv * w4.y;
                acc[r].z += xv * w4.z; acc[r].w += xv * w4.w;
            }
        }
    }
#pragma unroll
    for (int r = 0; r < 8; ++r) {
        int row = base + r;
        if (row < NN) *(ushort4*)&h[(size_t)row * 256 + col] = f4tobf(acc[r]);
        // fused al/ar from pre-rounding f32 acc
        float ps = acc[r].x * ua.x + acc[r].y * ua.y + acc[r].z * ua.z + acc[r].w * ua.w;
        float pd = acc[r].x * ud.x + acc[r].y * ud.y + acc[r].z * ud.z + acc[r].w * ud.w;
#pragma unroll
        for (int o = 1; o < 16; o <<= 1) {
            ps += __shfl_xor(ps, o, 64);
            pd += __shfl_xor(pd, o, 64);
        }
        if (row < NN && (lane & 15) == 0) {
            al[row * 4 + (lane >> 4)] = ps;
            ar[row * 4 + (lane >> 4)] = pd;
        }
    }
}

// out[N,64] = relu(gat[N,256](bf16) @ W[256,64] + b)  -- MFMA 16x16x32
// A: gat row-major k-contig; B: WT[n][k] k-contig (both 16B/lane loads);
// C/D: col=lane&15, row=(lane>>4)*4+j  [m89-verified layout]
__global__ __launch_bounds__(256) void k_gemm_lin_mfma(const u16* __restrict__ gat,
                                                       const u16* __restrict__ WT,
                                                       const float* __restrict__ b,
                                                       float* __restrict__ out) {
    int lane = threadIdx.x & 63;
    int wid = threadIdx.x >> 6;
    int g = lane >> 4, c = lane & 15;
    int r0 = blockIdx.x * 64 + wid * 16;
    int arow = r0 + c; if (arow > NN - 1) arow = NN - 1;
    const u16* aptr = gat + (size_t)arow * 256 + g * 8;
    const u16* bptr = WT + (size_t)c * 256 + g * 8;
    f32x4 acc[4];
#pragma unroll
    for (int t = 0; t < 4; ++t) acc[t] = (f32x4){0.f, 0.f, 0.f, 0.f};
#pragma unroll
    for (int ks = 0; ks < 8; ++ks) {
        bf16x8 af = *(const bf16x8*)(aptr + ks * 32);
#pragma unroll
        for (int t = 0; t < 4; ++t) {
            bf16x8 bfr = *(const bf16x8*)(bptr + t * 16 * 256 + ks * 32);
            acc[t] = __builtin_amdgcn_mfma_f32_16x16x32_bf16(af, bfr, acc[t], 0, 0, 0);
        }
    }
    int orow0 = r0 + g * 4;
#pragma unroll
    for (int t = 0; t < 4; ++t) {
        int col = t * 16 + c;
        float bv = b[col];
#pragma unroll
        for (int j = 0; j < 4; ++j) {
            int row = orow0 + j;
            if (row < NN) out[(size_t)row * 64 + col] = fmaxf(acc[t][j] + bv, 0.f);
        }
    }
}

// ---------------- attention aggregation (h bf16 in, gat bf16 out) ----------
__global__ __launch_bounds__(256) void k_agg(const int* __restrict__ off,
                                             const int* __restrict__ csr,
                                             const float* __restrict__ al,
                                             const float* __restrict__ ar,
                                             const u16* __restrict__ h,
                                             const float* __restrict__ bias,
                                             u16* __restrict__ out) {
    int lane = threadIdx.x & 63;
    int n = blockIdx.x * 4 + (threadIdx.x >> 6);
    int hd = lane >> 4;
    // exp(e-m)/sum == exp(e)/sum exactly; e bounded ~[-5,5] so exp is safe in f32
    float arh = ar[n * 4 + hd];
    int beg = off[n], end = off[n + 1];
    float den = 0.f;
    float4 acc = make_float4(0.f, 0.f, 0.f, 0.f);
    int j = beg;
    for (; j + 4 <= end; j += 4) {
        int s0 = csr[j], s1 = csr[j + 1], s2 = csr[j + 2], s3 = csr[j + 3];
        float a0 = al[s0 * 4 + hd];
        float a1 = al[s1 * 4 + hd];
        float a2 = al[s2 * 4 + hd];
        float a3 = al[s3 * 4 + hd];
        ushort4 u0 = *(const ushort4*)&h[(size_t)s0 * 256 + lane * 4];
        ushort4 u1 = *(const ushort4*)&h[(size_t)s1 * 256 + lane * 4];
        ushort4 u2 = *(const ushort4*)&h[(size_t)s2 * 256 + lane * 4];
        ushort4 u3 = *(const ushort4*)&h[(size_t)s3 * 256 + lane * 4];
        float p0 = expf(lrelu(a0 + arh));
        float p1 = expf(lrelu(a1 + arh));
        float p2 = expf(lrelu(a2 + arh));
        float p3 = expf(lrelu(a3 + arh));
        float4 h0 = bf4tof(u0), h1 = bf4tof(u1), h2 = bf4tof(u2), h3 = bf4tof(u3);
        den += (p0 + p1) + (p2 + p3);
        acc.x += p0 * h0.x + p1 * h1.x + p2 * h2.x + p3 * h3.x;
        acc.y += p0 * h0.y + p1 * h1.y + p2 * h2.y + p3 * h3.y;
        acc.z += p0 * h0.z + p1 * h1.z + p2 * h2.z + p3 * h3.z;
        acc.w += p0 * h0.w + p1 * h1.w + p2 * h2.w + p3 * h3.w;
    }
    for (; j < end; ++j) {
        int s0 = csr[j];
        float p0 = expf(lrelu(al[s0 * 4 + hd] + arh));
        float4 h0 = bf4tof(*(const ushort4*)&h[(size_t)s0 * 256 + lane * 4]);
        den += p0;
        acc.x += p0 * h0.x; acc.y += p0 * h0.y;
        acc.z += p0 * h0.z; acc.w += p0 * h0.w;
    }
    float inv = 1.f / (den + 1e-16f);
    float4 ub = ((const float4*)bias)[lane];
    float4 o;
    o.x = acc.x * inv + ub.x;
    o.y = acc.y * inv + ub.y;
    o.z = acc.z * inv + ub.z;
    o.w = acc.w * inv + ub.w;
    *(ushort4*)&out[(size_t)n * 256 + lane * 4] = f4tobf(o);
}

// ---------------- LSTM ----------------
__global__ __launch_bounds__(256) void k_lstm(const float* __restrict__ xa,
                                              const float* __restrict__ xb,
                                              const float* __restrict__ WiT,
                                              const float* __restrict__ WhT,
                                              const float* __restrict__ bb,
                                              const float* __restrict__ h_in,
                                              const float* __restrict__ c_in,
                                              float* __restrict__ h_out,
                                              float* __restrict__ c_out,
                                              float* __restrict__ hs_out) {
    __shared__ float xs[4][192];
    int w = threadIdx.x >> 6, lane = threadIdx.x & 63;
    int row = blockIdx.x * 4 + w;
    xs[w][lane] = xa[(size_t)row * 64 + lane];
    if (xb) xs[w][64 + lane] = xb[(size_t)row * 64 + lane];
    xs[w][128 + lane] = h_in[(size_t)row * 64 + lane];
    __syncthreads();
    float ai = bb[lane];
    float af = bb[64 + lane];
    float ag = bb[128 + lane];
    float ao = bb[192 + lane];
    int D = xb ? 128 : 64;
    for (int k = 0; k < D; ++k) {
        float xv = xs[w][k];
        const float* wr = &WiT[k * 256];
        ai += xv * wr[lane];       af += xv * wr[64 + lane];
        ag += xv * wr[128 + lane]; ao += xv * wr[192 + lane];
    }
    for (int k = 0; k < 64; ++k) {
        float hv = xs[w][128 + k];
        const float* wr = &WhT[k * 256];
        ai += hv * wr[lane];       af += hv * wr[64 + lane];
        ag += hv * wr[128 + lane]; ao += hv * wr[192 + lane];
    }
    float iv = sigm(ai), fv = sigm(af), gv = tanhf(ag), ov = sigm(ao);
    float c = fv * c_in[(size_t)row * 64 + lane] + iv * gv;
    float hh = ov * tanhf(c);
    c_out[(size_t)row * 64 + lane] = c;
    h_out[(size_t)row * 64 + lane] = hh;
    if (hs_out) hs_out[(size_t)row * 64 + lane] = hh;
}

// ---------------- final FC ----------------
__global__ __launch_bounds__(256) void k_final(const float* __restrict__ h1,
                                               const float* __restrict__ h2,
                                               const float* __restrict__ w1,
                                               const float* __restrict__ b1,
                                               const float* __restrict__ w2,
                                               const float* __restrict__ b2,
                                               float* __restrict__ out) {
    __shared__ float zs[4][128];
    int w = threadIdx.x >> 6, lane = threadIdx.x & 63;
    int row = blockIdx.x * 4 + w;
    zs[w][lane] = h1[(size_t)row * 64 + lane];
    zs[w][64 + lane] = h2[(size_t)row * 64 + lane];
    __syncthreads();
    float acc = b1[lane];
    for (int k = 0; k < 128; ++k) acc += zs[w][k] * w1[k * 64 + lane];
    float r = fmaxf(acc, 0.f);
    float t0 = r * w2[lane * 2];
    float t1 = r * w2[lane * 2 + 1];
#pragma unroll
    for (int o = 32; o >= 1; o >>= 1) {
        t0 += __shfl_xor(t0, o, 64);
        t1 += __shfl_xor(t1, o, 64);
    }
    if (lane == 0) {
        out[row * 2]     = fmaxf(t0 + b2[0], 0.f);
        out[row * 2 + 1] = fmaxf(t1 + b2[1], 0.f);
    }
}

extern "C" void kernel_launch(void* const* d_in, const int* in_sizes, int n_in,
                              void* d_out, int out_size, void* d_ws, size_t ws_size,
                              hipStream_t stream) {
    const float* emb  = (const float*)d_in[0];
    const float* g1W  = (const float*)d_in[1];
    const float* g1as = (const float*)d_in[2];
    const float* g1ad = (const float*)d_in[3];
    const float* g1b  = (const float*)d_in[4];
    const float* l1W  = (const float*)d_in[5];
    const float* l1b  = (const float*)d_in[6];
    const float* g2W  = (const float*)d_in[7];
    const float* g2as = (const float*)d_in[8];
    const float* g2ad = (const float*)d_in[9];
    const float* g2b  = (const float*)d_in[10];
    const float* l2W  = (const float*)d_in[11];
    const float* l2b  = (const float*)d_in[12];
    const float* Wi1  = (const float*)d_in[13];
    const float* Wh1  = (const float*)d_in[14];
    const float* b1   = (const float*)d_in[15];
    const float* Wi2  = (const float*)d_in[16];
    const float* Wh2  = (const float*)d_in[17];
    const float* b2   = (const float*)d_in[18];
    const float* fc1W = (const float*)d_in[19];
    const float* fc1b = (const float*)d_in[20];
    const float* fc2W = (const float*)d_in[21];
    const float* fc2b = (const float*)d_in[22];
    const int* edges = (const int*)d_in[23];
    const int* clf   = (const int*)d_in[27];

    char* ws = (char*)d_ws;
    size_t woff = 0;
    auto alloc = [&](size_t bytes) -> void* {
        void* p = ws + woff;
        woff += (bytes + 255) & ~(size_t)255;
        return p;
    };
    int* csr_off  = (int*)alloc((size_t)TT * (NN + 1) * 4);
    int* csr_fil  = (int*)alloc((size_t)TT * NN * 4);
    int* csr_src  = (int*)alloc((size_t)TT * ET * 4);
    int* scan_sum = (int*)alloc((size_t)TT * NCH * 4);
    int* scan_bas = (int*)alloc((size_t)TT * NCH * 4);
    float* xbuf   = (float*)alloc((size_t)NN * 64 * 4);
    u16* hbuf     = (u16*)alloc((size_t)NN * 256 * 2);
    u16* gatb     = (u16*)alloc((size_t)NN * 256 * 2);
    float* albuf  = (float*)alloc((size_t)NN * 4 * 4);
    float* arbuf  = (float*)alloc((size_t)NN * 4 * 4);
    float* seq    = (float*)alloc((size_t)2 * TT * NC * 64 * 4);
    float* hsb    = (float*)alloc((size_t)TT * NC * 64 * 4);
    float* h1s    = (float*)alloc((size_t)NC * 64 * 4);
    float* c1s    = (float*)alloc((size_t)NC * 64 * 4);
    float* h2s    = (float*)alloc((size_t)NC * 64 * 4);
    float* c2s    = (float*)alloc((size_t)NC * 64 * 4);
    float* WiT1   = (float*)alloc(128 * 256 * 4);
    float* WhT1   = (float*)alloc(64 * 256 * 4);
    float* WiT2   = (float*)alloc(64 * 256 * 4);
    float* WhT2   = (float*)alloc(64 * 256 * 4);
    u16* linWT1   = (u16*)alloc((size_t)2 * 64 * 256 * 2);  // [L][64][256] bf16
    u16* linWT2   = (u16*)alloc((size_t)2 * 64 * 256 * 2);

    // CSR build (per snapshot, includes self-loops)
    k_fill1<<<(TT * NN + 255) / 256, 256, 0, stream>>>(csr_fil, TT * NN);
    k_count<<<(TT * EE + 255) / 256, 256, 0, stream>>>(edges, csr_fil);
    k_scan1<<<TT * NCH, 256, 0, stream>>>(csr_fil, scan_sum);
    k_scan2<<<TT, 256, 0, stream>>>(scan_sum, scan_bas, csr_off);
    k_scan3<<<TT * NCH, 256, 0, stream>>>(csr_fil, scan_bas, csr_off);
    k_csrfill<<<(TT * ET + 255) / 256, 256, 0, stream>>>(edges, csr_fil, csr_src);

    // LSTM weight transposes (f32 [K][256] for coalesced gate loads)
    k_transpose<<<(256 * 128 + 255) / 256, 256, 0, stream>>>(Wi1, WiT1, 256, 128);
    k_transpose<<<(256 * 64 + 255) / 256, 256, 0, stream>>>(Wh1, WhT1, 256, 64);
    k_transpose<<<(256 * 64 + 255) / 256, 256, 0, stream>>>(Wi2, WiT2, 256, 64);
    k_transpose<<<(256 * 64 + 255) / 256, 256, 0, stream>>>(Wh2, WhT2, 256, 64);
    // lin weights -> bf16 [n][k] for MFMA B-operand
    k_prep_linW<<<(2 * 256 * 64 + 255) / 256, 256, 0, stream>>>(l1W, linWT1);
    k_prep_linW<<<(2 * 256 * 64 + 255) / 256, 256, 0, stream>>>(l2W, linWT2);

    for (int s = 0; s < 2; ++s) {
        const float* gW  = s ? g2W : g1W;
        const float* gas = s ? g2as : g1as;
        const float* gad = s ? g2ad : g1ad;
        const float* gb  = s ? g2b : g1b;
        const u16* lWT   = s ? linWT2 : linWT1;
        const float* lb  = s ? l2b : l1b;
        for (int t = 0; t < TT; ++t) {
            for (int l = 0; l < 2; ++l) {
                const float* xin = (l == 0) ? (emb + (size_t)t * NN * 64) : xbuf;
                k_gemm_h<<<(NN + 31) / 32, 256, 0, stream>>>(
                    xin, gW + (size_t)l * 64 * 256, gas + l * 256, gad + l * 256,
                    hbuf, albuf, arbuf);
                k_agg<<<NN / 4, 256, 0, stream>>>(
                    csr_off + (size_t)t * (NN + 1), csr_src + (size_t)t * ET,
                    albuf, arbuf, hbuf, gb + l * 256, gatb);
                k_gemm_lin_mfma<<<(NN + 63) / 64, 256, 0, stream>>>(
                    gatb, lWT + (size_t)l * 64 * 256, lb + l * 64, xbuf);
            }
            k_gather<<<(NC * 16 + 255) / 256, 256, 0, stream>>>(
                xbuf, clf, seq + ((size_t)s * TT + t) * NC * 64);
        }
    }

    hipMemsetAsync(h1s, 0, (size_t)NC * 64 * 4, stream);
    hipMemsetAsync(c1s, 0, (size_t)NC * 64 * 4, stream);
    hipMemsetAsync(h2s, 0, (size_t)NC * 64 * 4, stream);
    hipMemsetAsync(c2s, 0, (size_t)NC * 64 * 4, stream);

    // LSTM1: time reversed (outs[::-1]) -> step st reads snapshot TT-1-st
    for (int st = 0; st < TT; ++st) {
        int tsn = TT - 1 - st;
        k_lstm<<<NC / 4, 256, 0, stream>>>(
            seq + (size_t)tsn * NC * 64,
            seq + (size_t)(TT + tsn) * NC * 64,
            WiT1, WhT1, b1, h1s, c1s, h1s, c1s,
            hsb + (size_t)st * NC * 64);
    }
    // LSTM2 over hs
    for (int st = 0; st < TT; ++st) {
        k_lstm<<<NC / 4, 256, 0, stream>>>(
            hsb + (size_t)st * NC * 64, nullptr,
            WiT2, WhT2, b2, h2s, c2s, h2s, c2s, nullptr);
    }
    k_final<<<NC / 4, 256, 0, stream>>>(h1s, h2s, fc1W, fc1b, fc2W, fc2b, (float*)d_out);
}

// Round 11
// 2725.798 us; speedup vs baseline: 1.7287x; 1.1475x over previous
//
#include <hip/hip_runtime.h>

#define NN 50000
#define TT 5
#define EE 500000
#define NC 8192
#define ET (EE + NN)
#define NCH 196   // ceil(NN/256)

typedef unsigned short u16;
typedef __attribute__((ext_vector_type(8))) short bf16x8;
typedef __attribute__((ext_vector_type(4))) float f32x4;

__device__ __forceinline__ float lrelu(float x) { return x >= 0.f ? x : 0.2f * x; }
__device__ __forceinline__ float sigm(float x) { return 1.f / (1.f + expf(-x)); }
__device__ __forceinline__ float bf2f(u16 u) {
    union { unsigned int i; float f; } v; v.i = ((unsigned int)u) << 16; return v.f;
}
__device__ __forceinline__ u16 f2bf(float f) {
    unsigned int x = __float_as_uint(f);
    return (u16)((x + 0x7fffu + ((x >> 16) & 1u)) >> 16);
}
__device__ __forceinline__ ushort4 f4tobf(float4 v) {
    ushort4 u; u.x = f2bf(v.x); u.y = f2bf(v.y); u.z = f2bf(v.z); u.w = f2bf(v.w);
    return u;
}
__device__ __forceinline__ float4 bf4tof(ushort4 u) {
    return make_float4(bf2f(u.x), bf2f(u.y), bf2f(u.z), bf2f(u.w));
}

// ---------------- CSR build ----------------
__global__ void k_fill1(int* p, int n) {
    int i = blockIdx.x * 256 + threadIdx.x;
    if (i < n) p[i] = 1;
}

__global__ void k_count(const int* __restrict__ edges, int* __restrict__ cnt) {
    int i = blockIdx.x * 256 + threadIdx.x;
    if (i >= TT * EE) return;
    int t = i / EE, e = i % EE;
    int dst = edges[(size_t)t * 2 * EE + EE + e];
    atomicAdd(&cnt[t * NN + dst], 1);
}

__global__ __launch_bounds__(256) void k_scan1(const int* __restrict__ cnt,
                                               int* __restrict__ sums) {
    int t = blockIdx.x / NCH, ch = blockIdx.x % NCH;
    int i = ch * 256 + threadIdx.x;
    int v = (i < NN) ? cnt[t * NN + i] : 0;
    __shared__ int s[256];
    s[threadIdx.x] = v;
    __syncthreads();
    for (int o = 128; o > 0; o >>= 1) {
        if (threadIdx.x < o) s[threadIdx.x] += s[threadIdx.x + o];
        __syncthreads();
    }
    if (threadIdx.x == 0) sums[t * NCH + ch] = s[0];
}

__global__ __launch_bounds__(256) void k_scan2(const int* __restrict__ sums,
                                               int* __restrict__ bases,
                                               int* __restrict__ off) {
    int t = blockIdx.x;
    __shared__ int s[256];
    int v = (threadIdx.x < NCH) ? sums[t * NCH + threadIdx.x] : 0;
    s[threadIdx.x] = v;
    __syncthreads();
    for (int o = 1; o < 256; o <<= 1) {
        int tv = (threadIdx.x >= o) ? s[threadIdx.x - o] : 0;
        __syncthreads();
        s[threadIdx.x] += tv;
        __syncthreads();
    }
    if (threadIdx.x < NCH) bases[t * NCH + threadIdx.x] = s[threadIdx.x] - v;
    if (threadIdx.x == 255) off[t * (NN + 1) + NN] = s[255];
}

__global__ __launch_bounds__(256) void k_scan3(int* __restrict__ cnt,
                                               const int* __restrict__ bases,
                                               int* __restrict__ off) {
    int t = blockIdx.x / NCH, ch = blockIdx.x % NCH;
    int i = ch * 256 + threadIdx.x;
    int v = (i < NN) ? cnt[t * NN + i] : 0;
    __shared__ int s[256];
    s[threadIdx.x] = v;
    __syncthreads();
    for (int o = 1; o < 256; o <<= 1) {
        int tv = (threadIdx.x >= o) ? s[threadIdx.x - o] : 0;
        __syncthreads();
        s[threadIdx.x] += tv;
        __syncthreads();
    }
    if (i < NN) {
        int excl = bases[t * NCH + ch] + s[threadIdx.x] - v;
        off[t * (NN + 1) + i] = excl;
        cnt[t * NN + i] = excl;  // becomes fill pointer
    }
}

__global__ void k_csrfill(const int* __restrict__ edges, int* __restrict__ fil,
                          int* __restrict__ csr) {
    int i = blockIdx.x * 256 + threadIdx.x;
    if (i >= TT * ET) return;
    int t = i / ET, r = i % ET;
    int src, dst;
    if (r < EE) {
        src = edges[(size_t)t * 2 * EE + r];
        dst = edges[(size_t)t * 2 * EE + EE + r];
    } else {
        src = dst = r - EE;
    }
    int pos = atomicAdd(&fil[t * NN + dst], 1);
    csr[(size_t)t * ET + pos] = src;
}

// ---------------- prep ----------------
__global__ void k_transpose(const float* __restrict__ src, float* __restrict__ dst,
                            int R, int C) {
    int i = blockIdx.x * 256 + threadIdx.x;
    if (i >= R * C) return;
    int r = i / C, c = i % C;
    dst[c * R + r] = src[i];
}

// lin W [2][256][64] f32 -> WT [2][64][256] bf16 (n-major, k-contiguous)
__global__ void k_prep_linW(const float* __restrict__ W, u16* __restrict__ WT) {
    int i = blockIdx.x * 256 + threadIdx.x;
    if (i >= 2 * 256 * 64) return;
    int l = i / 16384, rem = i % 16384;
    int k = rem / 64, n = rem % 64;
    WT[(size_t)l * 16384 + n * 256 + k] = f2bf(W[i]);
}

// gat W [2][64][256] f32 -> WT [2][256][64] bf16 (n-major, k-contiguous)
__global__ void k_prep_gatW(const float* __restrict__ W, u16* __restrict__ WT) {
    int i = blockIdx.x * 256 + threadIdx.x;
    if (i >= 2 * 64 * 256) return;
    int l = i / 16384, rem = i % 16384;
    int k = rem / 256, n = rem % 256;
    WT[(size_t)l * 16384 + n * 64 + k] = f2bf(W[i]);
}

// was/wad[l][k][hd] = sum_f W[l][k][hd*64+f] * a[l][hd][f]   (f32-exact)
__global__ void k_prep_was(const float* __restrict__ W,
                           const float* __restrict__ as_,
                           const float* __restrict__ ad_,
                           float* __restrict__ was, float* __restrict__ wad) {
    int id = blockIdx.x * 256 + threadIdx.x;
    if (id >= 2 * 64 * 4) return;
    int l = id >> 8, rem = id & 255;
    int k = rem >> 2, hd = rem & 3;
    float s = 0.f, d = 0.f;
    for (int f = 0; f < 64; ++f) {
        float w = W[(size_t)l * 16384 + k * 256 + hd * 64 + f];
        s += w * as_[l * 256 + hd * 64 + f];
        d += w * ad_[l * 256 + hd * 64 + f];
    }
    was[l * 256 + k * 4 + hd] = s;
    wad[l * 256 + k * 4 + hd] = d;
}

// f32 -> bf16 bulk convert (float4 -> ushort4)
__global__ void k_f2bf4(const float* __restrict__ src, u16* __restrict__ dst, int n4) {
    int i = blockIdx.x * 256 + threadIdx.x;
    if (i >= n4) return;
    float4 f = ((const float4*)src)[i];
    ((ushort4*)dst)[i] = f4tobf(f);
}

__global__ void k_gather(const u16* __restrict__ x, const int* __restrict__ clf,
                         float* __restrict__ dst) {
    int i = blockIdx.x * 256 + threadIdx.x;
    if (i >= NC * 16) return;
    int row = i >> 4, c4 = i & 15;
    int node = clf[row];
    ushort4 u = ((const ushort4*)x)[(size_t)node * 16 + c4];
    ((float4*)dst)[row * 16 + c4] = bf4tof(u);
}

// ---------------- GAT GEMM (MFMA) + fused al/ar via was/wad ----------------
// h[N,256](bf16) = xb[N,64](bf16) @ W;  al/ar[n][hd] = x[n]·was[:,hd]
__global__ __launch_bounds__(256) void k_gemm_h_mfma(const u16* __restrict__ xb,
                                                     const u16* __restrict__ WT,
                                                     const float* __restrict__ was,
                                                     const float* __restrict__ wad,
                                                     u16* __restrict__ h,
                                                     float* __restrict__ al,
                                                     float* __restrict__ ar) {
    int lane = threadIdx.x & 63, wid = threadIdx.x >> 6;
    int g = lane >> 4, c = lane & 15;
    int r0 = blockIdx.x * 64 + wid * 16;
    int arow = r0 + c; if (arow > NN - 1) arow = NN - 1;
    const u16* aptr = xb + (size_t)arow * 64 + g * 8;
    f32x4 acc[16];
#pragma unroll
    for (int t = 0; t < 16; ++t) acc[t] = (f32x4){0.f, 0.f, 0.f, 0.f};
    float ps[4] = {0.f, 0.f, 0.f, 0.f};
    float pd[4] = {0.f, 0.f, 0.f, 0.f};
#pragma unroll
    for (int ks = 0; ks < 2; ++ks) {
        bf16x8 af = *(const bf16x8*)(aptr + ks * 32);
        // al/ar partials: af[s] is literally xb[arow][ks*32+g*8+s] (linear load)
#pragma unroll
        for (int s = 0; s < 8; ++s) {
            float xv = bf2f((u16)af[s]);
            int k = ks * 32 + g * 8 + s;
            float4 w4 = *(const float4*)&was[k * 4];
            float4 d4 = *(const float4*)&wad[k * 4];
            ps[0] += xv * w4.x; ps[1] += xv * w4.y;
            ps[2] += xv * w4.z; ps[3] += xv * w4.w;
            pd[0] += xv * d4.x; pd[1] += xv * d4.y;
            pd[2] += xv * d4.z; pd[3] += xv * d4.w;
        }
#pragma unroll
        for (int t = 0; t < 16; ++t) {
            bf16x8 bfr = *(const bf16x8*)(WT + (size_t)(t * 16 + c) * 64 + ks * 32 + g * 8);
            acc[t] = __builtin_amdgcn_mfma_f32_16x16x32_bf16(af, bfr, acc[t], 0, 0, 0);
        }
    }
    // reduce partials over the 4 k-groups (lanes differing in g, same c)
#pragma unroll
    for (int hd = 0; hd < 4; ++hd) {
        ps[hd] += __shfl_xor(ps[hd], 16, 64);
        ps[hd] += __shfl_xor(ps[hd], 32, 64);
        pd[hd] += __shfl_xor(pd[hd], 16, 64);
        pd[hd] += __shfl_xor(pd[hd], 32, 64);
    }
    if (g == 0 && r0 + c < NN) {
#pragma unroll
        for (int hd = 0; hd < 4; ++hd) {
            al[(r0 + c) * 4 + hd] = ps[hd];
            ar[(r0 + c) * 4 + hd] = pd[hd];
        }
    }
    // h stores: C/D col=lane&15, row=(lane>>4)*4+j [R10-verified]
#pragma unroll
    for (int t = 0; t < 16; ++t) {
#pragma unroll
        for (int j = 0; j < 4; ++j) {
            int row = r0 + g * 4 + j;
            if (row < NN) h[(size_t)row * 256 + t * 16 + c] = f2bf(acc[t][j]);
        }
    }
}

// out[N,64](bf16) = relu(gat[N,256](bf16) @ W[256,64] + b)  -- MFMA 16x16x32
__global__ __launch_bounds__(256) void k_gemm_lin_mfma(const u16* __restrict__ gat,
                                                       const u16* __restrict__ WT,
                                                       const float* __restrict__ b,
                                                       u16* __restrict__ out) {
    int lane = threadIdx.x & 63;
    int wid = threadIdx.x >> 6;
    int g = lane >> 4, c = lane & 15;
    int r0 = blockIdx.x * 64 + wid * 16;
    int arow = r0 + c; if (arow > NN - 1) arow = NN - 1;
    const u16* aptr = gat + (size_t)arow * 256 + g * 8;
    const u16* bptr = WT + (size_t)c * 256 + g * 8;
    f32x4 acc[4];
#pragma unroll
    for (int t = 0; t < 4; ++t) acc[t] = (f32x4){0.f, 0.f, 0.f, 0.f};
#pragma unroll
    for (int ks = 0; ks < 8; ++ks) {
        bf16x8 af = *(const bf16x8*)(aptr + ks * 32);
#pragma unroll
        for (int t = 0; t < 4; ++t) {
            bf16x8 bfr = *(const bf16x8*)(bptr + t * 16 * 256 + ks * 32);
            acc[t] = __builtin_amdgcn_mfma_f32_16x16x32_bf16(af, bfr, acc[t], 0, 0, 0);
        }
    }
    int orow0 = r0 + g * 4;
#pragma unroll
    for (int t = 0; t < 4; ++t) {
        int col = t * 16 + c;
        float bv = b[col];
#pragma unroll
        for (int j = 0; j < 4; ++j) {
            int row = orow0 + j;
            if (row < NN) out[(size_t)row * 64 + col] = f2bf(fmaxf(acc[t][j] + bv, 0.f));
        }
    }
}

// ---------------- attention aggregation (h bf16 in, gat bf16 out) ----------
__global__ __launch_bounds__(256) void k_agg(const int* __restrict__ off,
                                             const int* __restrict__ csr,
                                             const float* __restrict__ al,
                                             const float* __restrict__ ar,
                                             const u16* __restrict__ h,
                                             const float* __restrict__ bias,
                                             u16* __restrict__ out) {
    int lane = threadIdx.x & 63;
    int n = blockIdx.x * 4 + (threadIdx.x >> 6);
    int hd = lane >> 4;
    float arh = ar[n * 4 + hd];
    int beg = off[n], end = off[n + 1];
    float den = 0.f;
    float4 acc = make_float4(0.f, 0.f, 0.f, 0.f);
    int j = beg;
    for (; j + 4 <= end; j += 4) {
        int s0 = csr[j], s1 = csr[j + 1], s2 = csr[j + 2], s3 = csr[j + 3];
        float a0 = al[s0 * 4 + hd];
        float a1 = al[s1 * 4 + hd];
        float a2 = al[s2 * 4 + hd];
        float a3 = al[s3 * 4 + hd];
        ushort4 u0 = *(const ushort4*)&h[(size_t)s0 * 256 + lane * 4];
        ushort4 u1 = *(const ushort4*)&h[(size_t)s1 * 256 + lane * 4];
        ushort4 u2 = *(const ushort4*)&h[(size_t)s2 * 256 + lane * 4];
        ushort4 u3 = *(const ushort4*)&h[(size_t)s3 * 256 + lane * 4];
        float p0 = expf(lrelu(a0 + arh));
        float p1 = expf(lrelu(a1 + arh));
        float p2 = expf(lrelu(a2 + arh));
        float p3 = expf(lrelu(a3 + arh));
        float4 h0 = bf4tof(u0), h1 = bf4tof(u1), h2 = bf4tof(u2), h3 = bf4tof(u3);
        den += (p0 + p1) + (p2 + p3);
        acc.x += p0 * h0.x + p1 * h1.x + p2 * h2.x + p3 * h3.x;
        acc.y += p0 * h0.y + p1 * h1.y + p2 * h2.y + p3 * h3.y;
        acc.z += p0 * h0.z + p1 * h1.z + p2 * h2.z + p3 * h3.z;
        acc.w += p0 * h0.w + p1 * h1.w + p2 * h2.w + p3 * h3.w;
    }
    for (; j < end; ++j) {
        int s0 = csr[j];
        float p0 = expf(lrelu(al[s0 * 4 + hd] + arh));
        float4 h0 = bf4tof(*(const ushort4*)&h[(size_t)s0 * 256 + lane * 4]);
        den += p0;
        acc.x += p0 * h0.x; acc.y += p0 * h0.y;
        acc.z += p0 * h0.z; acc.w += p0 * h0.w;
    }
    float inv = 1.f / (den + 1e-16f);
    float4 ub = ((const float4*)bias)[lane];
    float4 o;
    o.x = acc.x * inv + ub.x;
    o.y = acc.y * inv + ub.y;
    o.z = acc.z * inv + ub.z;
    o.w = acc.w * inv + ub.w;
    *(ushort4*)&out[(size_t)n * 256 + lane * 4] = f4tobf(o);
}

// ---------------- LSTM ----------------
__global__ __launch_bounds__(256) void k_lstm(const float* __restrict__ xa,
                                              const float* __restrict__ xb,
                                              const float* __restrict__ WiT,
                                              const float* __restrict__ WhT,
                                              const float* __restrict__ bb,
                                              const float* __restrict__ h_in,
                                              const float* __restrict__ c_in,
                                              float* __restrict__ h_out,
                                              float* __restrict__ c_out,
                                              float* __restrict__ hs_out) {
    __shared__ float xs[4][192];
    int w = threadIdx.x >> 6, lane = threadIdx.x & 63;
    int row = blockIdx.x * 4 + w;
    xs[w][lane] = xa[(size_t)row * 64 + lane];
    if (xb) xs[w][64 + lane] = xb[(size_t)row * 64 + lane];
    xs[w][128 + lane] = h_in[(size_t)row * 64 + lane];
    __syncthreads();
    float ai = bb[lane];
    float af = bb[64 + lane];
    float ag = bb[128 + lane];
    float ao = bb[192 + lane];
    int D = xb ? 128 : 64;
    for (int k = 0; k < D; ++k) {
        float xv = xs[w][k];
        const float* wr = &WiT[k * 256];
        ai += xv * wr[lane];       af += xv * wr[64 + lane];
        ag += xv * wr[128 + lane]; ao += xv * wr[192 + lane];
    }
    for (int k = 0; k < 64; ++k) {
        float hv = xs[w][128 + k];
        const float* wr = &WhT[k * 256];
        ai += hv * wr[lane];       af += hv * wr[64 + lane];
        ag += hv * wr[128 + lane]; ao += hv * wr[192 + lane];
    }
    float iv = sigm(ai), fv = sigm(af), gv = tanhf(ag), ov = sigm(ao);
    float c = fv * c_in[(size_t)row * 64 + lane] + iv * gv;
    float hh = ov * tanhf(c);
    c_out[(size_t)row * 64 + lane] = c;
    h_out[(size_t)row * 64 + lane] = hh;
    if (hs_out) hs_out[(size_t)row * 64 + lane] = hh;
}

// ---------------- final FC ----------------
__global__ __launch_bounds__(256) void k_final(const float* __restrict__ h1,
                                               const float* __restrict__ h2,
                                               const float* __restrict__ w1,
                                               const float* __restrict__ b1,
                                               const float* __restrict__ w2,
                                               const float* __restrict__ b2,
                                               float* __restrict__ out) {
    __shared__ float zs[4][128];
    int w = threadIdx.x >> 6, lane = threadIdx.x & 63;
    int row = blockIdx.x * 4 + w;
    zs[w][lane] = h1[(size_t)row * 64 + lane];
    zs[w][64 + lane] = h2[(size_t)row * 64 + lane];
    __syncthreads();
    float acc = b1[lane];
    for (int k = 0; k < 128; ++k) acc += zs[w][k] * w1[k * 64 + lane];
    float r = fmaxf(acc, 0.f);
    float t0 = r * w2[lane * 2];
    float t1 = r * w2[lane * 2 + 1];
#pragma unroll
    for (int o = 32; o >= 1; o >>= 1) {
        t0 += __shfl_xor(t0, o, 64);
        t1 += __shfl_xor(t1, o, 64);
    }
    if (lane == 0) {
        out[row * 2]     = fmaxf(t0 + b2[0], 0.f);
        out[row * 2 + 1] = fmaxf(t1 + b2[1], 0.f);
    }
}

extern "C" void kernel_launch(void* const* d_in, const int* in_sizes, int n_in,
                              void* d_out, int out_size, void* d_ws, size_t ws_size,
                              hipStream_t stream) {
    const float* emb  = (const float*)d_in[0];
    const float* g1W  = (const float*)d_in[1];
    const float* g1as = (const float*)d_in[2];
    const float* g1ad = (const float*)d_in[3];
    const float* g1b  = (const float*)d_in[4];
    const float* l1W  = (const float*)d_in[5];
    const float* l1b  = (const float*)d_in[6];
    const float* g2W  = (const float*)d_in[7];
    const float* g2as = (const float*)d_in[8];
    const float* g2ad = (const float*)d_in[9];
    const float* g2b  = (const float*)d_in[10];
    const float* l2W  = (const float*)d_in[11];
    const float* l2b  = (const float*)d_in[12];
    const float* Wi1  = (const float*)d_in[13];
    const float* Wh1  = (const float*)d_in[14];
    const float* b1   = (const float*)d_in[15];
    const float* Wi2  = (const float*)d_in[16];
    const float* Wh2  = (const float*)d_in[17];
    const float* b2   = (const float*)d_in[18];
    const float* fc1W = (const float*)d_in[19];
    const float* fc1b = (const float*)d_in[20];
    const float* fc2W = (const float*)d_in[21];
    const float* fc2b = (const float*)d_in[22];
    const int* edges = (const int*)d_in[23];
    const int* clf   = (const int*)d_in[27];

    char* ws = (char*)d_ws;
    size_t woff = 0;
    auto alloc = [&](size_t bytes) -> void* {
        void* p = ws + woff;
        woff += (bytes + 255) & ~(size_t)255;
        return p;
    };
    int* csr_off  = (int*)alloc((size_t)TT * (NN + 1) * 4);
    int* csr_fil  = (int*)alloc((size_t)TT * NN * 4);
    int* csr_src  = (int*)alloc((size_t)TT * ET * 4);
    int* scan_sum = (int*)alloc((size_t)TT * NCH * 4);
    int* scan_bas = (int*)alloc((size_t)TT * NCH * 4);
    u16* embb     = (u16*)alloc((size_t)TT * NN * 64 * 2);
    u16* xbuf     = (u16*)alloc((size_t)NN * 64 * 2);
    u16* hbuf     = (u16*)alloc((size_t)NN * 256 * 2);
    u16* gatb     = (u16*)alloc((size_t)NN * 256 * 2);
    float* albuf  = (float*)alloc((size_t)NN * 4 * 4);
    float* arbuf  = (float*)alloc((size_t)NN * 4 * 4);
    float* seq    = (float*)alloc((size_t)2 * TT * NC * 64 * 4);
    float* hsb    = (float*)alloc((size_t)TT * NC * 64 * 4);
    float* h1s    = (float*)alloc((size_t)NC * 64 * 4);
    float* c1s    = (float*)alloc((size_t)NC * 64 * 4);
    float* h2s    = (float*)alloc((size_t)NC * 64 * 4);
    float* c2s    = (float*)alloc((size_t)NC * 64 * 4);
    float* WiT1   = (float*)alloc(128 * 256 * 4);
    float* WhT1   = (float*)alloc(64 * 256 * 4);
    float* WiT2   = (float*)alloc(64 * 256 * 4);
    float* WhT2   = (float*)alloc(64 * 256 * 4);
    u16* linWT1   = (u16*)alloc((size_t)2 * 64 * 256 * 2);   // [L][64][256] bf16
    u16* linWT2   = (u16*)alloc((size_t)2 * 64 * 256 * 2);
    u16* gatWT1   = (u16*)alloc((size_t)2 * 256 * 64 * 2);   // [L][256][64] bf16
    u16* gatWT2   = (u16*)alloc((size_t)2 * 256 * 64 * 2);
    float* wasb1  = (float*)alloc((size_t)2 * 64 * 4 * 4);   // [L][64][4]
    float* wadb1  = (float*)alloc((size_t)2 * 64 * 4 * 4);
    float* wasb2  = (float*)alloc((size_t)2 * 64 * 4 * 4);
    float* wadb2  = (float*)alloc((size_t)2 * 64 * 4 * 4);

    // CSR build (per snapshot, includes self-loops)
    k_fill1<<<(TT * NN + 255) / 256, 256, 0, stream>>>(csr_fil, TT * NN);
    k_count<<<(TT * EE + 255) / 256, 256, 0, stream>>>(edges, csr_fil);
    k_scan1<<<TT * NCH, 256, 0, stream>>>(csr_fil, scan_sum);
    k_scan2<<<TT, 256, 0, stream>>>(scan_sum, scan_bas, csr_off);
    k_scan3<<<TT * NCH, 256, 0, stream>>>(csr_fil, scan_bas, csr_off);
    k_csrfill<<<(TT * ET + 255) / 256, 256, 0, stream>>>(edges, csr_fil, csr_src);

    // weight preps
    k_transpose<<<(256 * 128 + 255) / 256, 256, 0, stream>>>(Wi1, WiT1, 256, 128);
    k_transpose<<<(256 * 64 + 255) / 256, 256, 0, stream>>>(Wh1, WhT1, 256, 64);
    k_transpose<<<(256 * 64 + 255) / 256, 256, 0, stream>>>(Wi2, WiT2, 256, 64);
    k_transpose<<<(256 * 64 + 255) / 256, 256, 0, stream>>>(Wh2, WhT2, 256, 64);
    k_prep_linW<<<(2 * 256 * 64 + 255) / 256, 256, 0, stream>>>(l1W, linWT1);
    k_prep_linW<<<(2 * 256 * 64 + 255) / 256, 256, 0, stream>>>(l2W, linWT2);
    k_prep_gatW<<<(2 * 64 * 256 + 255) / 256, 256, 0, stream>>>(g1W, gatWT1);
    k_prep_gatW<<<(2 * 64 * 256 + 255) / 256, 256, 0, stream>>>(g2W, gatWT2);
    k_prep_was<<<2, 256, 0, stream>>>(g1W, g1as, g1ad, wasb1, wadb1);
    k_prep_was<<<2, 256, 0, stream>>>(g2W, g2as, g2ad, wasb2, wadb2);
    // emb -> bf16
    k_f2bf4<<<(TT * NN * 16 + 255) / 256, 256, 0, stream>>>(emb, embb, TT * NN * 16);

    for (int s = 0; s < 2; ++s) {
        const u16* gWT   = s ? gatWT2 : gatWT1;
        const float* was = s ? wasb2 : wasb1;
        const float* wad = s ? wadb2 : wadb1;
        const float* gb  = s ? g2b : g1b;
        const u16* lWT   = s ? linWT2 : linWT1;
        const float* lb  = s ? l2b : l1b;
        for (int t = 0; t < TT; ++t) {
            for (int l = 0; l < 2; ++l) {
                const u16* xin = (l == 0) ? (embb + (size_t)t * NN * 64) : xbuf;
                k_gemm_h_mfma<<<(NN + 63) / 64, 256, 0, stream>>>(
                    xin, gWT + (size_t)l * 16384, was + l * 256, wad + l * 256,
                    hbuf, albuf, arbuf);
                k_agg<<<NN / 4, 256, 0, stream>>>(
                    csr_off + (size_t)t * (NN + 1), csr_src + (size_t)t * ET,
                    albuf, arbuf, hbuf, gb + l * 256, gatb);
                k_gemm_lin_mfma<<<(NN + 63) / 64, 256, 0, stream>>>(
                    gatb, lWT + (size_t)l * 64 * 256, lb + l * 64, xbuf);
            }
            k_gather<<<(NC * 16 + 255) / 256, 256, 0, stream>>>(
                xbuf, clf, seq + ((size_t)s * TT + t) * NC * 64);
        }
    }

    hipMemsetAsync(h1s, 0, (size_t)NC * 64 * 4, stream);
    hipMemsetAsync(c1s, 0, (size_t)NC * 64 * 4, stream);
    hipMemsetAsync(h2s, 0, (size_t)NC * 64 * 4, stream);
    hipMemsetAsync(c2s, 0, (size_t)NC * 64 * 4, stream);

    // LSTM1: time reversed (outs[::-1]) -> step st reads snapshot TT-1-st
    for (int st = 0; st < TT; ++st) {
        int tsn = TT - 1 - st;
        k_lstm<<<NC / 4, 256, 0, stream>>>(
            seq + (size_t)tsn * NC * 64,
            seq + (size_t)(TT + tsn) * NC * 64,
            WiT1, WhT1, b1, h1s, c1s, h1s, c1s,
            hsb + (size_t)st * NC * 64);
    }
    // LSTM2 over hs
    for (int st = 0; st < TT; ++st) {
        k_lstm<<<NC / 4, 256, 0, stream>>>(
            hsb + (size_t)st * NC * 64, nullptr,
            WiT2, WhT2, b2, h2s, c2s, h2s, c2s, nullptr);
    }
    k_final<<<NC / 4, 256, 0, stream>>>(h1s, h2s, fc1W, fc1b, fc2W, fc2b, (float*)d_out);
}

// Round 12
// 2679.118 us; speedup vs baseline: 1.7588x; 1.0174x over previous
//
#include <hip/hip_runtime.h>

#define NN 50000
#define TT 5
#define EE 500000
#define NC 8192
#define ET (EE + NN)
#define NCH 196   // ceil(NN/256)

typedef unsigned short u16;
typedef __attribute__((ext_vector_type(8))) short bf16x8;
typedef __attribute__((ext_vector_type(4))) float f32x4;

__device__ __forceinline__ float lrelu(float x) { return x >= 0.f ? x : 0.2f * x; }
__device__ __forceinline__ float sigm(float x) { return 1.f / (1.f + expf(-x)); }
__device__ __forceinline__ float bf2f(u16 u) {
    union { unsigned int i; float f; } v; v.i = ((unsigned int)u) << 16; return v.f;
}
__device__ __forceinline__ u16 f2bf(float f) {
    unsigned int x = __float_as_uint(f);
    return (u16)((x + 0x7fffu + ((x >> 16) & 1u)) >> 16);
}
__device__ __forceinline__ ushort4 f4tobf(float4 v) {
    ushort4 u; u.x = f2bf(v.x); u.y = f2bf(v.y); u.z = f2bf(v.z); u.w = f2bf(v.w);
    return u;
}
__device__ __forceinline__ float4 bf4tof(ushort4 u) {
    return make_float4(bf2f(u.x), bf2f(u.y), bf2f(u.z), bf2f(u.w));
}

// ---------------- CSR build ----------------
__global__ void k_fill1(int* p, int n) {
    int i = blockIdx.x * 256 + threadIdx.x;
    if (i < n) p[i] = 1;
}

__global__ void k_count(const int* __restrict__ edges, int* __restrict__ cnt) {
    int i = blockIdx.x * 256 + threadIdx.x;
    if (i >= TT * EE) return;
    int t = i / EE, e = i % EE;
    int dst = edges[(size_t)t * 2 * EE + EE + e];
    atomicAdd(&cnt[t * NN + dst], 1);
}

__global__ __launch_bounds__(256) void k_scan1(const int* __restrict__ cnt,
                                               int* __restrict__ sums) {
    int t = blockIdx.x / NCH, ch = blockIdx.x % NCH;
    int i = ch * 256 + threadIdx.x;
    int v = (i < NN) ? cnt[t * NN + i] : 0;
    __shared__ int s[256];
    s[threadIdx.x] = v;
    __syncthreads();
    for (int o = 128; o > 0; o >>= 1) {
        if (threadIdx.x < o) s[threadIdx.x] += s[threadIdx.x + o];
        __syncthreads();
    }
    if (threadIdx.x == 0) sums[t * NCH + ch] = s[0];
}

__global__ __launch_bounds__(256) void k_scan2(const int* __restrict__ sums,
                                               int* __restrict__ bases,
                                               int* __restrict__ off) {
    int t = blockIdx.x;
    __shared__ int s[256];
    int v = (threadIdx.x < NCH) ? sums[t * NCH + threadIdx.x] : 0;
    s[threadIdx.x] = v;
    __syncthreads();
    for (int o = 1; o < 256; o <<= 1) {
        int tv = (threadIdx.x >= o) ? s[threadIdx.x - o] : 0;
        __syncthreads();
        s[threadIdx.x] += tv;
        __syncthreads();
    }
    if (threadIdx.x < NCH) bases[t * NCH + threadIdx.x] = s[threadIdx.x] - v;
    if (threadIdx.x == 255) off[t * (NN + 1) + NN] = s[255];
}

__global__ __launch_bounds__(256) void k_scan3(int* __restrict__ cnt,
                                               const int* __restrict__ bases,
                                               int* __restrict__ off) {
    int t = blockIdx.x / NCH, ch = blockIdx.x % NCH;
    int i = ch * 256 + threadIdx.x;
    int v = (i < NN) ? cnt[t * NN + i] : 0;
    __shared__ int s[256];
    s[threadIdx.x] = v;
    __syncthreads();
    for (int o = 1; o < 256; o <<= 1) {
        int tv = (threadIdx.x >= o) ? s[threadIdx.x - o] : 0;
        __syncthreads();
        s[threadIdx.x] += tv;
        __syncthreads();
    }
    if (i < NN) {
        int excl = bases[t * NCH + ch] + s[threadIdx.x] - v;
        off[t * (NN + 1) + i] = excl;
        cnt[t * NN + i] = excl;  // becomes fill pointer
    }
}

__global__ void k_csrfill(const int* __restrict__ edges, int* __restrict__ fil,
                          int* __restrict__ csr) {
    int i = blockIdx.x * 256 + threadIdx.x;
    if (i >= TT * ET) return;
    int t = i / ET, r = i % ET;
    int src, dst;
    if (r < EE) {
        src = edges[(size_t)t * 2 * EE + r];
        dst = edges[(size_t)t * 2 * EE + EE + r];
    } else {
        src = dst = r - EE;
    }
    int pos = atomicAdd(&fil[t * NN + dst], 1);
    csr[(size_t)t * ET + pos] = src;
}

// ---------------- prep ----------------
__global__ void k_transpose(const float* __restrict__ src, float* __restrict__ dst,
                            int R, int C) {
    int i = blockIdx.x * 256 + threadIdx.x;
    if (i >= R * C) return;
    int r = i / C, c = i % C;
    dst[c * R + r] = src[i];
}

// lin W [2][256][64] f32 -> WT [2][64][256] bf16 (n-major, k-contiguous)
__global__ void k_prep_linW(const float* __restrict__ W, u16* __restrict__ WT) {
    int i = blockIdx.x * 256 + threadIdx.x;
    if (i >= 2 * 256 * 64) return;
    int l = i / 16384, rem = i % 16384;
    int k = rem / 64, n = rem % 64;
    WT[(size_t)l * 16384 + n * 256 + k] = f2bf(W[i]);
}

// gat W [2][64][256] f32 -> WT [2][256][64] bf16 (n-major, k-contiguous)
__global__ void k_prep_gatW(const float* __restrict__ W, u16* __restrict__ WT) {
    int i = blockIdx.x * 256 + threadIdx.x;
    if (i >= 2 * 64 * 256) return;
    int l = i / 16384, rem = i % 16384;
    int k = rem / 256, n = rem % 256;
    WT[(size_t)l * 16384 + n * 64 + k] = f2bf(W[i]);
}

// was/wad[l][k][hd] = sum_f W[l][k][hd*64+f] * a[l][hd][f]   (f32-exact)
__global__ void k_prep_was(const float* __restrict__ W,
                           const float* __restrict__ as_,
                           const float* __restrict__ ad_,
                           float* __restrict__ was, float* __restrict__ wad) {
    int id = blockIdx.x * 256 + threadIdx.x;
    if (id >= 2 * 64 * 4) return;
    int l = id >> 8, rem = id & 255;
    int k = rem >> 2, hd = rem & 3;
    float s = 0.f, d = 0.f;
    for (int f = 0; f < 64; ++f) {
        float w = W[(size_t)l * 16384 + k * 256 + hd * 64 + f];
        s += w * as_[l * 256 + hd * 64 + f];
        d += w * ad_[l * 256 + hd * 64 + f];
    }
    was[l * 256 + k * 4 + hd] = s;
    wad[l * 256 + k * 4 + hd] = d;
}

// f32 -> bf16 bulk convert (float4 -> ushort4)
__global__ void k_f2bf4(const float* __restrict__ src, u16* __restrict__ dst, int n4) {
    int i = blockIdx.x * 256 + threadIdx.x;
    if (i >= n4) return;
    float4 f = ((const float4*)src)[i];
    ((ushort4*)dst)[i] = f4tobf(f);
}

__global__ void k_gather(const u16* __restrict__ x, const int* __restrict__ clf,
                         float* __restrict__ dst) {
    int i = blockIdx.x * 256 + threadIdx.x;
    if (i >= NC * 16) return;
    int row = i >> 4, c4 = i & 15;
    int node = clf[row];
    ushort4 u = ((const ushort4*)x)[(size_t)node * 16 + c4];
    ((float4*)dst)[row * 16 + c4] = bf4tof(u);
}

// ---------------- GAT GEMM (MFMA) + fused al/ar via was/wad ----------------
__global__ __launch_bounds__(256) void k_gemm_h_mfma(const u16* __restrict__ xb,
                                                     const u16* __restrict__ WT,
                                                     const float* __restrict__ was,
                                                     const float* __restrict__ wad,
                                                     u16* __restrict__ h,
                                                     float* __restrict__ al,
                                                     float* __restrict__ ar) {
    int lane = threadIdx.x & 63, wid = threadIdx.x >> 6;
    int g = lane >> 4, c = lane & 15;
    int r0 = blockIdx.x * 64 + wid * 16;
    int arow = r0 + c; if (arow > NN - 1) arow = NN - 1;
    const u16* aptr = xb + (size_t)arow * 64 + g * 8;
    f32x4 acc[16];
#pragma unroll
    for (int t = 0; t < 16; ++t) acc[t] = (f32x4){0.f, 0.f, 0.f, 0.f};
    float ps[4] = {0.f, 0.f, 0.f, 0.f};
    float pd[4] = {0.f, 0.f, 0.f, 0.f};
#pragma unroll
    for (int ks = 0; ks < 2; ++ks) {
        bf16x8 af = *(const bf16x8*)(aptr + ks * 32);
#pragma unroll
        for (int s = 0; s < 8; ++s) {
            float xv = bf2f((u16)af[s]);
            int k = ks * 32 + g * 8 + s;
            float4 w4 = *(const float4*)&was[k * 4];
            float4 d4 = *(const float4*)&wad[k * 4];
            ps[0] += xv * w4.x; ps[1] += xv * w4.y;
            ps[2] += xv * w4.z; ps[3] += xv * w4.w;
            pd[0] += xv * d4.x; pd[1] += xv * d4.y;
            pd[2] += xv * d4.z; pd[3] += xv * d4.w;
        }
#pragma unroll
        for (int t = 0; t < 16; ++t) {
            bf16x8 bfr = *(const bf16x8*)(WT + (size_t)(t * 16 + c) * 64 + ks * 32 + g * 8);
            acc[t] = __builtin_amdgcn_mfma_f32_16x16x32_bf16(af, bfr, acc[t], 0, 0, 0);
        }
    }
#pragma unroll
    for (int hd = 0; hd < 4; ++hd) {
        ps[hd] += __shfl_xor(ps[hd], 16, 64);
        ps[hd] += __shfl_xor(ps[hd], 32, 64);
        pd[hd] += __shfl_xor(pd[hd], 16, 64);
        pd[hd] += __shfl_xor(pd[hd], 32, 64);
    }
    if (g == 0 && r0 + c < NN) {
#pragma unroll
        for (int hd = 0; hd < 4; ++hd) {
            al[(r0 + c) * 4 + hd] = ps[hd];
            ar[(r0 + c) * 4 + hd] = pd[hd];
        }
    }
#pragma unroll
    for (int t = 0; t < 16; ++t) {
#pragma unroll
        for (int j = 0; j < 4; ++j) {
            int row = r0 + g * 4 + j;
            if (row < NN) h[(size_t)row * 256 + t * 16 + c] = f2bf(acc[t][j]);
        }
    }
}

// out[N,64](bf16) = relu(gat[N,256](bf16) @ W[256,64] + b)  -- MFMA 16x16x32
__global__ __launch_bounds__(256) void k_gemm_lin_mfma(const u16* __restrict__ gat,
                                                       const u16* __restrict__ WT,
                                                       const float* __restrict__ b,
                                                       u16* __restrict__ out) {
    int lane = threadIdx.x & 63;
    int wid = threadIdx.x >> 6;
    int g = lane >> 4, c = lane & 15;
    int r0 = blockIdx.x * 64 + wid * 16;
    int arow = r0 + c; if (arow > NN - 1) arow = NN - 1;
    const u16* aptr = gat + (size_t)arow * 256 + g * 8;
    const u16* bptr = WT + (size_t)c * 256 + g * 8;
    f32x4 acc[4];
#pragma unroll
    for (int t = 0; t < 4; ++t) acc[t] = (f32x4){0.f, 0.f, 0.f, 0.f};
#pragma unroll
    for (int ks = 0; ks < 8; ++ks) {
        bf16x8 af = *(const bf16x8*)(aptr + ks * 32);
#pragma unroll
        for (int t = 0; t < 4; ++t) {
            bf16x8 bfr = *(const bf16x8*)(bptr + t * 16 * 256 + ks * 32);
            acc[t] = __builtin_amdgcn_mfma_f32_16x16x32_bf16(af, bfr, acc[t], 0, 0, 0);
        }
    }
    int orow0 = r0 + g * 4;
#pragma unroll
    for (int t = 0; t < 4; ++t) {
        int col = t * 16 + c;
        float bv = b[col];
#pragma unroll
        for (int j = 0; j < 4; ++j) {
            int row = orow0 + j;
            if (row < NN) out[(size_t)row * 64 + col] = f2bf(fmaxf(acc[t][j] + bv, 0.f));
        }
    }
}

// ---------------- attention aggregation v3 ----------------
// wave per node; csr prefetched to lane regs; p batch-computed (16 edges x 4 heads
// per shuffle batch); h-row loads software-pipelined 4-deep with p=0 padding.
__global__ __launch_bounds__(256) void k_agg(const int* __restrict__ off,
                                             const int* __restrict__ csr,
                                             const float* __restrict__ al,
                                             const float* __restrict__ ar,
                                             const u16* __restrict__ h,
                                             const float* __restrict__ bias,
                                             u16* __restrict__ out) {
    int lane = threadIdx.x & 63;
    int n = blockIdx.x * 4 + (threadIdx.x >> 6);
    int hd = lane >> 4;          // head consumed by this lane (weighted sum)
    int hh = lane & 3;           // head computed by this lane (p-phase)
    float ar_hh = ar[n * 4 + hh];
    int beg = off[n], end = off[n + 1];
    float den = 0.f;
    float4 acc = make_float4(0.f, 0.f, 0.f, 0.f);

    for (int cbase = beg; cbase < end; cbase += 64) {
        int cnt = min(64, end - cbase);
        // prefetch up to 64 neighbor ids (coalesced); pad with a valid id
        int sidx = csr[cbase + ((lane < cnt) ? lane : 0)];
        // p-phase: batch b covers edges b*16..b*16+15; lane computes edge (lane>>2), head (lane&3)
        float pb[4];
#pragma unroll
        for (int b = 0; b < 4; ++b) {
            int jj = b * 16 + (lane >> 2);
            int sj = __shfl(sidx, (jj < cnt) ? jj : 0, 64);
            pb[b] = expf(lrelu(al[sj * 4 + hh] + ar_hh));
        }
        int cntp = (cnt + 3) & ~3;
        // prologue: load first 4 h-rows
        ushort4 cu0, cu1, cu2, cu3;
        {
            int s0 = __shfl(sidx, 0 < cnt ? 0 : 0, 64);
            int s1 = __shfl(sidx, 1 < cnt ? 1 : 0, 64);
            int s2 = __shfl(sidx, 2 < cnt ? 2 : 0, 64);
            int s3 = __shfl(sidx, 3 < cnt ? 3 : 0, 64);
            cu0 = *(const ushort4*)&h[(size_t)s0 * 256 + lane * 4];
            cu1 = *(const ushort4*)&h[(size_t)s1 * 256 + lane * 4];
            cu2 = *(const ushort4*)&h[(size_t)s2 * 256 + lane * 4];
            cu3 = *(const ushort4*)&h[(size_t)s3 * 256 + lane * 4];
        }
        for (int j = 0; j < cntp; j += 4) {
            ushort4 nu0, nu1, nu2, nu3;
            bool more = (j + 4) < cntp;
            if (more) {
                int q0 = j + 4, q1 = j + 5, q2 = j + 6, q3 = j + 7;
                int s0 = __shfl(sidx, q0 < cnt ? q0 : 0, 64);
                int s1 = __shfl(sidx, q1 < cnt ? q1 : 0, 64);
                int s2 = __shfl(sidx, q2 < cnt ? q2 : 0, 64);
                int s3 = __shfl(sidx, q3 < cnt ? q3 : 0, 64);
                nu0 = *(const ushort4*)&h[(size_t)s0 * 256 + lane * 4];
                nu1 = *(const ushort4*)&h[(size_t)s1 * 256 + lane * 4];
                nu2 = *(const ushort4*)&h[(size_t)s2 * 256 + lane * 4];
                nu3 = *(const ushort4*)&h[(size_t)s3 * 256 + lane * 4];
            }
            // consume current 4 edges; p=0 for padded slots
#pragma unroll
            for (int q = 0; q < 4; ++q) {
                int jq = j + q;
                int b = jq >> 4;
                float p = __shfl(pb[b & 3], ((jq & 15) << 2) | hd, 64);
                p = (jq < cnt) ? p : 0.f;
                ushort4 uq = (q == 0) ? cu0 : (q == 1) ? cu1 : (q == 2) ? cu2 : cu3;
                float4 hv = bf4tof(uq);
                den += p;
                acc.x += p * hv.x; acc.y += p * hv.y;
                acc.z += p * hv.z; acc.w += p * hv.w;
            }
            if (more) { cu0 = nu0; cu1 = nu1; cu2 = nu2; cu3 = nu3; }
        }
    }
    float inv = 1.f / (den + 1e-16f);
    float4 ub = ((const float4*)bias)[lane];
    float4 o;
    o.x = acc.x * inv + ub.x;
    o.y = acc.y * inv + ub.y;
    o.z = acc.z * inv + ub.z;
    o.w = acc.w * inv + ub.w;
    *(ushort4*)&out[(size_t)n * 256 + lane * 4] = f4tobf(o);
}

// ---------------- LSTM ----------------
__global__ __launch_bounds__(256) void k_lstm(const float* __restrict__ xa,
                                              const float* __restrict__ xb,
                                              const float* __restrict__ WiT,
                                              const float* __restrict__ WhT,
                                              const float* __restrict__ bb,
                                              const float* __restrict__ h_in,
                                              const float* __restrict__ c_in,
                                              float* __restrict__ h_out,
                                              float* __restrict__ c_out,
                                              float* __restrict__ hs_out) {
    __shared__ float xs[4][192];
    int w = threadIdx.x >> 6, lane = threadIdx.x & 63;
    int row = blockIdx.x * 4 + w;
    xs[w][lane] = xa[(size_t)row * 64 + lane];
    if (xb) xs[w][64 + lane] = xb[(size_t)row * 64 + lane];
    xs[w][128 + lane] = h_in[(size_t)row * 64 + lane];
    __syncthreads();
    float ai = bb[lane];
    float af = bb[64 + lane];
    float ag = bb[128 + lane];
    float ao = bb[192 + lane];
    int D = xb ? 128 : 64;
    for (int k = 0; k < D; ++k) {
        float xv = xs[w][k];
        const float* wr = &WiT[k * 256];
        ai += xv * wr[lane];       af += xv * wr[64 + lane];
        ag += xv * wr[128 + lane]; ao += xv * wr[192 + lane];
    }
    for (int k = 0; k < 64; ++k) {
        float hv = xs[w][128 + k];
        const float* wr = &WhT[k * 256];
        ai += hv * wr[lane];       af += hv * wr[64 + lane];
        ag += hv * wr[128 + lane]; ao += hv * wr[192 + lane];
    }
    float iv = sigm(ai), fv = sigm(af), gv = tanhf(ag), ov = sigm(ao);
    float c = fv * c_in[(size_t)row * 64 + lane] + iv * gv;
    float hh = ov * tanhf(c);
    c_out[(size_t)row * 64 + lane] = c;
    h_out[(size_t)row * 64 + lane] = hh;
    if (hs_out) hs_out[(size_t)row * 64 + lane] = hh;
}

// ---------------- final FC ----------------
__global__ __launch_bounds__(256) void k_final(const float* __restrict__ h1,
                                               const float* __restrict__ h2,
                                               const float* __restrict__ w1,
                                               const float* __restrict__ b1,
                                               const float* __restrict__ w2,
                                               const float* __restrict__ b2,
                                               float* __restrict__ out) {
    __shared__ float zs[4][128];
    int w = threadIdx.x >> 6, lane = threadIdx.x & 63;
    int row = blockIdx.x * 4 + w;
    zs[w][lane] = h1[(size_t)row * 64 + lane];
    zs[w][64 + lane] = h2[(size_t)row * 64 + lane];
    __syncthreads();
    float acc = b1[lane];
    for (int k = 0; k < 128; ++k) acc += zs[w][k] * w1[k * 64 + lane];
    float r = fmaxf(acc, 0.f);
    float t0 = r * w2[lane * 2];
    float t1 = r * w2[lane * 2 + 1];
#pragma unroll
    for (int o = 32; o >= 1; o >>= 1) {
        t0 += __shfl_xor(t0, o, 64);
        t1 += __shfl_xor(t1, o, 64);
    }
    if (lane == 0) {
        out[row * 2]     = fmaxf(t0 + b2[0], 0.f);
        out[row * 2 + 1] = fmaxf(t1 + b2[1], 0.f);
    }
}

extern "C" void kernel_launch(void* const* d_in, const int* in_sizes, int n_in,
                              void* d_out, int out_size, void* d_ws, size_t ws_size,
                              hipStream_t stream) {
    const float* emb  = (const float*)d_in[0];
    const float* g1W  = (const float*)d_in[1];
    const float* g1as = (const float*)d_in[2];
    const float* g1ad = (const float*)d_in[3];
    const float* g1b  = (const float*)d_in[4];
    const float* l1W  = (const float*)d_in[5];
    const float* l1b  = (const float*)d_in[6];
    const float* g2W  = (const float*)d_in[7];
    const float* g2as = (const float*)d_in[8];
    const float* g2ad = (const float*)d_in[9];
    const float* g2b  = (const float*)d_in[10];
    const float* l2W  = (const float*)d_in[11];
    const float* l2b  = (const float*)d_in[12];
    const float* Wi1  = (const float*)d_in[13];
    const float* Wh1  = (const float*)d_in[14];
    const float* b1   = (const float*)d_in[15];
    const float* Wi2  = (const float*)d_in[16];
    const float* Wh2  = (const float*)d_in[17];
    const float* b2   = (const float*)d_in[18];
    const float* fc1W = (const float*)d_in[19];
    const float* fc1b = (const float*)d_in[20];
    const float* fc2W = (const float*)d_in[21];
    const float* fc2b = (const float*)d_in[22];
    const int* edges = (const int*)d_in[23];
    const int* clf   = (const int*)d_in[27];

    char* ws = (char*)d_ws;
    size_t woff = 0;
    auto alloc = [&](size_t bytes) -> void* {
        void* p = ws + woff;
        woff += (bytes + 255) & ~(size_t)255;
        return p;
    };
    int* csr_off  = (int*)alloc((size_t)TT * (NN + 1) * 4);
    int* csr_fil  = (int*)alloc((size_t)TT * NN * 4);
    int* csr_src  = (int*)alloc((size_t)TT * ET * 4);
    int* scan_sum = (int*)alloc((size_t)TT * NCH * 4);
    int* scan_bas = (int*)alloc((size_t)TT * NCH * 4);
    u16* embb     = (u16*)alloc((size_t)TT * NN * 64 * 2);
    u16* xbuf     = (u16*)alloc((size_t)NN * 64 * 2);
    u16* hbuf     = (u16*)alloc((size_t)NN * 256 * 2);
    u16* gatb     = (u16*)alloc((size_t)NN * 256 * 2);
    float* albuf  = (float*)alloc((size_t)NN * 4 * 4);
    float* arbuf  = (float*)alloc((size_t)NN * 4 * 4);
    float* seq    = (float*)alloc((size_t)2 * TT * NC * 64 * 4);
    float* hsb    = (float*)alloc((size_t)TT * NC * 64 * 4);
    float* h1s    = (float*)alloc((size_t)NC * 64 * 4);
    float* c1s    = (float*)alloc((size_t)NC * 64 * 4);
    float* h2s    = (float*)alloc((size_t)NC * 64 * 4);
    float* c2s    = (float*)alloc((size_t)NC * 64 * 4);
    float* WiT1   = (float*)alloc(128 * 256 * 4);
    float* WhT1   = (float*)alloc(64 * 256 * 4);
    float* WiT2   = (float*)alloc(64 * 256 * 4);
    float* WhT2   = (float*)alloc(64 * 256 * 4);
    u16* linWT1   = (u16*)alloc((size_t)2 * 64 * 256 * 2);   // [L][64][256] bf16
    u16* linWT2   = (u16*)alloc((size_t)2 * 64 * 256 * 2);
    u16* gatWT1   = (u16*)alloc((size_t)2 * 256 * 64 * 2);   // [L][256][64] bf16
    u16* gatWT2   = (u16*)alloc((size_t)2 * 256 * 64 * 2);
    float* wasb1  = (float*)alloc((size_t)2 * 64 * 4 * 4);   // [L][64][4]
    float* wadb1  = (float*)alloc((size_t)2 * 64 * 4 * 4);
    float* wasb2  = (float*)alloc((size_t)2 * 64 * 4 * 4);
    float* wadb2  = (float*)alloc((size_t)2 * 64 * 4 * 4);

    // CSR build (per snapshot, includes self-loops)
    k_fill1<<<(TT * NN + 255) / 256, 256, 0, stream>>>(csr_fil, TT * NN);
    k_count<<<(TT * EE + 255) / 256, 256, 0, stream>>>(edges, csr_fil);
    k_scan1<<<TT * NCH, 256, 0, stream>>>(csr_fil, scan_sum);
    k_scan2<<<TT, 256, 0, stream>>>(scan_sum, scan_bas, csr_off);
    k_scan3<<<TT * NCH, 256, 0, stream>>>(csr_fil, scan_bas, csr_off);
    k_csrfill<<<(TT * ET + 255) / 256, 256, 0, stream>>>(edges, csr_fil, csr_src);

    // weight preps
    k_transpose<<<(256 * 128 + 255) / 256, 256, 0, stream>>>(Wi1, WiT1, 256, 128);
    k_transpose<<<(256 * 64 + 255) / 256, 256, 0, stream>>>(Wh1, WhT1, 256, 64);
    k_transpose<<<(256 * 64 + 255) / 256, 256, 0, stream>>>(Wi2, WiT2, 256, 64);
    k_transpose<<<(256 * 64 + 255) / 256, 256, 0, stream>>>(Wh2, WhT2, 256, 64);
    k_prep_linW<<<(2 * 256 * 64 + 255) / 256, 256, 0, stream>>>(l1W, linWT1);
    k_prep_linW<<<(2 * 256 * 64 + 255) / 256, 256, 0, stream>>>(l2W, linWT2);
    k_prep_gatW<<<(2 * 64 * 256 + 255) / 256, 256, 0, stream>>>(g1W, gatWT1);
    k_prep_gatW<<<(2 * 64 * 256 + 255) / 256, 256, 0, stream>>>(g2W, gatWT2);
    k_prep_was<<<2, 256, 0, stream>>>(g1W, g1as, g1ad, wasb1, wadb1);
    k_prep_was<<<2, 256, 0, stream>>>(g2W, g2as, g2ad, wasb2, wadb2);
    // emb -> bf16
    k_f2bf4<<<(TT * NN * 16 + 255) / 256, 256, 0, stream>>>(emb, embb, TT * NN * 16);

    for (int s = 0; s < 2; ++s) {
        const u16* gWT   = s ? gatWT2 : gatWT1;
        const float* was = s ? wasb2 : wasb1;
        const float* wad = s ? wadb2 : wadb1;
        const float* gb  = s ? g2b : g1b;
        const u16* lWT   = s ? linWT2 : linWT1;
        const float* lb  = s ? l2b : l1b;
        for (int t = 0; t < TT; ++t) {
            for (int l = 0; l < 2; ++l) {
                const u16* xin = (l == 0) ? (embb + (size_t)t * NN * 64) : xbuf;
                k_gemm_h_mfma<<<(NN + 63) / 64, 256, 0, stream>>>(
                    xin, gWT + (size_t)l * 16384, was + l * 256, wad + l * 256,
                    hbuf, albuf, arbuf);
                k_agg<<<NN / 4, 256, 0, stream>>>(
                    csr_off + (size_t)t * (NN + 1), csr_src + (size_t)t * ET,
                    albuf, arbuf, hbuf, gb + l * 256, gatb);
                k_gemm_lin_mfma<<<(NN + 63) / 64, 256, 0, stream>>>(
                    gatb, lWT + (size_t)l * 64 * 256, lb + l * 64, xbuf);
            }
            k_gather<<<(NC * 16 + 255) / 256, 256, 0, stream>>>(
                xbuf, clf, seq + ((size_t)s * TT + t) * NC * 64);
        }
    }

    hipMemsetAsync(h1s, 0, (size_t)NC * 64 * 4, stream);
    hipMemsetAsync(c1s, 0, (size_t)NC * 64 * 4, stream);
    hipMemsetAsync(h2s, 0, (size_t)NC * 64 * 4, stream);
    hipMemsetAsync(c2s, 0, (size_t)NC * 64 * 4, stream);

    // LSTM1: time reversed (outs[::-1]) -> step st reads snapshot TT-1-st
    for (int st = 0; st < TT; ++st) {
        int tsn = TT - 1 - st;
        k_lstm<<<NC / 4, 256, 0, stream>>>(
            seq + (size_t)tsn * NC * 64,
            seq + (size_t)(TT + tsn) * NC * 64,
            WiT1, WhT1, b1, h1s, c1s, h1s, c1s,
            hsb + (size_t)st * NC * 64);
    }
    // LSTM2 over hs
    for (int st = 0; st < TT; ++st) {
        k_lstm<<<NC / 4, 256, 0, stream>>>(
            hsb + (size_t)st * NC * 64, nullptr,
            WiT2, WhT2, b2, h2s, c2s, h2s, c2s, nullptr);
    }
    k_final<<<NC / 4, 256, 0, stream>>>(h1s, h2s, fc1W, fc1b, fc2W, fc2b, (float*)d_out);
}

// Round 13
// 2244.786 us; speedup vs baseline: 2.0991x; 1.1935x over previous
//
#include <hip/hip_runtime.h>

#define NN 50000
#define TT 5
#define EE 500000
#define NC 8192
#define ET (EE + NN)
#define NCH 196   // ceil(NN/256)

typedef unsigned short u16;
typedef __attribute__((ext_vector_type(8))) short bf16x8;
typedef __attribute__((ext_vector_type(4))) float f32x4;

__device__ __forceinline__ float lrelu(float x) { return x >= 0.f ? x : 0.2f * x; }
__device__ __forceinline__ float sigm(float x) { return 1.f / (1.f + expf(-x)); }
__device__ __forceinline__ float bf2f(u16 u) {
    union { unsigned int i; float f; } v; v.i = ((unsigned int)u) << 16; return v.f;
}
__device__ __forceinline__ u16 f2bf(float f) {
    unsigned int x = __float_as_uint(f);
    return (u16)((x + 0x7fffu + ((x >> 16) & 1u)) >> 16);
}
__device__ __forceinline__ ushort4 f4tobf(float4 v) {
    ushort4 u; u.x = f2bf(v.x); u.y = f2bf(v.y); u.z = f2bf(v.z); u.w = f2bf(v.w);
    return u;
}
__device__ __forceinline__ float4 bf4tof(ushort4 u) {
    return make_float4(bf2f(u.x), bf2f(u.y), bf2f(u.z), bf2f(u.w));
}

// ---------------- CSR build ----------------
__global__ void k_fill1(int* p, int n) {
    int i = blockIdx.x * 256 + threadIdx.x;
    if (i < n) p[i] = 1;
}

__global__ void k_count(const int* __restrict__ edges, int* __restrict__ cnt) {
    int i = blockIdx.x * 256 + threadIdx.x;
    if (i >= TT * EE) return;
    int t = i / EE, e = i % EE;
    int dst = edges[(size_t)t * 2 * EE + EE + e];
    atomicAdd(&cnt[t * NN + dst], 1);
}

__global__ __launch_bounds__(256) void k_scan1(const int* __restrict__ cnt,
                                               int* __restrict__ sums) {
    int t = blockIdx.x / NCH, ch = blockIdx.x % NCH;
    int i = ch * 256 + threadIdx.x;
    int v = (i < NN) ? cnt[t * NN + i] : 0;
    __shared__ int s[256];
    s[threadIdx.x] = v;
    __syncthreads();
    for (int o = 128; o > 0; o >>= 1) {
        if (threadIdx.x < o) s[threadIdx.x] += s[threadIdx.x + o];
        __syncthreads();
    }
    if (threadIdx.x == 0) sums[t * NCH + ch] = s[0];
}

__global__ __launch_bounds__(256) void k_scan2(const int* __restrict__ sums,
                                               int* __restrict__ bases,
                                               int* __restrict__ off) {
    int t = blockIdx.x;
    __shared__ int s[256];
    int v = (threadIdx.x < NCH) ? sums[t * NCH + threadIdx.x] : 0;
    s[threadIdx.x] = v;
    __syncthreads();
    for (int o = 1; o < 256; o <<= 1) {
        int tv = (threadIdx.x >= o) ? s[threadIdx.x - o] : 0;
        __syncthreads();
        s[threadIdx.x] += tv;
        __syncthreads();
    }
    if (threadIdx.x < NCH) bases[t * NCH + threadIdx.x] = s[threadIdx.x] - v;
    if (threadIdx.x == 255) off[t * (NN + 1) + NN] = s[255];
}

__global__ __launch_bounds__(256) void k_scan3(int* __restrict__ cnt,
                                               const int* __restrict__ bases,
                                               int* __restrict__ off) {
    int t = blockIdx.x / NCH, ch = blockIdx.x % NCH;
    int i = ch * 256 + threadIdx.x;
    int v = (i < NN) ? cnt[t * NN + i] : 0;
    __shared__ int s[256];
    s[threadIdx.x] = v;
    __syncthreads();
    for (int o = 1; o < 256; o <<= 1) {
        int tv = (threadIdx.x >= o) ? s[threadIdx.x - o] : 0;
        __syncthreads();
        s[threadIdx.x] += tv;
        __syncthreads();
    }
    if (i < NN) {
        int excl = bases[t * NCH + ch] + s[threadIdx.x] - v;
        off[t * (NN + 1) + i] = excl;
        cnt[t * NN + i] = excl;  // becomes fill pointer
    }
}

__global__ void k_csrfill(const int* __restrict__ edges, int* __restrict__ fil,
                          int* __restrict__ csr) {
    int i = blockIdx.x * 256 + threadIdx.x;
    if (i >= TT * ET) return;
    int t = i / ET, r = i % ET;
    int src, dst;
    if (r < EE) {
        src = edges[(size_t)t * 2 * EE + r];
        dst = edges[(size_t)t * 2 * EE + EE + r];
    } else {
        src = dst = r - EE;
    }
    int pos = atomicAdd(&fil[t * NN + dst], 1);
    csr[(size_t)t * ET + pos] = src;
}

// ---------------- prep ----------------
__global__ void k_transpose(const float* __restrict__ src, float* __restrict__ dst,
                            int R, int C) {
    int i = blockIdx.x * 256 + threadIdx.x;
    if (i >= R * C) return;
    int r = i / C, c = i % C;
    dst[c * R + r] = src[i];
}

// was/wad[l][k][hd] = sum_f W[l][k][hd*64+f] * a[l][hd][f]   (f32-exact)
__global__ void k_prep_was(const float* __restrict__ W,
                           const float* __restrict__ as_,
                           const float* __restrict__ ad_,
                           float* __restrict__ was, float* __restrict__ wad) {
    int id = blockIdx.x * 256 + threadIdx.x;
    if (id >= 2 * 64 * 4) return;
    int l = id >> 8, rem = id & 255;
    int k = rem >> 2, hd = rem & 3;
    float s = 0.f, d = 0.f;
    for (int f = 0; f < 64; ++f) {
        float w = W[(size_t)l * 16384 + k * 256 + hd * 64 + f];
        s += w * as_[l * 256 + hd * 64 + f];
        d += w * ad_[l * 256 + hd * 64 + f];
    }
    was[l * 256 + k * 4 + hd] = s;
    wad[l * 256 + k * 4 + hd] = d;
}

// Combined C^T[l][f][kk] = sum_j W[l][k][hd*64+j] * lW[l][hd*64+j][f], kk=hd*64+k
// stored bf16 [2][64][256] (f-major, kk-contiguous) = MFMA B-operand format
__global__ void k_prep_cmb(const float* __restrict__ W, const float* __restrict__ lW,
                           u16* __restrict__ CT) {
    int i = blockIdx.x * 256 + threadIdx.x;
    if (i >= 2 * 64 * 256) return;
    int l = i >> 14, rem = i & 16383;
    int f = rem >> 8, kk = rem & 255;
    int hd = kk >> 6, k = kk & 63;
    float s = 0.f;
    for (int j = 0; j < 64; ++j)
        s += W[(size_t)l * 16384 + k * 256 + hd * 64 + j] *
             lW[(size_t)l * 16384 + (hd * 64 + j) * 64 + f];
    CT[(size_t)l * 16384 + f * 256 + kk] = f2bf(s);
}

// cb[l][f] = sum_j gb[l][j]*lW[l][j][f] + lb[l][f]
__global__ void k_prep_cb(const float* __restrict__ gb, const float* __restrict__ lW,
                          const float* __restrict__ lb, float* __restrict__ cb) {
    int i = blockIdx.x * 256 + threadIdx.x;
    if (i >= 2 * 64) return;
    int l = i >> 6, f = i & 63;
    float s = lb[l * 64 + f];
    for (int j = 0; j < 256; ++j)
        s += gb[l * 256 + j] * lW[(size_t)l * 16384 + j * 64 + f];
    cb[l * 64 + f] = s;
}

// f32 -> bf16 bulk convert (float4 -> ushort4)
__global__ void k_f2bf4(const float* __restrict__ src, u16* __restrict__ dst, int n4) {
    int i = blockIdx.x * 256 + threadIdx.x;
    if (i >= n4) return;
    float4 f = ((const float4*)src)[i];
    ((ushort4*)dst)[i] = f4tobf(f);
}

__global__ void k_gather(const u16* __restrict__ x, const int* __restrict__ clf,
                         float* __restrict__ dst) {
    int i = blockIdx.x * 256 + threadIdx.x;
    if (i >= NC * 16) return;
    int row = i >> 4, c4 = i & 15;
    int node = clf[row];
    ushort4 u = ((const ushort4*)x)[(size_t)node * 16 + c4];
    ((float4*)dst)[row * 16 + c4] = bf4tof(u);
}

// ---------------- al/ar: x[N,64] dot was/wad[64][4] ----------------
// wave per 4 nodes; 16 lanes/node, 4 k-dims/lane; butterfly reduce over 16 lanes
__global__ __launch_bounds__(256) void k_alar_x(const u16* __restrict__ xb,
                                                const float* __restrict__ was,
                                                const float* __restrict__ wad,
                                                float* __restrict__ al,
                                                float* __restrict__ ar) {
    int lane = threadIdx.x & 63;
    int n = blockIdx.x * 16 + (threadIdx.x >> 6) * 4 + (lane >> 4);
    int q = lane & 15;
    ushort4 u = *(const ushort4*)&xb[(size_t)n * 64 + q * 4];
    float ps[4] = {0.f, 0.f, 0.f, 0.f};
    float pd[4] = {0.f, 0.f, 0.f, 0.f};
#pragma unroll
    for (int d = 0; d < 4; ++d) {
        u16 uv = (d == 0) ? u.x : (d == 1) ? u.y : (d == 2) ? u.z : u.w;
        float xv = bf2f(uv);
        int k = q * 4 + d;
        float4 w4 = *(const float4*)&was[k * 4];
        float4 d4 = *(const float4*)&wad[k * 4];
        ps[0] += xv * w4.x; ps[1] += xv * w4.y;
        ps[2] += xv * w4.z; ps[3] += xv * w4.w;
        pd[0] += xv * d4.x; pd[1] += xv * d4.y;
        pd[2] += xv * d4.z; pd[3] += xv * d4.w;
    }
#pragma unroll
    for (int o = 1; o < 16; o <<= 1) {
#pragma unroll
        for (int hd = 0; hd < 4; ++hd) {
            ps[hd] += __shfl_xor(ps[hd], o, 64);
            pd[hd] += __shfl_xor(pd[hd], o, 64);
        }
    }
    if (q == 0) {
        *(float4*)&al[n * 4] = make_float4(ps[0], ps[1], ps[2], ps[3]);
        *(float4*)&ar[n * 4] = make_float4(pd[0], pd[1], pd[2], pd[3]);
    }
}

// ---------------- attention aggregation over x (128B rows) ----------------
// xagg[n][hd*64+k] = (sum_s p_hd(s) x[s][k]) / den_hd  -- bias folded into cb
__global__ __launch_bounds__(256) void k_agg_x(const int* __restrict__ off,
                                               const int* __restrict__ csr,
                                               const float* __restrict__ al,
                                               const float* __restrict__ ar,
                                               const u16* __restrict__ xb,
                                               u16* __restrict__ xagg) {
    int lane = threadIdx.x & 63;
    int n = blockIdx.x * 4 + (threadIdx.x >> 6);
    int hh = lane & 3;
    float ar_hh = ar[n * 4 + hh];
    int beg = off[n], end = off[n + 1];
    float den[4] = {0.f, 0.f, 0.f, 0.f};
    float acc[4] = {0.f, 0.f, 0.f, 0.f};

    for (int cbase = beg; cbase < end; cbase += 64) {
        int cnt = min(64, end - cbase);
        int sidx = csr[cbase + ((lane < cnt) ? lane : 0)];
        // p-phase: lane computes edge (lane>>2), head (lane&3) per 16-edge batch
        float pb[4];
#pragma unroll
        for (int b = 0; b < 4; ++b) {
            int jj = b * 16 + (lane >> 2);
            int sj = __shfl(sidx, (jj < cnt) ? jj : 0, 64);
            pb[b] = expf(lrelu(al[sj * 4 + hh] + ar_hh));
        }
        int cntp = (cnt + 3) & ~3;
        // prologue: 4 x-rows (lane = k-dim, 2B/lane = 128B coalesced)
        int s0 = __shfl(sidx, 0, 64);
        int s1 = __shfl(sidx, 1 < cnt ? 1 : 0, 64);
        int s2 = __shfl(sidx, 2 < cnt ? 2 : 0, 64);
        int s3 = __shfl(sidx, 3 < cnt ? 3 : 0, 64);
        float xv0 = bf2f(xb[(size_t)s0 * 64 + lane]);
        float xv1 = bf2f(xb[(size_t)s1 * 64 + lane]);
        float xv2 = bf2f(xb[(size_t)s2 * 64 + lane]);
        float xv3 = bf2f(xb[(size_t)s3 * 64 + lane]);
        for (int j = 0; j < cntp; j += 4) {
            float nv0, nv1, nv2, nv3;
            bool more = (j + 4) < cntp;
            if (more) {
                int q0 = j + 4, q1 = j + 5, q2 = j + 6, q3 = j + 7;
                int t0 = __shfl(sidx, q0 < cnt ? q0 : 0, 64);
                int t1 = __shfl(sidx, q1 < cnt ? q1 : 0, 64);
                int t2 = __shfl(sidx, q2 < cnt ? q2 : 0, 64);
                int t3 = __shfl(sidx, q3 < cnt ? q3 : 0, 64);
                nv0 = bf2f(xb[(size_t)t0 * 64 + lane]);
                nv1 = bf2f(xb[(size_t)t1 * 64 + lane]);
                nv2 = bf2f(xb[(size_t)t2 * 64 + lane]);
                nv3 = bf2f(xb[(size_t)t3 * 64 + lane]);
            }
#pragma unroll
            for (int q = 0; q < 4; ++q) {
                int jq = j + q;
                int b = (jq >> 4) & 3;
                float pbb = (b == 0) ? pb[0] : (b == 1) ? pb[1] : (b == 2) ? pb[2] : pb[3];
                float xq = (q == 0) ? xv0 : (q == 1) ? xv1 : (q == 2) ? xv2 : xv3;
#pragma unroll
                for (int hd = 0; hd < 4; ++hd) {
                    float p = __shfl(pbb, ((jq & 15) << 2) | hd, 64);
                    p = (jq < cnt) ? p : 0.f;
                    acc[hd] += p * xq;
                    den[hd] += p;
                }
            }
            if (more) { xv0 = nv0; xv1 = nv1; xv2 = nv2; xv3 = nv3; }
        }
    }
#pragma unroll
    for (int hd = 0; hd < 4; ++hd) {
        float inv = 1.f / (den[hd] + 1e-16f);
        xagg[(size_t)n * 256 + hd * 64 + lane] = f2bf(acc[hd] * inv);
    }
}

// out[N,64](bf16) = relu(A[N,256](bf16) @ C[256,64] + cb)  -- MFMA 16x16x32
__global__ __launch_bounds__(256) void k_gemm_cmb(const u16* __restrict__ A,
                                                  const u16* __restrict__ CT,
                                                  const float* __restrict__ cb,
                                                  u16* __restrict__ out) {
    int lane = threadIdx.x & 63;
    int wid = threadIdx.x >> 6;
    int g = lane >> 4, c = lane & 15;
    int r0 = blockIdx.x * 64 + wid * 16;
    int arow = r0 + c; if (arow > NN - 1) arow = NN - 1;
    const u16* aptr = A + (size_t)arow * 256 + g * 8;
    const u16* bptr = CT + (size_t)c * 256 + g * 8;
    f32x4 acc[4];
#pragma unroll
    for (int t = 0; t < 4; ++t) acc[t] = (f32x4){0.f, 0.f, 0.f, 0.f};
#pragma unroll
    for (int ks = 0; ks < 8; ++ks) {
        bf16x8 af = *(const bf16x8*)(aptr + ks * 32);
#pragma unroll
        for (int t = 0; t < 4; ++t) {
            bf16x8 bfr = *(const bf16x8*)(bptr + t * 16 * 256 + ks * 32);
            acc[t] = __builtin_amdgcn_mfma_f32_16x16x32_bf16(af, bfr, acc[t], 0, 0, 0);
        }
    }
    int orow0 = r0 + g * 4;
#pragma unroll
    for (int t = 0; t < 4; ++t) {
        int col = t * 16 + c;
        float bv = cb[col];
#pragma unroll
        for (int j = 0; j < 4; ++j) {
            int row = orow0 + j;
            if (row < NN) out[(size_t)row * 64 + col] = f2bf(fmaxf(acc[t][j] + bv, 0.f));
        }
    }
}

// ---------------- LSTM ----------------
__global__ __launch_bounds__(256) void k_lstm(const float* __restrict__ xa,
                                              const float* __restrict__ xb,
                                              const float* __restrict__ WiT,
                                              const float* __restrict__ WhT,
                                              const float* __restrict__ bb,
                                              const float* __restrict__ h_in,
                                              const float* __restrict__ c_in,
                                              float* __restrict__ h_out,
                                              float* __restrict__ c_out,
                                              float* __restrict__ hs_out) {
    __shared__ float xs[4][192];
    int w = threadIdx.x >> 6, lane = threadIdx.x & 63;
    int row = blockIdx.x * 4 + w;
    xs[w][lane] = xa[(size_t)row * 64 + lane];
    if (xb) xs[w][64 + lane] = xb[(size_t)row * 64 + lane];
    xs[w][128 + lane] = h_in[(size_t)row * 64 + lane];
    __syncthreads();
    float ai = bb[lane];
    float af = bb[64 + lane];
    float ag = bb[128 + lane];
    float ao = bb[192 + lane];
    int D = xb ? 128 : 64;
    for (int k = 0; k < D; ++k) {
        float xv = xs[w][k];
        const float* wr = &WiT[k * 256];
        ai += xv * wr[lane];       af += xv * wr[64 + lane];
        ag += xv * wr[128 + lane]; ao += xv * wr[192 + lane];
    }
    for (int k = 0; k < 64; ++k) {
        float hv = xs[w][128 + k];
        const float* wr = &WhT[k * 256];
        ai += hv * wr[lane];       af += hv * wr[64 + lane];
        ag += hv * wr[128 + lane]; ao += hv * wr[192 + lane];
    }
    float iv = sigm(ai), fv = sigm(af), gv = tanhf(ag), ov = sigm(ao);
    float c = fv * c_in[(size_t)row * 64 + lane] + iv * gv;
    float hh = ov * tanhf(c);
    c_out[(size_t)row * 64 + lane] = c;
    h_out[(size_t)row * 64 + lane] = hh;
    if (hs_out) hs_out[(size_t)row * 64 + lane] = hh;
}

// ---------------- final FC ----------------
__global__ __launch_bounds__(256) void k_final(const float* __restrict__ h1,
                                               const float* __restrict__ h2,
                                               const float* __restrict__ w1,
                                               const float* __restrict__ b1,
                                               const float* __restrict__ w2,
                                               const float* __restrict__ b2,
                                               float* __restrict__ out) {
    __shared__ float zs[4][128];
    int w = threadIdx.x >> 6, lane = threadIdx.x & 63;
    int row = blockIdx.x * 4 + w;
    zs[w][lane] = h1[(size_t)row * 64 + lane];
    zs[w][64 + lane] = h2[(size_t)row * 64 + lane];
    __syncthreads();
    float acc = b1[lane];
    for (int k = 0; k < 128; ++k) acc += zs[w][k] * w1[k * 64 + lane];
    float r = fmaxf(acc, 0.f);
    float t0 = r * w2[lane * 2];
    float t1 = r * w2[lane * 2 + 1];
#pragma unroll
    for (int o = 32; o >= 1; o >>= 1) {
        t0 += __shfl_xor(t0, o, 64);
        t1 += __shfl_xor(t1, o, 64);
    }
    if (lane == 0) {
        out[row * 2]     = fmaxf(t0 + b2[0], 0.f);
        out[row * 2 + 1] = fmaxf(t1 + b2[1], 0.f);
    }
}

extern "C" void kernel_launch(void* const* d_in, const int* in_sizes, int n_in,
                              void* d_out, int out_size, void* d_ws, size_t ws_size,
                              hipStream_t stream) {
    const float* emb  = (const float*)d_in[0];
    const float* g1W  = (const float*)d_in[1];
    const float* g1as = (const float*)d_in[2];
    const float* g1ad = (const float*)d_in[3];
    const float* g1b  = (const float*)d_in[4];
    const float* l1W  = (const float*)d_in[5];
    const float* l1b  = (const float*)d_in[6];
    const float* g2W  = (const float*)d_in[7];
    const float* g2as = (const float*)d_in[8];
    const float* g2ad = (const float*)d_in[9];
    const float* g2b  = (const float*)d_in[10];
    const float* l2W  = (const float*)d_in[11];
    const float* l2b  = (const float*)d_in[12];
    const float* Wi1  = (const float*)d_in[13];
    const float* Wh1  = (const float*)d_in[14];
    const float* b1   = (const float*)d_in[15];
    const float* Wi2  = (const float*)d_in[16];
    const float* Wh2  = (const float*)d_in[17];
    const float* b2   = (const float*)d_in[18];
    const float* fc1W = (const float*)d_in[19];
    const float* fc1b = (const float*)d_in[20];
    const float* fc2W = (const float*)d_in[21];
    const float* fc2b = (const float*)d_in[22];
    const int* edges = (const int*)d_in[23];
    const int* clf   = (const int*)d_in[27];

    char* ws = (char*)d_ws;
    size_t woff = 0;
    auto alloc = [&](size_t bytes) -> void* {
        void* p = ws + woff;
        woff += (bytes + 255) & ~(size_t)255;
        return p;
    };
    int* csr_off  = (int*)alloc((size_t)TT * (NN + 1) * 4);
    int* csr_fil  = (int*)alloc((size_t)TT * NN * 4);
    int* csr_src  = (int*)alloc((size_t)TT * ET * 4);
    int* scan_sum = (int*)alloc((size_t)TT * NCH * 4);
    int* scan_bas = (int*)alloc((size_t)TT * NCH * 4);
    u16* embb     = (u16*)alloc((size_t)TT * NN * 64 * 2);
    u16* xbuf     = (u16*)alloc((size_t)NN * 64 * 2);
    u16* xaggb    = (u16*)alloc((size_t)NN * 256 * 2);
    float* albuf  = (float*)alloc((size_t)NN * 4 * 4);
    float* arbuf  = (float*)alloc((size_t)NN * 4 * 4);
    float* seq    = (float*)alloc((size_t)2 * TT * NC * 64 * 4);
    float* hsb    = (float*)alloc((size_t)TT * NC * 64 * 4);
    float* h1s    = (float*)alloc((size_t)NC * 64 * 4);
    float* c1s    = (float*)alloc((size_t)NC * 64 * 4);
    float* h2s    = (float*)alloc((size_t)NC * 64 * 4);
    float* c2s    = (float*)alloc((size_t)NC * 64 * 4);
    float* WiT1   = (float*)alloc(128 * 256 * 4);
    float* WhT1   = (float*)alloc(64 * 256 * 4);
    float* WiT2   = (float*)alloc(64 * 256 * 4);
    float* WhT2   = (float*)alloc(64 * 256 * 4);
    u16* CT1      = (u16*)alloc((size_t)2 * 64 * 256 * 2);   // [L][64][256] bf16
    u16* CT2      = (u16*)alloc((size_t)2 * 64 * 256 * 2);
    float* cb1    = (float*)alloc((size_t)2 * 64 * 4);
    float* cb2    = (float*)alloc((size_t)2 * 64 * 4);
    float* wasb1  = (float*)alloc((size_t)2 * 64 * 4 * 4);   // [L][64][4]
    float* wadb1  = (float*)alloc((size_t)2 * 64 * 4 * 4);
    float* wasb2  = (float*)alloc((size_t)2 * 64 * 4 * 4);
    float* wadb2  = (float*)alloc((size_t)2 * 64 * 4 * 4);

    // CSR build (per snapshot, includes self-loops)
    k_fill1<<<(TT * NN + 255) / 256, 256, 0, stream>>>(csr_fil, TT * NN);
    k_count<<<(TT * EE + 255) / 256, 256, 0, stream>>>(edges, csr_fil);
    k_scan1<<<TT * NCH, 256, 0, stream>>>(csr_fil, scan_sum);
    k_scan2<<<TT, 256, 0, stream>>>(scan_sum, scan_bas, csr_off);
    k_scan3<<<TT * NCH, 256, 0, stream>>>(csr_fil, scan_bas, csr_off);
    k_csrfill<<<(TT * ET + 255) / 256, 256, 0, stream>>>(edges, csr_fil, csr_src);

    // weight preps
    k_transpose<<<(256 * 128 + 255) / 256, 256, 0, stream>>>(Wi1, WiT1, 256, 128);
    k_transpose<<<(256 * 64 + 255) / 256, 256, 0, stream>>>(Wh1, WhT1, 256, 64);
    k_transpose<<<(256 * 64 + 255) / 256, 256, 0, stream>>>(Wi2, WiT2, 256, 64);
    k_transpose<<<(256 * 64 + 255) / 256, 256, 0, stream>>>(Wh2, WhT2, 256, 64);
    k_prep_was<<<2, 256, 0, stream>>>(g1W, g1as, g1ad, wasb1, wadb1);
    k_prep_was<<<2, 256, 0, stream>>>(g2W, g2as, g2ad, wasb2, wadb2);
    k_prep_cmb<<<(2 * 64 * 256 + 255) / 256, 256, 0, stream>>>(g1W, l1W, CT1);
    k_prep_cmb<<<(2 * 64 * 256 + 255) / 256, 256, 0, stream>>>(g2W, l2W, CT2);
    k_prep_cb<<<1, 256, 0, stream>>>(g1b, l1W, l1b, cb1);
    k_prep_cb<<<1, 256, 0, stream>>>(g2b, l2W, l2b, cb2);
    // emb -> bf16
    k_f2bf4<<<(TT * NN * 16 + 255) / 256, 256, 0, stream>>>(emb, embb, TT * NN * 16);

    for (int s = 0; s < 2; ++s) {
        const float* was = s ? wasb2 : wasb1;
        const float* wad = s ? wadb2 : wadb1;
        const u16* CT    = s ? CT2 : CT1;
        const float* cbp = s ? cb2 : cb1;
        for (int t = 0; t < TT; ++t) {
            for (int l = 0; l < 2; ++l) {
                const u16* xin = (l == 0) ? (embb + (size_t)t * NN * 64) : xbuf;
                k_alar_x<<<NN / 16, 256, 0, stream>>>(
                    xin, was + l * 256, wad + l * 256, albuf, arbuf);
                k_agg_x<<<NN / 4, 256, 0, stream>>>(
                    csr_off + (size_t)t * (NN + 1), csr_src + (size_t)t * ET,
                    albuf, arbuf, xin, xaggb);
                k_gemm_cmb<<<(NN + 63) / 64, 256, 0, stream>>>(
                    xaggb, CT + (size_t)l * 16384, cbp + l * 64, xbuf);
            }
            k_gather<<<(NC * 16 + 255) / 256, 256, 0, stream>>>(
                xbuf, clf, seq + ((size_t)s * TT + t) * NC * 64);
        }
    }

    hipMemsetAsync(h1s, 0, (size_t)NC * 64 * 4, stream);
    hipMemsetAsync(c1s, 0, (size_t)NC * 64 * 4, stream);
    hipMemsetAsync(h2s, 0, (size_t)NC * 64 * 4, stream);
    hipMemsetAsync(c2s, 0, (size_t)NC * 64 * 4, stream);

    // LSTM1: time reversed (outs[::-1]) -> step st reads snapshot TT-1-st
    for (int st = 0; st < TT; ++st) {
        int tsn = TT - 1 - st;
        k_lstm<<<NC / 4, 256, 0, stream>>>(
            seq + (size_t)tsn * NC * 64,
            seq + (size_t)(TT + tsn) * NC * 64,
            WiT1, WhT1, b1, h1s, c1s, h1s, c1s,
            hsb + (size_t)st * NC * 64);
    }
    // LSTM2 over hs
    for (int st = 0; st < TT; ++st) {
        k_lstm<<<NC / 4, 256, 0, stream>>>(
            hsb + (size_t)st * NC * 64, nullptr,
            WiT2, WhT2, b2, h2s, c2s, h2s, c2s, nullptr);
    }
    k_final<<<NC / 4, 256, 0, stream>>>(h1s, h2s, fc1W, fc1b, fc2W, fc2b, (float*)d_out);
}